// Round 1
// baseline (4601.968 us; speedup 1.0000x reference)
//
#include <hip/hip_runtime.h>
#include <math.h>

#define NB 16
#define NM 2048
#define NCTR 512
#define NK 32
#define NDIM 384

typedef unsigned long long ull;

// Exact (no-FMA-contraction) squared distance, matching XLA's per-op fp32:
// ((dx*dx + dy*dy) + dz*dz) with each op individually rounded.
__device__ __forceinline__ float dist2_exact(float ax, float ay, float az,
                                             float bx, float by, float bz) {
  float dx = __fsub_rn(ax, bx);
  float dy = __fsub_rn(ay, by);
  float dz = __fsub_rn(az, bz);
  return __fadd_rn(__fadd_rn(__fmul_rn(dx, dx), __fmul_rn(dy, dy)),
                   __fmul_rn(dz, dz));
}

__device__ __forceinline__ float gelu_f(float x) {
  return 0.5f * x * (1.0f + erff(x * 0.70710678118654752f));
}

// ---------------------------------------------------------------------------
// FPS: one block per batch, 512 threads, 4 points/thread in registers.
// Key = (dist_bits << 32) | (0x7FFFFFFF - idx): max-reduce == argmax with
// first-index tiebreak (matches jnp.argmax).
// ---------------------------------------------------------------------------
__global__ __launch_bounds__(512)
void fps_kernel(const float* __restrict__ pc, float* __restrict__ centers) {
  int b = blockIdx.x;
  __shared__ float pos[NM * 3];
  __shared__ ull red[2][8];
  const float* pb = pc + (size_t)b * (NM * 3);
  for (int i = threadIdx.x; i < NM * 3; i += 512) pos[i] = pb[i];
  __syncthreads();
  int tid = threadIdx.x, lane = tid & 63, wv = tid >> 6;
  float* cb = centers + (size_t)b * (NCTR * 3);
  float sx = pos[0], sy = pos[1], sz = pos[2];
  if (tid == 0) { cb[0] = sx; cb[1] = sy; cb[2] = sz; }
  float d[4];
  for (int n = 1; n < NCTR; ++n) {
    ull best = 0;
#pragma unroll
    for (int i = 0; i < 4; ++i) {
      int p = tid + 512 * i;
      float nd = dist2_exact(pos[3 * p], pos[3 * p + 1], pos[3 * p + 2], sx, sy, sz);
      d[i] = (n == 1) ? nd : fminf(d[i], nd);
      ull key = ((ull)__float_as_uint(d[i]) << 32) | (unsigned)(0x7FFFFFFF - p);
      best = best > key ? best : key;
    }
#pragma unroll
    for (int off = 32; off; off >>= 1) {
      ull o = __shfl_xor(best, off);
      best = best > o ? best : o;
    }
    if (lane == 0) red[n & 1][wv] = best;
    __syncthreads();
    ull gb = red[n & 1][0];
#pragma unroll
    for (int w = 1; w < 8; ++w) {
      ull o = red[n & 1][w];
      gb = gb > o ? gb : o;
    }
    int j = 0x7FFFFFFF - (int)(unsigned)(gb & 0xFFFFFFFFull);
    sx = pos[3 * j]; sy = pos[3 * j + 1]; sz = pos[3 * j + 2];
    if (tid == 0) { cb[n * 3] = sx; cb[n * 3 + 1] = sy; cb[n * 3 + 2] = sz; }
  }
}

// ---------------------------------------------------------------------------
// KNN: 4 centers per block (one per wave), 32 points/lane in registers.
// Key = (dist_bits << 11) | idx; 32 rounds of cached-min extraction.
// Min-key order == top_k(-d2) stable order (smaller dist, then smaller idx).
// ---------------------------------------------------------------------------
__global__ __launch_bounds__(256)
void knn_kernel(const float* __restrict__ pc, const float* __restrict__ centers,
                int* __restrict__ nn) {
  __shared__ float pos[NM * 3];
  int b = blockIdx.x >> 7;            // 128 blocks per batch
  int n0 = (blockIdx.x & 127) << 2;
  const float* pb = pc + (size_t)b * (NM * 3);
  for (int i = threadIdx.x; i < NM * 3; i += 256) pos[i] = pb[i];
  __syncthreads();
  int wv = threadIdx.x >> 6, lane = threadIdx.x & 63;
  int gc = b * NCTR + n0 + wv;
  float cx = centers[gc * 3], cy = centers[gc * 3 + 1], cz = centers[gc * 3 + 2];
  ull key[32];
  ull lmin = ~0ull;
#pragma unroll
  for (int r = 0; r < 32; ++r) {
    int p = lane + (r << 6);
    float nd = dist2_exact(pos[3 * p], pos[3 * p + 1], pos[3 * p + 2], cx, cy, cz);
    key[r] = ((ull)__float_as_uint(nd) << 11) | (unsigned)p;
    lmin = lmin < key[r] ? lmin : key[r];
  }
  int* nnc = nn + (size_t)gc * NK;
  for (int round = 0; round < NK; ++round) {
    ull w = lmin;
#pragma unroll
    for (int off = 32; off; off >>= 1) {
      ull o = __shfl_xor(w, off);
      w = w < o ? w : o;
    }
    if (lmin == w) {                  // unique owner (idx embedded in key)
      nnc[round] = (int)(w & 2047ull);
      lmin = ~0ull;
#pragma unroll
      for (int r = 0; r < 32; ++r) {
        key[r] = (key[r] == w) ? ~0ull : key[r];
        lmin = lmin < key[r] ? lmin : key[r];
      }
    }
  }
}

// ---------------------------------------------------------------------------
// Edge MLP: one block per center. feat[51] per edge -> relu(@lw1[51,256]) ->
// @lw2[256,256] -> max over 32 edges. Transposed LDS tiles for float4
// broadcast reads; acc[32] per thread (thread = output channel).
// ---------------------------------------------------------------------------
__global__ __launch_bounds__(256)
void edge_mlp(const float* __restrict__ pc, const float* __restrict__ centers,
              const int* __restrict__ nn,
              const float* __restrict__ lw1, const float* __restrict__ lb1,
              const float* __restrict__ lw2, const float* __restrict__ lb2,
              float* __restrict__ h) {
  __shared__ float featT[51][36];   // [comp][edge]
  __shared__ float t1T[256][36];    // [chan][edge]
  int c = blockIdx.x;
  int b = c >> 9;
  int tid = threadIdx.x;
  {
    int e = tid >> 3, g = tid & 7;
    int j = nn[(size_t)c * NK + e];
    const float* sp = pc + ((size_t)b * NM + j) * 3;
    float rx = sp[0] - centers[c * 3];
    float ry = sp[1] - centers[c * 3 + 1];
    float rz = sp[2] - centers[c * 3 + 2];
    if (g == 0) { featT[0][e] = rx; featT[1][e] = ry; featT[2][e] = rz; }
    float ef = (float)(M_PI * (double)(1 << g));
    featT[3 + g][e]       = sinf(rx * ef);
    featT[3 + 8 + g][e]   = sinf(ry * ef);
    featT[3 + 16 + g][e]  = sinf(rz * ef);
    featT[27 + g][e]      = cosf(rx * ef);
    featT[27 + 8 + g][e]  = cosf(ry * ef);
    featT[27 + 16 + g][e] = cosf(rz * ef);
  }
  __syncthreads();
  float acc[32];
  int col = tid;
  {
    float bias = lb1[col];
#pragma unroll
    for (int e = 0; e < 32; ++e) acc[e] = bias;
    for (int k = 0; k < 51; ++k) {
      float w = lw1[k * 256 + col];
      const float4* fr = (const float4*)&featT[k][0];
#pragma unroll
      for (int e4 = 0; e4 < 8; ++e4) {
        float4 f4 = fr[e4];
        acc[(e4 << 2) + 0] = fmaf(f4.x, w, acc[(e4 << 2) + 0]);
        acc[(e4 << 2) + 1] = fmaf(f4.y, w, acc[(e4 << 2) + 1]);
        acc[(e4 << 2) + 2] = fmaf(f4.z, w, acc[(e4 << 2) + 2]);
        acc[(e4 << 2) + 3] = fmaf(f4.w, w, acc[(e4 << 2) + 3]);
      }
    }
#pragma unroll
    for (int e = 0; e < 32; ++e) t1T[col][e] = fmaxf(acc[e], 0.f);
  }
  __syncthreads();
  {
    float bias = lb2[col];
#pragma unroll
    for (int e = 0; e < 32; ++e) acc[e] = bias;
    for (int k = 0; k < 256; ++k) {
      float w = lw2[k * 256 + col];
      const float4* tr = (const float4*)&t1T[k][0];
#pragma unroll
      for (int e4 = 0; e4 < 8; ++e4) {
        float4 f4 = tr[e4];
        acc[(e4 << 2) + 0] = fmaf(f4.x, w, acc[(e4 << 2) + 0]);
        acc[(e4 << 2) + 1] = fmaf(f4.y, w, acc[(e4 << 2) + 1]);
        acc[(e4 << 2) + 2] = fmaf(f4.z, w, acc[(e4 << 2) + 2]);
        acc[(e4 << 2) + 3] = fmaf(f4.w, w, acc[(e4 << 2) + 3]);
      }
    }
    float m = acc[0];
#pragma unroll
    for (int e = 1; e < 32; ++e) m = fmaxf(m, acc[e]);
    h[(size_t)c * 256 + col] = m;
  }
}

// ---------------------------------------------------------------------------
// Generic fp32 GEMM: C[M,N] = epi(A[M,K] @ W[K,N] + bias), 64x64 tile, BK=16,
// 256 threads, 4x4 per thread. EPI: 0=bias 1=relu 2=gelu 3=resid+gamma*(.)
// ---------------------------------------------------------------------------
template <int EPI>
__global__ __launch_bounds__(256)
void gemm_f32(const float* __restrict__ A, const float* __restrict__ W,
              const float* __restrict__ bias, const float* __restrict__ gamma,
              const float* resid, float* C, int M, int N, int K) {
  __shared__ float As[16][68];  // A^T tile [k][m]
  __shared__ float Ws[16][68];  // [k][n]
  int tid = threadIdx.x;
  int tx = tid & 15, ty = tid >> 4;
  int bn = blockIdx.x << 6, bm = blockIdx.y << 6;
  float acc[4][4] = {{0.f}};
  int ar = tid >> 2, ak = (tid & 3) << 2;
  int wk = tid >> 4, wc = (tid & 15) << 2;
  const float* Ap = A + (size_t)(bm + ar) * K + ak;
  const float* Wp = W + (size_t)wk * N + bn + wc;
  for (int kt = 0; kt < K; kt += 16) {
    float4 av = *(const float4*)(Ap + kt);
    float4 wv = *(const float4*)(Wp + (size_t)kt * N);
    As[ak + 0][ar] = av.x; As[ak + 1][ar] = av.y;
    As[ak + 2][ar] = av.z; As[ak + 3][ar] = av.w;
    *(float4*)&Ws[wk][wc] = wv;
    __syncthreads();
#pragma unroll
    for (int kk = 0; kk < 16; ++kk) {
      float4 a = *(const float4*)&As[kk][ty << 2];
      float4 w = *(const float4*)&Ws[kk][tx << 2];
      acc[0][0] = fmaf(a.x, w.x, acc[0][0]); acc[0][1] = fmaf(a.x, w.y, acc[0][1]);
      acc[0][2] = fmaf(a.x, w.z, acc[0][2]); acc[0][3] = fmaf(a.x, w.w, acc[0][3]);
      acc[1][0] = fmaf(a.y, w.x, acc[1][0]); acc[1][1] = fmaf(a.y, w.y, acc[1][1]);
      acc[1][2] = fmaf(a.y, w.z, acc[1][2]); acc[1][3] = fmaf(a.y, w.w, acc[1][3]);
      acc[2][0] = fmaf(a.z, w.x, acc[2][0]); acc[2][1] = fmaf(a.z, w.y, acc[2][1]);
      acc[2][2] = fmaf(a.z, w.z, acc[2][2]); acc[2][3] = fmaf(a.z, w.w, acc[2][3]);
      acc[3][0] = fmaf(a.w, w.x, acc[3][0]); acc[3][1] = fmaf(a.w, w.y, acc[3][1]);
      acc[3][2] = fmaf(a.w, w.z, acc[3][2]); acc[3][3] = fmaf(a.w, w.w, acc[3][3]);
    }
    __syncthreads();
  }
  float4 bv = *(const float4*)(bias + bn + (tx << 2));
  float4 g4;
  if (EPI == 3) g4 = *(const float4*)(gamma + bn + (tx << 2));
#pragma unroll
  for (int i = 0; i < 4; ++i) {
    int row = bm + (ty << 2) + i;
    float v0 = acc[i][0] + bv.x, v1 = acc[i][1] + bv.y;
    float v2 = acc[i][2] + bv.z, v3 = acc[i][3] + bv.w;
    if (EPI == 1) {
      v0 = fmaxf(v0, 0.f); v1 = fmaxf(v1, 0.f);
      v2 = fmaxf(v2, 0.f); v3 = fmaxf(v3, 0.f);
    } else if (EPI == 2) {
      v0 = gelu_f(v0); v1 = gelu_f(v1); v2 = gelu_f(v2); v3 = gelu_f(v3);
    } else if (EPI == 3) {
      const float* rp = resid + (size_t)row * N + bn + (tx << 2);
      float4 r4 = *(const float4*)rp;
      v0 = r4.x + g4.x * v0; v1 = r4.y + g4.y * v1;
      v2 = r4.z + g4.z * v2; v3 = r4.w + g4.w * v3;
    }
    float4 ov; ov.x = v0; ov.y = v1; ov.z = v2; ov.w = v3;
    *(float4*)(C + (size_t)row * N + bn + (tx << 2)) = ov;
  }
}

// ---------------------------------------------------------------------------
// Positional-embedding add: x[c,:] += concat(center, fourier(center)) @ ew + eb
// ---------------------------------------------------------------------------
__global__ __launch_bounds__(256)
void pe_add(const float* __restrict__ centers, const float* __restrict__ ew,
            const float* __restrict__ eb, float* x) {
  __shared__ float fc[51];
  int c = blockIdx.x, tid = threadIdx.x;
  if (tid < 24) {
    int a = tid >> 3, f = tid & 7;
    float coord = centers[c * 3 + a];
    float p = coord * (float)(M_PI * (double)(1 << f));
    fc[3 + tid] = sinf(p);
    fc[27 + tid] = cosf(p);
  } else if (tid < 27) {
    fc[tid - 24] = centers[c * 3 + (tid - 24)];
  }
  __syncthreads();
  for (int j = tid; j < NDIM; j += 256) {
    float acc = eb[j];
#pragma unroll
    for (int d = 0; d < 51; ++d) acc = fmaf(fc[d], ew[d * NDIM + j], acc);
    x[(size_t)c * NDIM + j] += acc;
  }
}

// ---------------------------------------------------------------------------
// LayerNorm: one wave per row (384 = 6 per lane).
// ---------------------------------------------------------------------------
__global__ __launch_bounds__(256)
void ln_f32(const float* __restrict__ x, const float* __restrict__ g,
            const float* __restrict__ b, float* __restrict__ y) {
  int row = (blockIdx.x << 2) + (threadIdx.x >> 6);
  int lane = threadIdx.x & 63;
  const float* xr = x + (size_t)row * NDIM;
  float v[6];
#pragma unroll
  for (int i = 0; i < 6; ++i) v[i] = xr[lane + (i << 6)];
  float s = 0.f;
#pragma unroll
  for (int i = 0; i < 6; ++i) s += v[i];
#pragma unroll
  for (int off = 32; off; off >>= 1) s += __shfl_xor(s, off);
  float m = s / 384.f;
  float var = 0.f;
#pragma unroll
  for (int i = 0; i < 6; ++i) { float dd = v[i] - m; var += dd * dd; }
#pragma unroll
  for (int off = 32; off; off >>= 1) var += __shfl_xor(var, off);
  var = var / 384.f;
  float rs = 1.f / sqrtf(var + 1e-6f);
#pragma unroll
  for (int i = 0; i < 6; ++i) {
    int cc = lane + (i << 6);
    y[(size_t)row * NDIM + cc] = (v[i] - m) * rs * g[cc] + b[cc];
  }
}

// ---------------------------------------------------------------------------
// Attention: one block per (batch, head, 64 q-rows). Online softmax over 8
// chunks of 64 keys. oacc 4x4 per thread in registers.
// ---------------------------------------------------------------------------
__global__ __launch_bounds__(256)
void attn_f32(const float* __restrict__ qkv, float* __restrict__ o) {
  __shared__ float qT[64][68];  // [d][r]
  __shared__ float kT[64][68];  // [d][j]
  __shared__ float vS[64][68];  // [j][d]
  __shared__ float sS[64][68];  // [r][j]
  __shared__ float mS[64], lS[64], fS[64];
  int bi = blockIdx.x;
  int qt = bi & 7;
  int hh = (bi >> 3) % 6;
  int b = bi / 48;
  int tid = threadIdx.x;
  const float* qbase = qkv + (size_t)(b * NCTR) * 1152;
  {
    int r = tid >> 2, dg = (tid & 3) << 4;
    const float* qp = qbase + (size_t)(qt * 64 + r) * 1152 + hh * 64 + dg;
#pragma unroll
    for (int i = 0; i < 4; ++i) {
      float4 v4 = *(const float4*)(qp + (i << 2));
      qT[dg + (i << 2) + 0][r] = v4.x;
      qT[dg + (i << 2) + 1][r] = v4.y;
      qT[dg + (i << 2) + 2][r] = v4.z;
      qT[dg + (i << 2) + 3][r] = v4.w;
    }
  }
  if (tid < 64) { mS[tid] = -INFINITY; lS[tid] = 0.f; }
  float oacc[4][4] = {{0.f}};
  int ty = tid >> 4, tx = tid & 15;
  for (int ch = 0; ch < 8; ++ch) {
    __syncthreads();
    {
      int r = tid >> 2, dg = (tid & 3) << 4;
      const float* kp = qbase + (size_t)(ch * 64 + r) * 1152 + 384 + hh * 64 + dg;
      const float* vp = qbase + (size_t)(ch * 64 + r) * 1152 + 768 + hh * 64 + dg;
#pragma unroll
      for (int i = 0; i < 4; ++i) {
        float4 v4 = *(const float4*)(kp + (i << 2));
        kT[dg + (i << 2) + 0][r] = v4.x;
        kT[dg + (i << 2) + 1][r] = v4.y;
        kT[dg + (i << 2) + 2][r] = v4.z;
        kT[dg + (i << 2) + 3][r] = v4.w;
      }
#pragma unroll
      for (int i = 0; i < 4; ++i) {
        *(float4*)&vS[r][dg + (i << 2)] = *(const float4*)(vp + (i << 2));
      }
    }
    __syncthreads();
    float sacc[4][4] = {{0.f}};
    for (int dd = 0; dd < 64; ++dd) {
      float4 a = *(const float4*)&qT[dd][ty << 2];
      float4 w = *(const float4*)&kT[dd][tx << 2];
      sacc[0][0] = fmaf(a.x, w.x, sacc[0][0]); sacc[0][1] = fmaf(a.x, w.y, sacc[0][1]);
      sacc[0][2] = fmaf(a.x, w.z, sacc[0][2]); sacc[0][3] = fmaf(a.x, w.w, sacc[0][3]);
      sacc[1][0] = fmaf(a.y, w.x, sacc[1][0]); sacc[1][1] = fmaf(a.y, w.y, sacc[1][1]);
      sacc[1][2] = fmaf(a.y, w.z, sacc[1][2]); sacc[1][3] = fmaf(a.y, w.w, sacc[1][3]);
      sacc[2][0] = fmaf(a.z, w.x, sacc[2][0]); sacc[2][1] = fmaf(a.z, w.y, sacc[2][1]);
      sacc[2][2] = fmaf(a.z, w.z, sacc[2][2]); sacc[2][3] = fmaf(a.z, w.w, sacc[2][3]);
      sacc[3][0] = fmaf(a.w, w.x, sacc[3][0]); sacc[3][1] = fmaf(a.w, w.y, sacc[3][1]);
      sacc[3][2] = fmaf(a.w, w.z, sacc[3][2]); sacc[3][3] = fmaf(a.w, w.w, sacc[3][3]);
    }
#pragma unroll
    for (int i = 0; i < 4; ++i) {
      float4 sv;
      sv.x = sacc[i][0] * 0.125f; sv.y = sacc[i][1] * 0.125f;
      sv.z = sacc[i][2] * 0.125f; sv.w = sacc[i][3] * 0.125f;
      *(float4*)&sS[(ty << 2) + i][tx << 2] = sv;
    }
    __syncthreads();
    {
      int r = tid >> 2, gg = tid & 3;
      float vals[16];
      float vmax = -INFINITY;
#pragma unroll
      for (int i = 0; i < 4; ++i) {
        float4 p4 = *(const float4*)&sS[r][(gg << 4) + (i << 2)];
        vals[4 * i + 0] = p4.x; vals[4 * i + 1] = p4.y;
        vals[4 * i + 2] = p4.z; vals[4 * i + 3] = p4.w;
        vmax = fmaxf(vmax, fmaxf(fmaxf(p4.x, p4.y), fmaxf(p4.z, p4.w)));
      }
      vmax = fmaxf(vmax, __shfl_xor(vmax, 1));
      vmax = fmaxf(vmax, __shfl_xor(vmax, 2));
      float mold = mS[r];
      float mnew = fmaxf(mold, vmax);
      float sum = 0.f;
#pragma unroll
      for (int i = 0; i < 16; ++i) {
        float p = expf(vals[i] - mnew);
        vals[i] = p;
        sum += p;
      }
#pragma unroll
      for (int i = 0; i < 4; ++i) {
        float4 p4;
        p4.x = vals[4 * i + 0]; p4.y = vals[4 * i + 1];
        p4.z = vals[4 * i + 2]; p4.w = vals[4 * i + 3];
        *(float4*)&sS[r][(gg << 4) + (i << 2)] = p4;
      }
      sum += __shfl_xor(sum, 1);
      sum += __shfl_xor(sum, 2);
      if (gg == 0) {
        float f = expf(mold - mnew);  // exp(-inf)=0 on first chunk
        fS[r] = f;
        mS[r] = mnew;
        lS[r] = lS[r] * f + sum;
      }
    }
    __syncthreads();
    {
      float f0 = fS[(ty << 2) + 0], f1 = fS[(ty << 2) + 1];
      float f2 = fS[(ty << 2) + 2], f3 = fS[(ty << 2) + 3];
#pragma unroll
      for (int j = 0; j < 4; ++j) {
        oacc[0][j] *= f0; oacc[1][j] *= f1; oacc[2][j] *= f2; oacc[3][j] *= f3;
      }
      for (int jj = 0; jj < 64; ++jj) {
        float4 vv = *(const float4*)&vS[jj][tx << 2];
        float p0 = sS[(ty << 2) + 0][jj];
        float p1 = sS[(ty << 2) + 1][jj];
        float p2 = sS[(ty << 2) + 2][jj];
        float p3 = sS[(ty << 2) + 3][jj];
        oacc[0][0] = fmaf(p0, vv.x, oacc[0][0]); oacc[0][1] = fmaf(p0, vv.y, oacc[0][1]);
        oacc[0][2] = fmaf(p0, vv.z, oacc[0][2]); oacc[0][3] = fmaf(p0, vv.w, oacc[0][3]);
        oacc[1][0] = fmaf(p1, vv.x, oacc[1][0]); oacc[1][1] = fmaf(p1, vv.y, oacc[1][1]);
        oacc[1][2] = fmaf(p1, vv.z, oacc[1][2]); oacc[1][3] = fmaf(p1, vv.w, oacc[1][3]);
        oacc[2][0] = fmaf(p2, vv.x, oacc[2][0]); oacc[2][1] = fmaf(p2, vv.y, oacc[2][1]);
        oacc[2][2] = fmaf(p2, vv.z, oacc[2][2]); oacc[2][3] = fmaf(p2, vv.w, oacc[2][3]);
        oacc[3][0] = fmaf(p3, vv.x, oacc[3][0]); oacc[3][1] = fmaf(p3, vv.y, oacc[3][1]);
        oacc[3][2] = fmaf(p3, vv.z, oacc[3][2]); oacc[3][3] = fmaf(p3, vv.w, oacc[3][3]);
      }
    }
  }
  __syncthreads();
  {
    float il[4];
#pragma unroll
    for (int i = 0; i < 4; ++i) il[i] = 1.f / lS[(ty << 2) + i];
#pragma unroll
    for (int i = 0; i < 4; ++i) {
      int row = b * NCTR + qt * 64 + (ty << 2) + i;
      float4 ov;
      ov.x = oacc[i][0] * il[i]; ov.y = oacc[i][1] * il[i];
      ov.z = oacc[i][2] * il[i]; ov.w = oacc[i][3] * il[i];
      *(float4*)(o + (size_t)row * NDIM + hh * 64 + (tx << 2)) = ov;
    }
  }
}

// ---------------------------------------------------------------------------
extern "C" void kernel_launch(void* const* d_in, const int* in_sizes, int n_in,
                              void* d_out, int out_size, void* d_ws, size_t ws_size,
                              hipStream_t stream) {
  const float* pc      = (const float*)d_in[0];
  const float* embed_w = (const float*)d_in[1];
  const float* embed_b = (const float*)d_in[2];
  const float* lw1     = (const float*)d_in[3];
  const float* lb1     = (const float*)d_in[4];
  const float* lw2     = (const float*)d_in[5];
  const float* lb2     = (const float*)d_in[6];
  const float* gw1     = (const float*)d_in[7];
  const float* gb1     = (const float*)d_in[8];
  const float* gw2     = (const float*)d_in[9];
  const float* gb2     = (const float*)d_in[10];
  const float* ln1_g   = (const float*)d_in[11];
  const float* ln1_b   = (const float*)d_in[12];
  const float* qkv_w   = (const float*)d_in[13];
  const float* qkv_b   = (const float*)d_in[14];
  const float* proj_w  = (const float*)d_in[15];
  const float* proj_b  = (const float*)d_in[16];
  const float* gamma1  = (const float*)d_in[17];
  const float* ln2_g   = (const float*)d_in[18];
  const float* ln2_b   = (const float*)d_in[19];
  const float* fc1_w   = (const float*)d_in[20];
  const float* fc1_b   = (const float*)d_in[21];
  const float* fc2_w   = (const float*)d_in[22];
  const float* fc2_b   = (const float*)d_in[23];
  const float* gamma2  = (const float*)d_in[24];
  const float* lnf_g   = (const float*)d_in[25];
  const float* lnf_b   = (const float*)d_in[26];

  float* out = (float*)d_out;
  float* centers = out + (size_t)NB * NCTR * NDIM;  // second tuple element

  int* nn = (int*)d_ws;
  float* fws = (float*)d_ws;
  float* h  = fws + 262144;          // [8192,256]
  float* x  = h + 8192 * 256;        // [8192,384]
  float* xn = x + 8192 * 384;        // [8192,384] (also 256-wide scratch)
  float* F  = xn + 8192 * 384;       // [8192,1536] (qkv / mlp hidden)

  fps_kernel<<<NB, 512, 0, stream>>>(pc, centers);
  knn_kernel<<<2048, 256, 0, stream>>>(pc, centers, nn);
  edge_mlp<<<8192, 256, 0, stream>>>(pc, centers, nn, lw1, lb1, lw2, lb2, h);
  gemm_f32<1><<<dim3(4, 128), 256, 0, stream>>>(h, gw1, gb1, nullptr, nullptr, xn,
                                                8192, 256, 256);
  gemm_f32<0><<<dim3(6, 128), 256, 0, stream>>>(xn, gw2, gb2, nullptr, nullptr, x,
                                                8192, 384, 256);
  pe_add<<<8192, 256, 0, stream>>>(centers, embed_w, embed_b, x);

  for (int l = 0; l < 6; ++l) {
    ln_f32<<<2048, 256, 0, stream>>>(x, ln1_g + l * 384, ln1_b + l * 384, xn);
    gemm_f32<0><<<dim3(18, 128), 256, 0, stream>>>(
        xn, qkv_w + (size_t)l * 384 * 1152, qkv_b + l * 1152, nullptr, nullptr, F,
        8192, 1152, 384);
    attn_f32<<<768, 256, 0, stream>>>(F, xn);
    gemm_f32<3><<<dim3(6, 128), 256, 0, stream>>>(
        xn, proj_w + (size_t)l * 384 * 384, proj_b + l * 384, gamma1 + l * 384, x, x,
        8192, 384, 384);
    ln_f32<<<2048, 256, 0, stream>>>(x, ln2_g + l * 384, ln2_b + l * 384, xn);
    gemm_f32<2><<<dim3(24, 128), 256, 0, stream>>>(
        xn, fc1_w + (size_t)l * 384 * 1536, fc1_b + l * 1536, nullptr, nullptr, F,
        8192, 1536, 384);
    gemm_f32<3><<<dim3(6, 128), 256, 0, stream>>>(
        F, fc2_w + (size_t)l * 1536 * 384, fc2_b + l * 384, gamma2 + l * 384, x, x,
        8192, 384, 1536);
  }
  ln_f32<<<2048, 256, 0, stream>>>(x, lnf_g, lnf_b, out);
}

// Round 2
// 3007.288 us; speedup vs baseline: 1.5303x; 1.5303x over previous
//
#include <hip/hip_runtime.h>
#include <math.h>

#define NB 16
#define NM 2048
#define NCTR 512
#define NK 32
#define NDIM 384

typedef unsigned long long ull;
typedef unsigned int uint;
typedef unsigned short ushort;
typedef __attribute__((ext_vector_type(8))) short bf16x8;
typedef __attribute__((ext_vector_type(4))) float f32x4;

// Exact (no-FMA-contraction) squared distance, matching XLA's per-op fp32.
__device__ __forceinline__ float dist2_exact(float ax, float ay, float az,
                                             float bx, float by, float bz) {
  float dx = __fsub_rn(ax, bx);
  float dy = __fsub_rn(ay, by);
  float dz = __fsub_rn(az, bz);
  return __fadd_rn(__fadd_rn(__fmul_rn(dx, dx), __fmul_rn(dy, dy)),
                   __fmul_rn(dz, dz));
}

__device__ __forceinline__ float gelu_f(float x) {
  return 0.5f * x * (1.0f + erff(x * 0.70710678118654752f));
}

// fp32 -> bf16 round-to-nearest-even (bit trick), and back.
__device__ __forceinline__ ushort f2bf(float f) {
  uint u = __float_as_uint(f);
  return (ushort)((u + 0x7FFFu + ((u >> 16) & 1u)) >> 16);
}
__device__ __forceinline__ float bf2f(ushort h) {
  return __uint_as_float(((uint)h) << 16);
}

// Split 8 fp32 into bf16 hi / lo packed words (2 bf16 per uint, little-endian).
__device__ __forceinline__ void cvt8(float4 p, float4 q, uint4& hi, uint4& lo) {
  float v0 = p.x, v1 = p.y, v2 = p.z, v3 = p.w;
  float v4 = q.x, v5 = q.y, v6 = q.z, v7 = q.w;
  ushort h0 = f2bf(v0), h1 = f2bf(v1), h2 = f2bf(v2), h3 = f2bf(v3);
  ushort h4 = f2bf(v4), h5 = f2bf(v5), h6 = f2bf(v6), h7 = f2bf(v7);
  ushort l0 = f2bf(v0 - bf2f(h0)), l1 = f2bf(v1 - bf2f(h1));
  ushort l2 = f2bf(v2 - bf2f(h2)), l3 = f2bf(v3 - bf2f(h3));
  ushort l4 = f2bf(v4 - bf2f(h4)), l5 = f2bf(v5 - bf2f(h5));
  ushort l6 = f2bf(v6 - bf2f(h6)), l7 = f2bf(v7 - bf2f(h7));
  hi.x = (uint)h0 | ((uint)h1 << 16); hi.y = (uint)h2 | ((uint)h3 << 16);
  hi.z = (uint)h4 | ((uint)h5 << 16); hi.w = (uint)h6 | ((uint)h7 << 16);
  lo.x = (uint)l0 | ((uint)l1 << 16); lo.y = (uint)l2 | ((uint)l3 << 16);
  lo.z = (uint)l4 | ((uint)l5 << 16); lo.w = (uint)l6 | ((uint)l7 << 16);
}

// ---------------------------------------------------------------------------
// FPS (unchanged from round 1): exact argmax semantics.
// ---------------------------------------------------------------------------
__global__ __launch_bounds__(512)
void fps_kernel(const float* __restrict__ pc, float* __restrict__ centers) {
  int b = blockIdx.x;
  __shared__ float pos[NM * 3];
  __shared__ ull red[2][8];
  const float* pb = pc + (size_t)b * (NM * 3);
  for (int i = threadIdx.x; i < NM * 3; i += 512) pos[i] = pb[i];
  __syncthreads();
  int tid = threadIdx.x, lane = tid & 63, wv = tid >> 6;
  float* cb = centers + (size_t)b * (NCTR * 3);
  float sx = pos[0], sy = pos[1], sz = pos[2];
  if (tid == 0) { cb[0] = sx; cb[1] = sy; cb[2] = sz; }
  float d[4];
  for (int n = 1; n < NCTR; ++n) {
    ull best = 0;
#pragma unroll
    for (int i = 0; i < 4; ++i) {
      int p = tid + 512 * i;
      float nd = dist2_exact(pos[3 * p], pos[3 * p + 1], pos[3 * p + 2], sx, sy, sz);
      d[i] = (n == 1) ? nd : fminf(d[i], nd);
      ull key = ((ull)__float_as_uint(d[i]) << 32) | (unsigned)(0x7FFFFFFF - p);
      best = best > key ? best : key;
    }
#pragma unroll
    for (int off = 32; off; off >>= 1) {
      ull o = __shfl_xor(best, off);
      best = best > o ? best : o;
    }
    if (lane == 0) red[n & 1][wv] = best;
    __syncthreads();
    ull gb = red[n & 1][0];
#pragma unroll
    for (int w = 1; w < 8; ++w) {
      ull o = red[n & 1][w];
      gb = gb > o ? gb : o;
    }
    int j = 0x7FFFFFFF - (int)(unsigned)(gb & 0xFFFFFFFFull);
    sx = pos[3 * j]; sy = pos[3 * j + 1]; sz = pos[3 * j + 2];
    if (tid == 0) { cb[n * 3] = sx; cb[n * 3 + 1] = sy; cb[n * 3 + 2] = sz; }
  }
}

// ---------------------------------------------------------------------------
// KNN (unchanged from round 1).
// ---------------------------------------------------------------------------
__global__ __launch_bounds__(256)
void knn_kernel(const float* __restrict__ pc, const float* __restrict__ centers,
                int* __restrict__ nn) {
  __shared__ float pos[NM * 3];
  int b = blockIdx.x >> 7;
  int n0 = (blockIdx.x & 127) << 2;
  const float* pb = pc + (size_t)b * (NM * 3);
  for (int i = threadIdx.x; i < NM * 3; i += 256) pos[i] = pb[i];
  __syncthreads();
  int wv = threadIdx.x >> 6, lane = threadIdx.x & 63;
  int gc = b * NCTR + n0 + wv;
  float cx = centers[gc * 3], cy = centers[gc * 3 + 1], cz = centers[gc * 3 + 2];
  ull key[32];
  ull lmin = ~0ull;
#pragma unroll
  for (int r = 0; r < 32; ++r) {
    int p = lane + (r << 6);
    float nd = dist2_exact(pos[3 * p], pos[3 * p + 1], pos[3 * p + 2], cx, cy, cz);
    key[r] = ((ull)__float_as_uint(nd) << 11) | (unsigned)p;
    lmin = lmin < key[r] ? lmin : key[r];
  }
  int* nnc = nn + (size_t)gc * NK;
  for (int round = 0; round < NK; ++round) {
    ull w = lmin;
#pragma unroll
    for (int off = 32; off; off >>= 1) {
      ull o = __shfl_xor(w, off);
      w = w < o ? w : o;
    }
    if (lmin == w) {
      nnc[round] = (int)(w & 2047ull);
      lmin = ~0ull;
#pragma unroll
      for (int r = 0; r < 32; ++r) {
        key[r] = (key[r] == w) ? ~0ull : key[r];
        lmin = lmin < key[r] ? lmin : key[r];
      }
    }
  }
}

// ---------------------------------------------------------------------------
// Edge MLP (unchanged from round 1) — next round's target.
// ---------------------------------------------------------------------------
__global__ __launch_bounds__(256)
void edge_mlp(const float* __restrict__ pc, const float* __restrict__ centers,
              const int* __restrict__ nn,
              const float* __restrict__ lw1, const float* __restrict__ lb1,
              const float* __restrict__ lw2, const float* __restrict__ lb2,
              float* __restrict__ h) {
  __shared__ float featT[51][36];
  __shared__ float t1T[256][36];
  int c = blockIdx.x;
  int b = c >> 9;
  int tid = threadIdx.x;
  {
    int e = tid >> 3, g = tid & 7;
    int j = nn[(size_t)c * NK + e];
    const float* sp = pc + ((size_t)b * NM + j) * 3;
    float rx = sp[0] - centers[c * 3];
    float ry = sp[1] - centers[c * 3 + 1];
    float rz = sp[2] - centers[c * 3 + 2];
    if (g == 0) { featT[0][e] = rx; featT[1][e] = ry; featT[2][e] = rz; }
    float ef = (float)(M_PI * (double)(1 << g));
    featT[3 + g][e]       = sinf(rx * ef);
    featT[3 + 8 + g][e]   = sinf(ry * ef);
    featT[3 + 16 + g][e]  = sinf(rz * ef);
    featT[27 + g][e]      = cosf(rx * ef);
    featT[27 + 8 + g][e]  = cosf(ry * ef);
    featT[27 + 16 + g][e] = cosf(rz * ef);
  }
  __syncthreads();
  float acc[32];
  int col = tid;
  {
    float bias = lb1[col];
#pragma unroll
    for (int e = 0; e < 32; ++e) acc[e] = bias;
    for (int k = 0; k < 51; ++k) {
      float w = lw1[k * 256 + col];
      const float4* fr = (const float4*)&featT[k][0];
#pragma unroll
      for (int e4 = 0; e4 < 8; ++e4) {
        float4 f4 = fr[e4];
        acc[(e4 << 2) + 0] = fmaf(f4.x, w, acc[(e4 << 2) + 0]);
        acc[(e4 << 2) + 1] = fmaf(f4.y, w, acc[(e4 << 2) + 1]);
        acc[(e4 << 2) + 2] = fmaf(f4.z, w, acc[(e4 << 2) + 2]);
        acc[(e4 << 2) + 3] = fmaf(f4.w, w, acc[(e4 << 2) + 3]);
      }
    }
#pragma unroll
    for (int e = 0; e < 32; ++e) t1T[col][e] = fmaxf(acc[e], 0.f);
  }
  __syncthreads();
  {
    float bias = lb2[col];
#pragma unroll
    for (int e = 0; e < 32; ++e) acc[e] = bias;
    for (int k = 0; k < 256; ++k) {
      float w = lw2[k * 256 + col];
      const float4* tr = (const float4*)&t1T[k][0];
#pragma unroll
      for (int e4 = 0; e4 < 8; ++e4) {
        float4 f4 = tr[e4];
        acc[(e4 << 2) + 0] = fmaf(f4.x, w, acc[(e4 << 2) + 0]);
        acc[(e4 << 2) + 1] = fmaf(f4.y, w, acc[(e4 << 2) + 1]);
        acc[(e4 << 2) + 2] = fmaf(f4.z, w, acc[(e4 << 2) + 2]);
        acc[(e4 << 2) + 3] = fmaf(f4.w, w, acc[(e4 << 2) + 3]);
      }
    }
    float m = acc[0];
#pragma unroll
    for (int e = 1; e < 32; ++e) m = fmaxf(m, acc[e]);
    h[(size_t)c * 256 + col] = m;
  }
}

// ---------------------------------------------------------------------------
// Weight pre-split: W[K,N] fp32 -> hi/lo bf16 in MFMA layout
// dst[((k>>3)*N + n)*8 + (k&7)], lo block at dst + K*N elements.
// One thread per (kb,n) chunk: reads coalesced over n, writes 16B contiguous.
// ---------------------------------------------------------------------------
__global__ __launch_bounds__(256)
void wconv(const float* __restrict__ W, ushort* __restrict__ out, int K8, int N) {
  int c = blockIdx.x * 256 + threadIdx.x;
  if (c >= K8 * N) return;
  int kb = c / N, n = c - kb * N;
  float4 p, q;
  p.x = W[(size_t)(kb * 8 + 0) * N + n];
  p.y = W[(size_t)(kb * 8 + 1) * N + n];
  p.z = W[(size_t)(kb * 8 + 2) * N + n];
  p.w = W[(size_t)(kb * 8 + 3) * N + n];
  q.x = W[(size_t)(kb * 8 + 4) * N + n];
  q.y = W[(size_t)(kb * 8 + 5) * N + n];
  q.z = W[(size_t)(kb * 8 + 6) * N + n];
  q.w = W[(size_t)(kb * 8 + 7) * N + n];
  uint4 hi, lo;
  cvt8(p, q, hi, lo);
  *(uint4*)(out + (size_t)c * 8) = hi;
  *(uint4*)(out + (size_t)(K8 * N + c) * 8) = lo;
}

// ---------------------------------------------------------------------------
// bf16x3 split MFMA GEMM: C[M,N] = epi(A@W + bias). 128x128 tile, BK=32,
// 256 threads = 4 waves (2x2 of 64x64), mfma_f32_16x16x32_bf16.
// A fp32 row-major, split inline while staging. W pre-split ([K/8][N][8]).
// acc += Al*Wh + Ah*Wl + Ah*Wh  (3 MFMA per fragment pair).
// EPI: 0=bias 1=relu 2=gelu 3=resid+gamma*(.)
// ---------------------------------------------------------------------------
template <int EPI>
__global__ __launch_bounds__(256, 2)
void gemm_x3(const float* __restrict__ A, const ushort* __restrict__ Wh,
             const ushort* __restrict__ Wl, const float* __restrict__ bias,
             const float* __restrict__ gamma, const float* __restrict__ resid,
             float* __restrict__ C, int M, int N, int K) {
  __shared__ __align__(16) ushort Ah[4096], Al[4096], Bh[4096], Bl[4096];
  int tid = threadIdx.x;
  int bn = blockIdx.x << 7, bm = blockIdx.y << 7;
  int wid = tid >> 6, lane = tid & 63;
  int wr = wid >> 1, wc = wid & 1;
  int l15 = lane & 15, l4 = lane >> 4;

  // A staging: thread covers chunks (akb0,arow) and (akb0+1,arow) = 16 fp32.
  int arow = tid >> 1, akb0 = (tid & 1) << 1;
  const float* Ap = A + (size_t)(bm + arow) * K + (akb0 << 3);
  // W staging: chunks c=tid (kb=tid>>7,n=tid&127) and c+256 (kb+2,n).
  int wkb = tid >> 7, wn = tid & 127;

  f32x4 acc[4][4];
#pragma unroll
  for (int i = 0; i < 4; ++i)
#pragma unroll
    for (int j = 0; j < 4; ++j) acc[i][j] = (f32x4){0.f, 0.f, 0.f, 0.f};

  // prefetch kt=0
  float4 a0 = *(const float4*)(Ap + 0);
  float4 a1 = *(const float4*)(Ap + 4);
  float4 a2 = *(const float4*)(Ap + 8);
  float4 a3 = *(const float4*)(Ap + 12);
  size_t wo1 = ((size_t)wkb * N + bn + wn) * 8;
  size_t wo2 = ((size_t)(wkb + 2) * N + bn + wn) * 8;
  uint4 w0 = *(const uint4*)(Wh + wo1);
  uint4 w1 = *(const uint4*)(Wh + wo2);
  uint4 w2 = *(const uint4*)(Wl + wo1);
  uint4 w3 = *(const uint4*)(Wl + wo2);

  int nkt = K >> 5;
  for (int kt = 0; kt < nkt; ++kt) {
    // convert A regs -> hi/lo, write LDS; copy W regs -> LDS
    uint4 h0, l0, h1, l1;
    cvt8(a0, a1, h0, l0);
    cvt8(a2, a3, h1, l1);
    *(uint4*)&Ah[(akb0 * 128 + arow) * 8] = h0;
    *(uint4*)&Ah[((akb0 + 1) * 128 + arow) * 8] = h1;
    *(uint4*)&Al[(akb0 * 128 + arow) * 8] = l0;
    *(uint4*)&Al[((akb0 + 1) * 128 + arow) * 8] = l1;
    *(uint4*)&Bh[tid * 8] = w0;
    *(uint4*)&Bh[(tid + 256) * 8] = w1;
    *(uint4*)&Bl[tid * 8] = w2;
    *(uint4*)&Bl[(tid + 256) * 8] = w3;
    __syncthreads();
    // prefetch kt+1 (overlaps MFMA below)
    if (kt + 1 < nkt) {
      const float* Apn = Ap + ((kt + 1) << 5);
      a0 = *(const float4*)(Apn + 0);
      a1 = *(const float4*)(Apn + 4);
      a2 = *(const float4*)(Apn + 8);
      a3 = *(const float4*)(Apn + 12);
      size_t b1 = ((size_t)((kt + 1) * 4 + wkb) * N + bn + wn) * 8;
      size_t b2 = ((size_t)((kt + 1) * 4 + wkb + 2) * N + bn + wn) * 8;
      w0 = *(const uint4*)(Wh + b1);
      w1 = *(const uint4*)(Wh + b2);
      w2 = *(const uint4*)(Wl + b1);
      w3 = *(const uint4*)(Wl + b2);
    }
    // fragments + MFMA
    bf16x8 ahf[4], alf[4];
#pragma unroll
    for (int fm = 0; fm < 4; ++fm) {
      int ci = l4 * 128 + wr * 64 + fm * 16 + l15;
      ahf[fm] = *(bf16x8*)&Ah[ci * 8];
      alf[fm] = *(bf16x8*)&Al[ci * 8];
    }
#pragma unroll
    for (int fn = 0; fn < 4; ++fn) {
      int ci = l4 * 128 + wc * 64 + fn * 16 + l15;
      bf16x8 bh = *(bf16x8*)&Bh[ci * 8];
      bf16x8 bl = *(bf16x8*)&Bl[ci * 8];
#pragma unroll
      for (int fm = 0; fm < 4; ++fm) {
        acc[fm][fn] = __builtin_amdgcn_mfma_f32_16x16x32_bf16(alf[fm], bh, acc[fm][fn], 0, 0, 0);
        acc[fm][fn] = __builtin_amdgcn_mfma_f32_16x16x32_bf16(ahf[fm], bl, acc[fm][fn], 0, 0, 0);
        acc[fm][fn] = __builtin_amdgcn_mfma_f32_16x16x32_bf16(ahf[fm], bh, acc[fm][fn], 0, 0, 0);
      }
    }
    __syncthreads();
  }

  // epilogue: D[row][col], row=(lane>>4)*4+r, col=lane&15 within fragment.
#pragma unroll
  for (int fn = 0; fn < 4; ++fn) {
    int col = bn + wc * 64 + fn * 16 + l15;
    float bv = bias[col];
    float gv = (EPI == 3) ? gamma[col] : 0.f;
#pragma unroll
    for (int fm = 0; fm < 4; ++fm) {
      int row0 = bm + wr * 64 + fm * 16 + l4 * 4;
#pragma unroll
      for (int r = 0; r < 4; ++r) {
        float v = acc[fm][fn][r] + bv;
        if (EPI == 1) v = fmaxf(v, 0.f);
        else if (EPI == 2) v = gelu_f(v);
        else if (EPI == 3) v = resid[(size_t)(row0 + r) * N + col] + gv * v;
        C[(size_t)(row0 + r) * N + col] = v;
      }
    }
  }
}

// ---------------------------------------------------------------------------
// Positional-embedding add (unchanged).
// ---------------------------------------------------------------------------
__global__ __launch_bounds__(256)
void pe_add(const float* __restrict__ centers, const float* __restrict__ ew,
            const float* __restrict__ eb, float* x) {
  __shared__ float fc[51];
  int c = blockIdx.x, tid = threadIdx.x;
  if (tid < 24) {
    int a = tid >> 3, f = tid & 7;
    float coord = centers[c * 3 + a];
    float p = coord * (float)(M_PI * (double)(1 << f));
    fc[3 + tid] = sinf(p);
    fc[27 + tid] = cosf(p);
  } else if (tid < 27) {
    fc[tid - 24] = centers[c * 3 + (tid - 24)];
  }
  __syncthreads();
  for (int j = tid; j < NDIM; j += 256) {
    float acc = eb[j];
#pragma unroll
    for (int d = 0; d < 51; ++d) acc = fmaf(fc[d], ew[d * NDIM + j], acc);
    x[(size_t)c * NDIM + j] += acc;
  }
}

// ---------------------------------------------------------------------------
// LayerNorm (unchanged).
// ---------------------------------------------------------------------------
__global__ __launch_bounds__(256)
void ln_f32(const float* __restrict__ x, const float* __restrict__ g,
            const float* __restrict__ b, float* __restrict__ y) {
  int row = (blockIdx.x << 2) + (threadIdx.x >> 6);
  int lane = threadIdx.x & 63;
  const float* xr = x + (size_t)row * NDIM;
  float v[6];
#pragma unroll
  for (int i = 0; i < 6; ++i) v[i] = xr[lane + (i << 6)];
  float s = 0.f;
#pragma unroll
  for (int i = 0; i < 6; ++i) s += v[i];
#pragma unroll
  for (int off = 32; off; off >>= 1) s += __shfl_xor(s, off);
  float m = s / 384.f;
  float var = 0.f;
#pragma unroll
  for (int i = 0; i < 6; ++i) { float dd = v[i] - m; var += dd * dd; }
#pragma unroll
  for (int off = 32; off; off >>= 1) var += __shfl_xor(var, off);
  var = var / 384.f;
  float rs = 1.f / sqrtf(var + 1e-6f);
#pragma unroll
  for (int i = 0; i < 6; ++i) {
    int cc = lane + (i << 6);
    y[(size_t)row * NDIM + cc] = (v[i] - m) * rs * g[cc] + b[cc];
  }
}

// ---------------------------------------------------------------------------
// Attention (unchanged).
// ---------------------------------------------------------------------------
__global__ __launch_bounds__(256)
void attn_f32(const float* __restrict__ qkv, float* __restrict__ o) {
  __shared__ float qT[64][68];
  __shared__ float kT[64][68];
  __shared__ float vS[64][68];
  __shared__ float sS[64][68];
  __shared__ float mS[64], lS[64], fS[64];
  int bi = blockIdx.x;
  int qt = bi & 7;
  int hh = (bi >> 3) % 6;
  int b = bi / 48;
  int tid = threadIdx.x;
  const float* qbase = qkv + (size_t)(b * NCTR) * 1152;
  {
    int r = tid >> 2, dg = (tid & 3) << 4;
    const float* qp = qbase + (size_t)(qt * 64 + r) * 1152 + hh * 64 + dg;
#pragma unroll
    for (int i = 0; i < 4; ++i) {
      float4 v4 = *(const float4*)(qp + (i << 2));
      qT[dg + (i << 2) + 0][r] = v4.x;
      qT[dg + (i << 2) + 1][r] = v4.y;
      qT[dg + (i << 2) + 2][r] = v4.z;
      qT[dg + (i << 2) + 3][r] = v4.w;
    }
  }
  if (tid < 64) { mS[tid] = -INFINITY; lS[tid] = 0.f; }
  float oacc[4][4] = {{0.f}};
  int ty = tid >> 4, tx = tid & 15;
  for (int ch = 0; ch < 8; ++ch) {
    __syncthreads();
    {
      int r = tid >> 2, dg = (tid & 3) << 4;
      const float* kp = qbase + (size_t)(ch * 64 + r) * 1152 + 384 + hh * 64 + dg;
      const float* vp = qbase + (size_t)(ch * 64 + r) * 1152 + 768 + hh * 64 + dg;
#pragma unroll
      for (int i = 0; i < 4; ++i) {
        float4 v4 = *(const float4*)(kp + (i << 2));
        kT[dg + (i << 2) + 0][r] = v4.x;
        kT[dg + (i << 2) + 1][r] = v4.y;
        kT[dg + (i << 2) + 2][r] = v4.z;
        kT[dg + (i << 2) + 3][r] = v4.w;
      }
#pragma unroll
      for (int i = 0; i < 4; ++i) {
        *(float4*)&vS[r][dg + (i << 2)] = *(const float4*)(vp + (i << 2));
      }
    }
    __syncthreads();
    float sacc[4][4] = {{0.f}};
    for (int dd = 0; dd < 64; ++dd) {
      float4 a = *(const float4*)&qT[dd][ty << 2];
      float4 w = *(const float4*)&kT[dd][tx << 2];
      sacc[0][0] = fmaf(a.x, w.x, sacc[0][0]); sacc[0][1] = fmaf(a.x, w.y, sacc[0][1]);
      sacc[0][2] = fmaf(a.x, w.z, sacc[0][2]); sacc[0][3] = fmaf(a.x, w.w, sacc[0][3]);
      sacc[1][0] = fmaf(a.y, w.x, sacc[1][0]); sacc[1][1] = fmaf(a.y, w.y, sacc[1][1]);
      sacc[1][2] = fmaf(a.y, w.z, sacc[1][2]); sacc[1][3] = fmaf(a.y, w.w, sacc[1][3]);
      sacc[2][0] = fmaf(a.z, w.x, sacc[2][0]); sacc[2][1] = fmaf(a.z, w.y, sacc[2][1]);
      sacc[2][2] = fmaf(a.z, w.z, sacc[2][2]); sacc[2][3] = fmaf(a.z, w.w, sacc[2][3]);
      sacc[3][0] = fmaf(a.w, w.x, sacc[3][0]); sacc[3][1] = fmaf(a.w, w.y, sacc[3][1]);
      sacc[3][2] = fmaf(a.w, w.z, sacc[3][2]); sacc[3][3] = fmaf(a.w, w.w, sacc[3][3]);
    }
#pragma unroll
    for (int i = 0; i < 4; ++i) {
      float4 sv;
      sv.x = sacc[i][0] * 0.125f; sv.y = sacc[i][1] * 0.125f;
      sv.z = sacc[i][2] * 0.125f; sv.w = sacc[i][3] * 0.125f;
      *(float4*)&sS[(ty << 2) + i][tx << 2] = sv;
    }
    __syncthreads();
    {
      int r = tid >> 2, gg = tid & 3;
      float vals[16];
      float vmax = -INFINITY;
#pragma unroll
      for (int i = 0; i < 4; ++i) {
        float4 p4 = *(const float4*)&sS[r][(gg << 4) + (i << 2)];
        vals[4 * i + 0] = p4.x; vals[4 * i + 1] = p4.y;
        vals[4 * i + 2] = p4.z; vals[4 * i + 3] = p4.w;
        vmax = fmaxf(vmax, fmaxf(fmaxf(p4.x, p4.y), fmaxf(p4.z, p4.w)));
      }
      vmax = fmaxf(vmax, __shfl_xor(vmax, 1));
      vmax = fmaxf(vmax, __shfl_xor(vmax, 2));
      float mold = mS[r];
      float mnew = fmaxf(mold, vmax);
      float sum = 0.f;
#pragma unroll
      for (int i = 0; i < 16; ++i) {
        float p = expf(vals[i] - mnew);
        vals[i] = p;
        sum += p;
      }
#pragma unroll
      for (int i = 0; i < 4; ++i) {
        float4 p4;
        p4.x = vals[4 * i + 0]; p4.y = vals[4 * i + 1];
        p4.z = vals[4 * i + 2]; p4.w = vals[4 * i + 3];
        *(float4*)&sS[r][(gg << 4) + (i << 2)] = p4;
      }
      sum += __shfl_xor(sum, 1);
      sum += __shfl_xor(sum, 2);
      if (gg == 0) {
        float f = expf(mold - mnew);
        fS[r] = f;
        mS[r] = mnew;
        lS[r] = lS[r] * f + sum;
      }
    }
    __syncthreads();
    {
      float f0 = fS[(ty << 2) + 0], f1 = fS[(ty << 2) + 1];
      float f2 = fS[(ty << 2) + 2], f3 = fS[(ty << 2) + 3];
#pragma unroll
      for (int j = 0; j < 4; ++j) {
        oacc[0][j] *= f0; oacc[1][j] *= f1; oacc[2][j] *= f2; oacc[3][j] *= f3;
      }
      for (int jj = 0; jj < 64; ++jj) {
        float4 vv = *(const float4*)&vS[jj][tx << 2];
        float p0 = sS[(ty << 2) + 0][jj];
        float p1 = sS[(ty << 2) + 1][jj];
        float p2 = sS[(ty << 2) + 2][jj];
        float p3 = sS[(ty << 2) + 3][jj];
        oacc[0][0] = fmaf(p0, vv.x, oacc[0][0]); oacc[0][1] = fmaf(p0, vv.y, oacc[0][1]);
        oacc[0][2] = fmaf(p0, vv.z, oacc[0][2]); oacc[0][3] = fmaf(p0, vv.w, oacc[0][3]);
        oacc[1][0] = fmaf(p1, vv.x, oacc[1][0]); oacc[1][1] = fmaf(p1, vv.y, oacc[1][1]);
        oacc[1][2] = fmaf(p1, vv.z, oacc[1][2]); oacc[1][3] = fmaf(p1, vv.w, oacc[1][3]);
        oacc[2][0] = fmaf(p2, vv.x, oacc[2][0]); oacc[2][1] = fmaf(p2, vv.y, oacc[2][1]);
        oacc[2][2] = fmaf(p2, vv.z, oacc[2][2]); oacc[2][3] = fmaf(p2, vv.w, oacc[2][3]);
        oacc[3][0] = fmaf(p3, vv.x, oacc[3][0]); oacc[3][1] = fmaf(p3, vv.y, oacc[3][1]);
        oacc[3][2] = fmaf(p3, vv.z, oacc[3][2]); oacc[3][3] = fmaf(p3, vv.w, oacc[3][3]);
      }
    }
  }
  __syncthreads();
  {
    float il[4];
#pragma unroll
    for (int i = 0; i < 4; ++i) il[i] = 1.f / lS[(ty << 2) + i];
#pragma unroll
    for (int i = 0; i < 4; ++i) {
      int row = b * NCTR + qt * 64 + (ty << 2) + i;
      float4 ov;
      ov.x = oacc[i][0] * il[i]; ov.y = oacc[i][1] * il[i];
      ov.z = oacc[i][2] * il[i]; ov.w = oacc[i][3] * il[i];
      *(float4*)(o + (size_t)row * NDIM + hh * 64 + (tx << 2)) = ov;
    }
  }
}

// ---------------------------------------------------------------------------
extern "C" void kernel_launch(void* const* d_in, const int* in_sizes, int n_in,
                              void* d_out, int out_size, void* d_ws, size_t ws_size,
                              hipStream_t stream) {
  const float* pc      = (const float*)d_in[0];
  const float* embed_w = (const float*)d_in[1];
  const float* embed_b = (const float*)d_in[2];
  const float* lw1     = (const float*)d_in[3];
  const float* lb1     = (const float*)d_in[4];
  const float* lw2     = (const float*)d_in[5];
  const float* lb2     = (const float*)d_in[6];
  const float* gw1     = (const float*)d_in[7];
  const float* gb1     = (const float*)d_in[8];
  const float* gw2     = (const float*)d_in[9];
  const float* gb2     = (const float*)d_in[10];
  const float* ln1_g   = (const float*)d_in[11];
  const float* ln1_b   = (const float*)d_in[12];
  const float* qkv_w   = (const float*)d_in[13];
  const float* qkv_b   = (const float*)d_in[14];
  const float* proj_w  = (const float*)d_in[15];
  const float* proj_b  = (const float*)d_in[16];
  const float* gamma1  = (const float*)d_in[17];
  const float* ln2_g   = (const float*)d_in[18];
  const float* ln2_b   = (const float*)d_in[19];
  const float* fc1_w   = (const float*)d_in[20];
  const float* fc1_b   = (const float*)d_in[21];
  const float* fc2_w   = (const float*)d_in[22];
  const float* fc2_b   = (const float*)d_in[23];
  const float* gamma2  = (const float*)d_in[24];
  const float* lnf_g   = (const float*)d_in[25];
  const float* lnf_b   = (const float*)d_in[26];

  float* out = (float*)d_out;
  float* centers = out + (size_t)NB * NCTR * NDIM;

  int* nn = (int*)d_ws;
  float* fws = (float*)d_ws;
  float* h  = fws + 262144;            // [8192,256]
  float* x  = h + 8192 * 256;          // [8192,384]
  float* xn = x + 8192 * 384;          // [8192,384]
  float* F  = xn + 8192 * 384;         // [8192,1536]
  ushort* wsplit = (ushort*)(fws + 21233664);  // byte ofs 84,934,656

  // --- weight pre-split (bf16 hi/lo, MFMA layout) ---
  size_t wofs = 0;
  ushort* qkvH[6]; ushort* projH[6]; ushort* fc1H[6]; ushort* fc2H[6];
  auto convm = [&](const float* w, int K, int N) -> ushort* {
    ushort* dst = wsplit + wofs;
    int K8 = K >> 3, total = K8 * N;
    wconv<<<(total + 255) / 256, 256, 0, stream>>>(w, dst, K8, N);
    wofs += (size_t)2 * K * N;
    return dst;
  };
  for (int l = 0; l < 6; ++l) qkvH[l] = convm(qkv_w + (size_t)l * 384 * 1152, 384, 1152);
  for (int l = 0; l < 6; ++l) projH[l] = convm(proj_w + (size_t)l * 384 * 384, 384, 384);
  for (int l = 0; l < 6; ++l) fc1H[l] = convm(fc1_w + (size_t)l * 384 * 1536, 384, 1536);
  for (int l = 0; l < 6; ++l) fc2H[l] = convm(fc2_w + (size_t)l * 1536 * 384, 1536, 384);
  ushort* g1H = convm(gw1, 256, 256);
  ushort* g2H = convm(gw2, 256, 384);

  // --- geometry + edge pipeline ---
  fps_kernel<<<NB, 512, 0, stream>>>(pc, centers);
  knn_kernel<<<2048, 256, 0, stream>>>(pc, centers, nn);
  edge_mlp<<<8192, 256, 0, stream>>>(pc, centers, nn, lw1, lb1, lw2, lb2, h);

  gemm_x3<1><<<dim3(2, 64), 256, 0, stream>>>(h, g1H, g1H + 256 * 256, gb1,
                                              nullptr, nullptr, xn, 8192, 256, 256);
  gemm_x3<0><<<dim3(3, 64), 256, 0, stream>>>(xn, g2H, g2H + 256 * 384, gb2,
                                              nullptr, nullptr, x, 8192, 384, 256);
  pe_add<<<8192, 256, 0, stream>>>(centers, embed_w, embed_b, x);

  for (int l = 0; l < 6; ++l) {
    ln_f32<<<2048, 256, 0, stream>>>(x, ln1_g + l * 384, ln1_b + l * 384, xn);
    gemm_x3<0><<<dim3(9, 64), 256, 0, stream>>>(
        xn, qkvH[l], qkvH[l] + 384 * 1152, qkv_b + l * 1152, nullptr, nullptr, F,
        8192, 1152, 384);
    attn_f32<<<768, 256, 0, stream>>>(F, xn);
    gemm_x3<3><<<dim3(3, 64), 256, 0, stream>>>(
        xn, projH[l], projH[l] + 384 * 384, proj_b + l * 384, gamma1 + l * 384, x, x,
        8192, 384, 384);
    ln_f32<<<2048, 256, 0, stream>>>(x, ln2_g + l * 384, ln2_b + l * 384, xn);
    gemm_x3<2><<<dim3(12, 64), 256, 0, stream>>>(
        xn, fc1H[l], fc1H[l] + 384 * 1536, fc1_b + l * 1536, nullptr, nullptr, F,
        8192, 1536, 384);
    gemm_x3<3><<<dim3(3, 64), 256, 0, stream>>>(
        F, fc2H[l], fc2H[l] + 1536 * 384, fc2_b + l * 384, gamma2 + l * 384, x, x,
        8192, 384, 1536);
  }
  ln_f32<<<2048, 256, 0, stream>>>(x, lnf_g, lnf_b, out);
}

// Round 4
// 2606.322 us; speedup vs baseline: 1.7657x; 1.1538x over previous
//
#include <hip/hip_runtime.h>
#include <math.h>

#define NB 16
#define NM 2048
#define NCTR 512
#define NK 32
#define NDIM 384

typedef unsigned long long ull;
typedef unsigned int uint;
typedef unsigned short ushort;
typedef __attribute__((ext_vector_type(8))) short bf16x8;
typedef __attribute__((ext_vector_type(4))) float f32x4;

// Exact (no-FMA-contraction) squared distance, matching XLA's per-op fp32.
__device__ __forceinline__ float dist2_exact(float ax, float ay, float az,
                                             float bx, float by, float bz) {
  float dx = __fsub_rn(ax, bx);
  float dy = __fsub_rn(ay, by);
  float dz = __fsub_rn(az, bz);
  return __fadd_rn(__fadd_rn(__fmul_rn(dx, dx), __fmul_rn(dy, dy)),
                   __fmul_rn(dz, dz));
}

__device__ __forceinline__ float gelu_f(float x) {
  return 0.5f * x * (1.0f + erff(x * 0.70710678118654752f));
}

// fp32 -> bf16 round-to-nearest-even (bit trick), and back.
__device__ __forceinline__ ushort f2bf(float f) {
  uint u = __float_as_uint(f);
  return (ushort)((u + 0x7FFFu + ((u >> 16) & 1u)) >> 16);
}
__device__ __forceinline__ float bf2f(ushort h) {
  return __uint_as_float(((uint)h) << 16);
}

// Split 8 fp32 into bf16 hi / lo packed words (2 bf16 per uint).
__device__ __forceinline__ void cvt8(float4 p, float4 q, uint4& hi, uint4& lo) {
  float v0 = p.x, v1 = p.y, v2 = p.z, v3 = p.w;
  float v4 = q.x, v5 = q.y, v6 = q.z, v7 = q.w;
  ushort h0 = f2bf(v0), h1 = f2bf(v1), h2 = f2bf(v2), h3 = f2bf(v3);
  ushort h4 = f2bf(v4), h5 = f2bf(v5), h6 = f2bf(v6), h7 = f2bf(v7);
  ushort l0 = f2bf(v0 - bf2f(h0)), l1 = f2bf(v1 - bf2f(h1));
  ushort l2 = f2bf(v2 - bf2f(h2)), l3 = f2bf(v3 - bf2f(h3));
  ushort l4 = f2bf(v4 - bf2f(h4)), l5 = f2bf(v5 - bf2f(h5));
  ushort l6 = f2bf(v6 - bf2f(h6)), l7 = f2bf(v7 - bf2f(h7));
  hi.x = (uint)h0 | ((uint)h1 << 16); hi.y = (uint)h2 | ((uint)h3 << 16);
  hi.z = (uint)h4 | ((uint)h5 << 16); hi.w = (uint)h6 | ((uint)h7 << 16);
  lo.x = (uint)l0 | ((uint)l1 << 16); lo.y = (uint)l2 | ((uint)l3 << 16);
  lo.z = (uint)l4 | ((uint)l5 << 16); lo.w = (uint)l6 | ((uint)l7 << 16);
}

// ---------------------------------------------------------------------------
// FPS (exact argmax semantics).
// ---------------------------------------------------------------------------
__global__ __launch_bounds__(512)
void fps_kernel(const float* __restrict__ pc, float* __restrict__ centers) {
  int b = blockIdx.x;
  __shared__ float pos[NM * 3];
  __shared__ ull red[2][8];
  const float* pb = pc + (size_t)b * (NM * 3);
  for (int i = threadIdx.x; i < NM * 3; i += 512) pos[i] = pb[i];
  __syncthreads();
  int tid = threadIdx.x, lane = tid & 63, wv = tid >> 6;
  float* cb = centers + (size_t)b * (NCTR * 3);
  float sx = pos[0], sy = pos[1], sz = pos[2];
  if (tid == 0) { cb[0] = sx; cb[1] = sy; cb[2] = sz; }
  float d[4];
  for (int n = 1; n < NCTR; ++n) {
    ull best = 0;
#pragma unroll
    for (int i = 0; i < 4; ++i) {
      int p = tid + 512 * i;
      float nd = dist2_exact(pos[3 * p], pos[3 * p + 1], pos[3 * p + 2], sx, sy, sz);
      d[i] = (n == 1) ? nd : fminf(d[i], nd);
      ull key = ((ull)__float_as_uint(d[i]) << 32) | (unsigned)(0x7FFFFFFF - p);
      best = best > key ? best : key;
    }
#pragma unroll
    for (int off = 32; off; off >>= 1) {
      ull o = __shfl_xor(best, off);
      best = best > o ? best : o;
    }
    if (lane == 0) red[n & 1][wv] = best;
    __syncthreads();
    ull gb = red[n & 1][0];
#pragma unroll
    for (int w = 1; w < 8; ++w) {
      ull o = red[n & 1][w];
      gb = gb > o ? gb : o;
    }
    int j = 0x7FFFFFFF - (int)(unsigned)(gb & 0xFFFFFFFFull);
    sx = pos[3 * j]; sy = pos[3 * j + 1]; sz = pos[3 * j + 2];
    if (tid == 0) { cb[n * 3] = sx; cb[n * 3 + 1] = sy; cb[n * 3 + 2] = sz; }
  }
}

// ---------------------------------------------------------------------------
// KNN (unchanged).
// ---------------------------------------------------------------------------
__global__ __launch_bounds__(256)
void knn_kernel(const float* __restrict__ pc, const float* __restrict__ centers,
                int* __restrict__ nn) {
  __shared__ float pos[NM * 3];
  int b = blockIdx.x >> 7;
  int n0 = (blockIdx.x & 127) << 2;
  const float* pb = pc + (size_t)b * (NM * 3);
  for (int i = threadIdx.x; i < NM * 3; i += 256) pos[i] = pb[i];
  __syncthreads();
  int wv = threadIdx.x >> 6, lane = threadIdx.x & 63;
  int gc = b * NCTR + n0 + wv;
  float cx = centers[gc * 3], cy = centers[gc * 3 + 1], cz = centers[gc * 3 + 2];
  ull key[32];
  ull lmin = ~0ull;
#pragma unroll
  for (int r = 0; r < 32; ++r) {
    int p = lane + (r << 6);
    float nd = dist2_exact(pos[3 * p], pos[3 * p + 1], pos[3 * p + 2], cx, cy, cz);
    key[r] = ((ull)__float_as_uint(nd) << 11) | (unsigned)p;
    lmin = lmin < key[r] ? lmin : key[r];
  }
  int* nnc = nn + (size_t)gc * NK;
  for (int round = 0; round < NK; ++round) {
    ull w = lmin;
#pragma unroll
    for (int off = 32; off; off >>= 1) {
      ull o = __shfl_xor(w, off);
      w = w < o ? w : o;
    }
    if (lmin == w) {
      nnc[round] = (int)(w & 2047ull);
      lmin = ~0ull;
#pragma unroll
      for (int r = 0; r < 32; ++r) {
        key[r] = (key[r] == w) ? ~0ull : key[r];
        lmin = lmin < key[r] ? lmin : key[r];
      }
    }
  }
}

// ---------------------------------------------------------------------------
// Weight pre-split: W[Ksrc,N] fp32 -> hi/lo bf16 in MFMA layout, K padded to
// K8*8 rows (rows >= Ksrc are zero). dst[((k>>3)*N + n)*8 + (k&7)]; lo block
// at dst + K8*8*N elements.
// ---------------------------------------------------------------------------
__global__ __launch_bounds__(256)
void wconv(const float* __restrict__ W, ushort* __restrict__ out, int K8, int N,
           int Ksrc) {
  int c = blockIdx.x * 256 + threadIdx.x;
  if (c >= K8 * N) return;
  int kb = c / N, n = c - kb * N;
  float v[8];
#pragma unroll
  for (int i = 0; i < 8; ++i) {
    int row = kb * 8 + i;
    v[i] = (row < Ksrc) ? W[(size_t)row * N + n] : 0.f;
  }
  float4 p, q;
  p.x = v[0]; p.y = v[1]; p.z = v[2]; p.w = v[3];
  q.x = v[4]; q.y = v[5]; q.z = v[6]; q.w = v[7];
  uint4 hi, lo;
  cvt8(p, q, hi, lo);
  *(uint4*)(out + (size_t)c * 8) = hi;
  *(uint4*)(out + (size_t)(K8 * N + c) * 8) = lo;
}

// ---------------------------------------------------------------------------
// Fused edge pipeline with MFMA (bf16x3 split == fp32-equivalent):
// per block: 64 edges (2 centers), 4 waves.
//   1. gather + fourier features -> feat[64 e][64 k] bf16 hi/lo in LDS
//   2. GEMM1: t1 = relu(feat @ lw1 + lb1)  [64,256], re-split to LDS
//   3. GEMM2: o = t1 @ lw2                 [64,256], B frags direct from L2
//   4. max over 32 edge-rows per center (+lb2) -> h[center][256]
// Wave w owns output chans [64w, 64w+64): acc 4x4 fragments.
// ---------------------------------------------------------------------------
__global__ __launch_bounds__(256, 2)
void edge_mfma(const float* __restrict__ pc, const float* __restrict__ centers,
               const int* __restrict__ nn, const ushort* __restrict__ lw1s,
               const float* __restrict__ lb1, const ushort* __restrict__ lw2s,
               const float* __restrict__ lb2, float* __restrict__ h) {
  __shared__ __align__(16) ushort featH[4096], featL[4096];   // [kb8][64][8]
  __shared__ __align__(16) ushort t1H[16384], t1L[16384];     // [kb32][64][8]
  int tid = threadIdx.x;
  int w = tid >> 6, lane = tid & 63;
  int l15 = lane & 15, l4 = lane >> 4;
  int wbase = w << 6;

  // ---- 1. features ----
  {
    int e = tid >> 2, s = tid & 3;
    int ge = blockIdx.x * 64 + e;
    int c = ge >> 5;
    int b = c >> 9;
    int j = nn[ge];
    const float* sp = pc + ((size_t)b * NM + j) * 3;
    float rx = sp[0] - centers[c * 3];
    float ry = sp[1] - centers[c * 3 + 1];
    float rz = sp[2] - centers[c * 3 + 2];
    auto putk = [&](int k, float v) {
      ushort hi = f2bf(v);
      ushort lo = f2bf(v - bf2f(hi));
      int idx = ((k >> 3) * 64 + e) * 8 + (k & 7);
      featH[idx] = hi;
      featL[idx] = lo;
    };
    if (s < 3) {
      float r = (s == 0) ? rx : (s == 1) ? ry : rz;
#pragma unroll
      for (int f = 0; f < 8; ++f) {
        float ef = (float)(M_PI * (double)(1 << f));
        float p = r * ef;
        putk(3 + 8 * s + f, sinf(p));
        putk(27 + 8 * s + f, cosf(p));
      }
    } else {
      putk(0, rx);
      putk(1, ry);
      putk(2, rz);
#pragma unroll
      for (int k = 51; k < 64; ++k) putk(k, 0.f);
    }
  }
  __syncthreads();

  // ---- 2. GEMM1: [64,64] @ [64,256] -> wave's [64, 64] chan slice ----
  const ushort* lw1H = lw1s;
  const ushort* lw1L = lw1s + 8 * 256 * 8;
  f32x4 acc1[4][4];
#pragma unroll
  for (int i = 0; i < 4; ++i)
#pragma unroll
    for (int j = 0; j < 4; ++j) acc1[i][j] = (f32x4){0.f, 0.f, 0.f, 0.f};
#pragma unroll
  for (int ks = 0; ks < 2; ++ks) {
    bf16x8 ah[4], al[4];
#pragma unroll
    for (int fm = 0; fm < 4; ++fm) {
      int idx = ((ks * 4 + l4) * 64 + fm * 16 + l15) * 8;
      ah[fm] = *(const bf16x8*)&featH[idx];
      al[fm] = *(const bf16x8*)&featL[idx];
    }
#pragma unroll
    for (int fn = 0; fn < 4; ++fn) {
      int col = wbase + fn * 16 + l15;
      size_t boff = ((size_t)(ks * 4 + l4) * 256 + col) * 8;
      bf16x8 bh = *(const bf16x8*)(lw1H + boff);
      bf16x8 bl = *(const bf16x8*)(lw1L + boff);
#pragma unroll
      for (int fm = 0; fm < 4; ++fm) {
        acc1[fm][fn] = __builtin_amdgcn_mfma_f32_16x16x32_bf16(al[fm], bh, acc1[fm][fn], 0, 0, 0);
        acc1[fm][fn] = __builtin_amdgcn_mfma_f32_16x16x32_bf16(ah[fm], bl, acc1[fm][fn], 0, 0, 0);
        acc1[fm][fn] = __builtin_amdgcn_mfma_f32_16x16x32_bf16(ah[fm], bh, acc1[fm][fn], 0, 0, 0);
      }
    }
  }
  // bias + relu + split -> t1 LDS ([kb][edge][8] layout)
#pragma unroll
  for (int fn = 0; fn < 4; ++fn) {
    int chan = wbase + fn * 16 + l15;
    float bias = lb1[chan];
    int kb = chan >> 3, k7 = chan & 7;
#pragma unroll
    for (int fm = 0; fm < 4; ++fm) {
#pragma unroll
      for (int r = 0; r < 4; ++r) {
        int edge = fm * 16 + l4 * 4 + r;
        float v = fmaxf(acc1[fm][fn][r] + bias, 0.f);
        ushort hi = f2bf(v);
        ushort lo = f2bf(v - bf2f(hi));
        int idx = (kb * 64 + edge) * 8 + k7;
        t1H[idx] = hi;
        t1L[idx] = lo;
      }
    }
  }
  __syncthreads();

  // ---- 3. GEMM2: [64,256] @ [256,256] -> wave's [64,64] slice ----
  const ushort* lw2H = lw2s;
  const ushort* lw2L = lw2s + 32 * 256 * 8;
  f32x4 acc2[4][4];
#pragma unroll
  for (int i = 0; i < 4; ++i)
#pragma unroll
    for (int j = 0; j < 4; ++j) acc2[i][j] = (f32x4){0.f, 0.f, 0.f, 0.f};
#pragma unroll
  for (int ks = 0; ks < 8; ++ks) {
    bf16x8 ah[4], al[4];
#pragma unroll
    for (int fm = 0; fm < 4; ++fm) {
      int idx = ((ks * 4 + l4) * 64 + fm * 16 + l15) * 8;
      ah[fm] = *(const bf16x8*)&t1H[idx];
      al[fm] = *(const bf16x8*)&t1L[idx];
    }
#pragma unroll
    for (int fn = 0; fn < 4; ++fn) {
      int col = wbase + fn * 16 + l15;
      size_t boff = ((size_t)(ks * 4 + l4) * 256 + col) * 8;
      bf16x8 bh = *(const bf16x8*)(lw2H + boff);
      bf16x8 bl = *(const bf16x8*)(lw2L + boff);
#pragma unroll
      for (int fm = 0; fm < 4; ++fm) {
        acc2[fm][fn] = __builtin_amdgcn_mfma_f32_16x16x32_bf16(al[fm], bh, acc2[fm][fn], 0, 0, 0);
        acc2[fm][fn] = __builtin_amdgcn_mfma_f32_16x16x32_bf16(ah[fm], bl, acc2[fm][fn], 0, 0, 0);
        acc2[fm][fn] = __builtin_amdgcn_mfma_f32_16x16x32_bf16(ah[fm], bh, acc2[fm][fn], 0, 0, 0);
      }
    }
  }

  // ---- 4. max over edge rows per center, +lb2, write h ----
#pragma unroll
  for (int fn = 0; fn < 4; ++fn) {
    int col = wbase + fn * 16 + l15;
    float m0 = -INFINITY, m1 = -INFINITY;
#pragma unroll
    for (int r = 0; r < 4; ++r) {
      m0 = fmaxf(m0, fmaxf(acc2[0][fn][r], acc2[1][fn][r]));
      m1 = fmaxf(m1, fmaxf(acc2[2][fn][r], acc2[3][fn][r]));
    }
    m0 = fmaxf(m0, __shfl_xor(m0, 16));
    m0 = fmaxf(m0, __shfl_xor(m0, 32));
    m1 = fmaxf(m1, __shfl_xor(m1, 16));
    m1 = fmaxf(m1, __shfl_xor(m1, 32));
    if (l4 == 0) {
      float bias = lb2[col];
      int c0 = blockIdx.x * 2;
      h[(size_t)c0 * 256 + col] = m0 + bias;
      h[(size_t)(c0 + 1) * 256 + col] = m1 + bias;
    }
  }
}

// ---------------------------------------------------------------------------
// bf16x3 split MFMA GEMM (unchanged from round 2).
// ---------------------------------------------------------------------------
template <int EPI>
__global__ __launch_bounds__(256, 2)
void gemm_x3(const float* __restrict__ A, const ushort* __restrict__ Wh,
             const ushort* __restrict__ Wl, const float* __restrict__ bias,
             const float* __restrict__ gamma, const float* __restrict__ resid,
             float* __restrict__ C, int M, int N, int K) {
  __shared__ __align__(16) ushort Ah[4096], Al[4096], Bh[4096], Bl[4096];
  int tid = threadIdx.x;
  int bn = blockIdx.x << 7, bm = blockIdx.y << 7;
  int wid = tid >> 6, lane = tid & 63;
  int wr = wid >> 1, wc = wid & 1;
  int l15 = lane & 15, l4 = lane >> 4;

  int arow = tid >> 1, akb0 = (tid & 1) << 1;
  const float* Ap = A + (size_t)(bm + arow) * K + (akb0 << 3);
  int wkb = tid >> 7, wn = tid & 127;

  f32x4 acc[4][4];
#pragma unroll
  for (int i = 0; i < 4; ++i)
#pragma unroll
    for (int j = 0; j < 4; ++j) acc[i][j] = (f32x4){0.f, 0.f, 0.f, 0.f};

  float4 a0 = *(const float4*)(Ap + 0);
  float4 a1 = *(const float4*)(Ap + 4);
  float4 a2 = *(const float4*)(Ap + 8);
  float4 a3 = *(const float4*)(Ap + 12);
  size_t wo1 = ((size_t)wkb * N + bn + wn) * 8;
  size_t wo2 = ((size_t)(wkb + 2) * N + bn + wn) * 8;
  uint4 w0 = *(const uint4*)(Wh + wo1);
  uint4 w1 = *(const uint4*)(Wh + wo2);
  uint4 w2 = *(const uint4*)(Wl + wo1);
  uint4 w3 = *(const uint4*)(Wl + wo2);

  int nkt = K >> 5;
  for (int kt = 0; kt < nkt; ++kt) {
    uint4 h0, l0, h1, l1;
    cvt8(a0, a1, h0, l0);
    cvt8(a2, a3, h1, l1);
    *(uint4*)&Ah[(akb0 * 128 + arow) * 8] = h0;
    *(uint4*)&Ah[((akb0 + 1) * 128 + arow) * 8] = h1;
    *(uint4*)&Al[(akb0 * 128 + arow) * 8] = l0;
    *(uint4*)&Al[((akb0 + 1) * 128 + arow) * 8] = l1;
    *(uint4*)&Bh[tid * 8] = w0;
    *(uint4*)&Bh[(tid + 256) * 8] = w1;
    *(uint4*)&Bl[tid * 8] = w2;
    *(uint4*)&Bl[(tid + 256) * 8] = w3;
    __syncthreads();
    if (kt + 1 < nkt) {
      const float* Apn = Ap + ((kt + 1) << 5);
      a0 = *(const float4*)(Apn + 0);
      a1 = *(const float4*)(Apn + 4);
      a2 = *(const float4*)(Apn + 8);
      a3 = *(const float4*)(Apn + 12);
      size_t b1 = ((size_t)((kt + 1) * 4 + wkb) * N + bn + wn) * 8;
      size_t b2 = ((size_t)((kt + 1) * 4 + wkb + 2) * N + bn + wn) * 8;
      w0 = *(const uint4*)(Wh + b1);
      w1 = *(const uint4*)(Wh + b2);
      w2 = *(const uint4*)(Wl + b1);
      w3 = *(const uint4*)(Wl + b2);
    }
    bf16x8 ahf[4], alf[4];
#pragma unroll
    for (int fm = 0; fm < 4; ++fm) {
      int ci = l4 * 128 + wr * 64 + fm * 16 + l15;
      ahf[fm] = *(bf16x8*)&Ah[ci * 8];
      alf[fm] = *(bf16x8*)&Al[ci * 8];
    }
#pragma unroll
    for (int fn = 0; fn < 4; ++fn) {
      int ci = l4 * 128 + wc * 64 + fn * 16 + l15;
      bf16x8 bh = *(bf16x8*)&Bh[ci * 8];
      bf16x8 bl = *(bf16x8*)&Bl[ci * 8];
#pragma unroll
      for (int fm = 0; fm < 4; ++fm) {
        acc[fm][fn] = __builtin_amdgcn_mfma_f32_16x16x32_bf16(alf[fm], bh, acc[fm][fn], 0, 0, 0);
        acc[fm][fn] = __builtin_amdgcn_mfma_f32_16x16x32_bf16(ahf[fm], bl, acc[fm][fn], 0, 0, 0);
        acc[fm][fn] = __builtin_amdgcn_mfma_f32_16x16x32_bf16(ahf[fm], bh, acc[fm][fn], 0, 0, 0);
      }
    }
    __syncthreads();
  }

#pragma unroll
  for (int fn = 0; fn < 4; ++fn) {
    int col = bn + wc * 64 + fn * 16 + l15;
    float bv = bias[col];
    float gv = (EPI == 3) ? gamma[col] : 0.f;
#pragma unroll
    for (int fm = 0; fm < 4; ++fm) {
      int row0 = bm + wr * 64 + fm * 16 + l4 * 4;
#pragma unroll
      for (int r = 0; r < 4; ++r) {
        float v = acc[fm][fn][r] + bv;
        if (EPI == 1) v = fmaxf(v, 0.f);
        else if (EPI == 2) v = gelu_f(v);
        else if (EPI == 3) v = resid[(size_t)(row0 + r) * N + col] + gv * v;
        C[(size_t)(row0 + r) * N + col] = v;
      }
    }
  }
}

// ---------------------------------------------------------------------------
// Positional-embedding add (unchanged).
// ---------------------------------------------------------------------------
__global__ __launch_bounds__(256)
void pe_add(const float* __restrict__ centers, const float* __restrict__ ew,
            const float* __restrict__ eb, float* x) {
  __shared__ float fc[51];
  int c = blockIdx.x, tid = threadIdx.x;
  if (tid < 24) {
    int a = tid >> 3, f = tid & 7;
    float coord = centers[c * 3 + a];
    float p = coord * (float)(M_PI * (double)(1 << f));
    fc[3 + tid] = sinf(p);
    fc[27 + tid] = cosf(p);
  } else if (tid < 27) {
    fc[tid - 24] = centers[c * 3 + (tid - 24)];
  }
  __syncthreads();
  for (int j = tid; j < NDIM; j += 256) {
    float acc = eb[j];
#pragma unroll
    for (int d = 0; d < 51; ++d) acc = fmaf(fc[d], ew[d * NDIM + j], acc);
    x[(size_t)c * NDIM + j] += acc;
  }
}

// ---------------------------------------------------------------------------
// LayerNorm (unchanged).
// ---------------------------------------------------------------------------
__global__ __launch_bounds__(256)
void ln_f32(const float* __restrict__ x, const float* __restrict__ g,
            const float* __restrict__ b, float* __restrict__ y) {
  int row = (blockIdx.x << 2) + (threadIdx.x >> 6);
  int lane = threadIdx.x & 63;
  const float* xr = x + (size_t)row * NDIM;
  float v[6];
#pragma unroll
  for (int i = 0; i < 6; ++i) v[i] = xr[lane + (i << 6)];
  float s = 0.f;
#pragma unroll
  for (int i = 0; i < 6; ++i) s += v[i];
#pragma unroll
  for (int off = 32; off; off >>= 1) s += __shfl_xor(s, off);
  float m = s / 384.f;
  float var = 0.f;
#pragma unroll
  for (int i = 0; i < 6; ++i) { float dd = v[i] - m; var += dd * dd; }
#pragma unroll
  for (int off = 32; off; off >>= 1) var += __shfl_xor(var, off);
  var = var / 384.f;
  float rs = 1.f / sqrtf(var + 1e-6f);
#pragma unroll
  for (int i = 0; i < 6; ++i) {
    int cc = lane + (i << 6);
    y[(size_t)row * NDIM + cc] = (v[i] - m) * rs * g[cc] + b[cc];
  }
}

// ---------------------------------------------------------------------------
// Attention (unchanged).
// ---------------------------------------------------------------------------
__global__ __launch_bounds__(256)
void attn_f32(const float* __restrict__ qkv, float* __restrict__ o) {
  __shared__ float qT[64][68];
  __shared__ float kT[64][68];
  __shared__ float vS[64][68];
  __shared__ float sS[64][68];
  __shared__ float mS[64], lS[64], fS[64];
  int bi = blockIdx.x;
  int qt = bi & 7;
  int hh = (bi >> 3) % 6;
  int b = bi / 48;
  int tid = threadIdx.x;
  const float* qbase = qkv + (size_t)(b * NCTR) * 1152;
  {
    int r = tid >> 2, dg = (tid & 3) << 4;
    const float* qp = qbase + (size_t)(qt * 64 + r) * 1152 + hh * 64 + dg;
#pragma unroll
    for (int i = 0; i < 4; ++i) {
      float4 v4 = *(const float4*)(qp + (i << 2));
      qT[dg + (i << 2) + 0][r] = v4.x;
      qT[dg + (i << 2) + 1][r] = v4.y;
      qT[dg + (i << 2) + 2][r] = v4.z;
      qT[dg + (i << 2) + 3][r] = v4.w;
    }
  }
  if (tid < 64) { mS[tid] = -INFINITY; lS[tid] = 0.f; }
  float oacc[4][4] = {{0.f}};
  int ty = tid >> 4, tx = tid & 15;
  for (int ch = 0; ch < 8; ++ch) {
    __syncthreads();
    {
      int r = tid >> 2, dg = (tid & 3) << 4;
      const float* kp = qbase + (size_t)(ch * 64 + r) * 1152 + 384 + hh * 64 + dg;
      const float* vp = qbase + (size_t)(ch * 64 + r) * 1152 + 768 + hh * 64 + dg;
#pragma unroll
      for (int i = 0; i < 4; ++i) {
        float4 v4 = *(const float4*)(kp + (i << 2));
        kT[dg + (i << 2) + 0][r] = v4.x;
        kT[dg + (i << 2) + 1][r] = v4.y;
        kT[dg + (i << 2) + 2][r] = v4.z;
        kT[dg + (i << 2) + 3][r] = v4.w;
      }
#pragma unroll
      for (int i = 0; i < 4; ++i) {
        *(float4*)&vS[r][dg + (i << 2)] = *(const float4*)(vp + (i << 2));
      }
    }
    __syncthreads();
    float sacc[4][4] = {{0.f}};
    for (int dd = 0; dd < 64; ++dd) {
      float4 a = *(const float4*)&qT[dd][ty << 2];
      float4 w = *(const float4*)&kT[dd][tx << 2];
      sacc[0][0] = fmaf(a.x, w.x, sacc[0][0]); sacc[0][1] = fmaf(a.x, w.y, sacc[0][1]);
      sacc[0][2] = fmaf(a.x, w.z, sacc[0][2]); sacc[0][3] = fmaf(a.x, w.w, sacc[0][3]);
      sacc[1][0] = fmaf(a.y, w.x, sacc[1][0]); sacc[1][1] = fmaf(a.y, w.y, sacc[1][1]);
      sacc[1][2] = fmaf(a.y, w.z, sacc[1][2]); sacc[1][3] = fmaf(a.y, w.w, sacc[1][3]);
      sacc[2][0] = fmaf(a.z, w.x, sacc[2][0]); sacc[2][1] = fmaf(a.z, w.y, sacc[2][1]);
      sacc[2][2] = fmaf(a.z, w.z, sacc[2][2]); sacc[2][3] = fmaf(a.z, w.w, sacc[2][3]);
      sacc[3][0] = fmaf(a.w, w.x, sacc[3][0]); sacc[3][1] = fmaf(a.w, w.y, sacc[3][1]);
      sacc[3][2] = fmaf(a.w, w.z, sacc[3][2]); sacc[3][3] = fmaf(a.w, w.w, sacc[3][3]);
    }
#pragma unroll
    for (int i = 0; i < 4; ++i) {
      float4 sv;
      sv.x = sacc[i][0] * 0.125f; sv.y = sacc[i][1] * 0.125f;
      sv.z = sacc[i][2] * 0.125f; sv.w = sacc[i][3] * 0.125f;
      *(float4*)&sS[(ty << 2) + i][tx << 2] = sv;
    }
    __syncthreads();
    {
      int r = tid >> 2, gg = tid & 3;
      float vals[16];
      float vmax = -INFINITY;
#pragma unroll
      for (int i = 0; i < 4; ++i) {
        float4 p4 = *(const float4*)&sS[r][(gg << 4) + (i << 2)];
        vals[4 * i + 0] = p4.x; vals[4 * i + 1] = p4.y;
        vals[4 * i + 2] = p4.z; vals[4 * i + 3] = p4.w;
        vmax = fmaxf(vmax, fmaxf(fmaxf(p4.x, p4.y), fmaxf(p4.z, p4.w)));
      }
      vmax = fmaxf(vmax, __shfl_xor(vmax, 1));
      vmax = fmaxf(vmax, __shfl_xor(vmax, 2));
      float mold = mS[r];
      float mnew = fmaxf(mold, vmax);
      float sum = 0.f;
#pragma unroll
      for (int i = 0; i < 16; ++i) {
        float p = expf(vals[i] - mnew);
        vals[i] = p;
        sum += p;
      }
#pragma unroll
      for (int i = 0; i < 4; ++i) {
        float4 p4;
        p4.x = vals[4 * i + 0]; p4.y = vals[4 * i + 1];
        p4.z = vals[4 * i + 2]; p4.w = vals[4 * i + 3];
        *(float4*)&sS[r][(gg << 4) + (i << 2)] = p4;
      }
      sum += __shfl_xor(sum, 1);
      sum += __shfl_xor(sum, 2);
      if (gg == 0) {
        float f = expf(mold - mnew);
        fS[r] = f;
        mS[r] = mnew;
        lS[r] = lS[r] * f + sum;
      }
    }
    __syncthreads();
    {
      float f0 = fS[(ty << 2) + 0], f1 = fS[(ty << 2) + 1];
      float f2 = fS[(ty << 2) + 2], f3 = fS[(ty << 2) + 3];
#pragma unroll
      for (int j = 0; j < 4; ++j) {
        oacc[0][j] *= f0; oacc[1][j] *= f1; oacc[2][j] *= f2; oacc[3][j] *= f3;
      }
      for (int jj = 0; jj < 64; ++jj) {
        float4 vv = *(const float4*)&vS[jj][tx << 2];
        float p0 = sS[(ty << 2) + 0][jj];
        float p1 = sS[(ty << 2) + 1][jj];
        float p2 = sS[(ty << 2) + 2][jj];
        float p3 = sS[(ty << 2) + 3][jj];
        oacc[0][0] = fmaf(p0, vv.x, oacc[0][0]); oacc[0][1] = fmaf(p0, vv.y, oacc[0][1]);
        oacc[0][2] = fmaf(p0, vv.z, oacc[0][2]); oacc[0][3] = fmaf(p0, vv.w, oacc[0][3]);
        oacc[1][0] = fmaf(p1, vv.x, oacc[1][0]); oacc[1][1] = fmaf(p1, vv.y, oacc[1][1]);
        oacc[1][2] = fmaf(p1, vv.z, oacc[1][2]); oacc[1][3] = fmaf(p1, vv.w, oacc[1][3]);
        oacc[2][0] = fmaf(p2, vv.x, oacc[2][0]); oacc[2][1] = fmaf(p2, vv.y, oacc[2][1]);
        oacc[2][2] = fmaf(p2, vv.z, oacc[2][2]); oacc[2][3] = fmaf(p2, vv.w, oacc[2][3]);
        oacc[3][0] = fmaf(p3, vv.x, oacc[3][0]); oacc[3][1] = fmaf(p3, vv.y, oacc[3][1]);
        oacc[3][2] = fmaf(p3, vv.z, oacc[3][2]); oacc[3][3] = fmaf(p3, vv.w, oacc[3][3]);
      }
    }
  }
  __syncthreads();
  {
    float il[4];
#pragma unroll
    for (int i = 0; i < 4; ++i) il[i] = 1.f / lS[(ty << 2) + i];
#pragma unroll
    for (int i = 0; i < 4; ++i) {
      int row = b * NCTR + qt * 64 + (ty << 2) + i;
      float4 ov;
      ov.x = oacc[i][0] * il[i]; ov.y = oacc[i][1] * il[i];
      ov.z = oacc[i][2] * il[i]; ov.w = oacc[i][3] * il[i];
      *(float4*)(o + (size_t)row * NDIM + hh * 64 + (tx << 2)) = ov;
    }
  }
}

// ---------------------------------------------------------------------------
extern "C" void kernel_launch(void* const* d_in, const int* in_sizes, int n_in,
                              void* d_out, int out_size, void* d_ws, size_t ws_size,
                              hipStream_t stream) {
  const float* pc      = (const float*)d_in[0];
  const float* embed_w = (const float*)d_in[1];
  const float* embed_b = (const float*)d_in[2];
  const float* lw1     = (const float*)d_in[3];
  const float* lb1     = (const float*)d_in[4];
  const float* lw2     = (const float*)d_in[5];
  const float* lb2     = (const float*)d_in[6];
  const float* gw1     = (const float*)d_in[7];
  const float* gb1     = (const float*)d_in[8];
  const float* gw2     = (const float*)d_in[9];
  const float* gb2     = (const float*)d_in[10];
  const float* ln1_g   = (const float*)d_in[11];
  const float* ln1_b   = (const float*)d_in[12];
  const float* qkv_w   = (const float*)d_in[13];
  const float* qkv_b   = (const float*)d_in[14];
  const float* proj_w  = (const float*)d_in[15];
  const float* proj_b  = (const float*)d_in[16];
  const float* gamma1  = (const float*)d_in[17];
  const float* ln2_g   = (const float*)d_in[18];
  const float* ln2_b   = (const float*)d_in[19];
  const float* fc1_w   = (const float*)d_in[20];
  const float* fc1_b   = (const float*)d_in[21];
  const float* fc2_w   = (const float*)d_in[22];
  const float* fc2_b   = (const float*)d_in[23];
  const float* gamma2  = (const float*)d_in[24];
  const float* lnf_g   = (const float*)d_in[25];
  const float* lnf_b   = (const float*)d_in[26];

  float* out = (float*)d_out;
  float* centers = out + (size_t)NB * NCTR * NDIM;

  int* nn = (int*)d_ws;
  float* fws = (float*)d_ws;
  float* h  = fws + 262144;            // [8192,256]
  float* x  = h + 8192 * 256;          // [8192,384]
  float* xn = x + 8192 * 384;          // [8192,384]
  float* F  = xn + 8192 * 384;         // [8192,1536]
  ushort* wsplit = (ushort*)(fws + 21233664);

  // --- weight pre-split (bf16 hi/lo, MFMA layout) ---
  size_t wofs = 0;
  ushort* qkvH[6]; ushort* projH[6]; ushort* fc1H[6]; ushort* fc2H[6];
  auto convp = [&](const float* w, int Kpad, int N, int Ksrc) -> ushort* {
    ushort* dst = wsplit + wofs;
    int K8 = Kpad >> 3, total = K8 * N;
    wconv<<<(total + 255) / 256, 256, 0, stream>>>(w, dst, K8, N, Ksrc);
    wofs += (size_t)2 * Kpad * N;
    return dst;
  };
  for (int l = 0; l < 6; ++l) qkvH[l] = convp(qkv_w + (size_t)l * 384 * 1152, 384, 1152, 384);
  for (int l = 0; l < 6; ++l) projH[l] = convp(proj_w + (size_t)l * 384 * 384, 384, 384, 384);
  for (int l = 0; l < 6; ++l) fc1H[l] = convp(fc1_w + (size_t)l * 384 * 1536, 384, 1536, 384);
  for (int l = 0; l < 6; ++l) fc2H[l] = convp(fc2_w + (size_t)l * 1536 * 384, 1536, 384, 1536);
  ushort* g1H = convp(gw1, 256, 256, 256);
  ushort* g2H = convp(gw2, 256, 384, 256);
  ushort* lw1s = convp(lw1, 64, 256, 51);   // pad 51 -> 64
  ushort* lw2s = convp(lw2, 256, 256, 256);

  // --- geometry + fused edge pipeline ---
  fps_kernel<<<NB, 512, 0, stream>>>(pc, centers);
  knn_kernel<<<2048, 256, 0, stream>>>(pc, centers, nn);
  edge_mfma<<<4096, 256, 0, stream>>>(pc, centers, nn, lw1s, lb1, lw2s, lb2, h);

  gemm_x3<1><<<dim3(2, 64), 256, 0, stream>>>(h, g1H, g1H + 256 * 256, gb1,
                                              nullptr, nullptr, xn, 8192, 256, 256);
  gemm_x3<0><<<dim3(3, 64), 256, 0, stream>>>(xn, g2H, g2H + 256 * 384, gb2,
                                              nullptr, nullptr, x, 8192, 384, 256);
  pe_add<<<8192, 256, 0, stream>>>(centers, embed_w, embed_b, x);

  for (int l = 0; l < 6; ++l) {
    ln_f32<<<2048, 256, 0, stream>>>(x, ln1_g + l * 384, ln1_b + l * 384, xn);
    gemm_x3<0><<<dim3(9, 64), 256, 0, stream>>>(
        xn, qkvH[l], qkvH[l] + 384 * 1152, qkv_b + l * 1152, nullptr, nullptr, F,
        8192, 1152, 384);
    attn_f32<<<768, 256, 0, stream>>>(F, xn);
    gemm_x3<3><<<dim3(3, 64), 256, 0, stream>>>(
        xn, projH[l], projH[l] + 384 * 384, proj_b + l * 384, gamma1 + l * 384, x, x,
        8192, 384, 384);
    ln_f32<<<2048, 256, 0, stream>>>(x, ln2_g + l * 384, ln2_b + l * 384, xn);
    gemm_x3<2><<<dim3(12, 64), 256, 0, stream>>>(
        xn, fc1H[l], fc1H[l] + 384 * 1536, fc1_b + l * 1536, nullptr, nullptr, F,
        8192, 1536, 384);
    gemm_x3<3><<<dim3(3, 64), 256, 0, stream>>>(
        F, fc2H[l], fc2H[l] + 1536 * 384, fc2_b + l * 384, gamma2 + l * 384, x, x,
        8192, 384, 1536);
  }
  ln_f32<<<2048, 256, 0, stream>>>(x, lnf_g, lnf_b, out);
}

// Round 5
// 2269.232 us; speedup vs baseline: 2.0280x; 1.1485x over previous
//
#include <hip/hip_runtime.h>
#include <math.h>

#define NB 16
#define NM 2048
#define NCTR 512
#define NK 32
#define NDIM 384

typedef unsigned long long ull;
typedef unsigned int uint;
typedef unsigned short ushort;
typedef __attribute__((ext_vector_type(8))) short bf16x8;
typedef __attribute__((ext_vector_type(4))) float f32x4;

// Exact (no-FMA-contraction) squared distance, matching XLA's per-op fp32.
__device__ __forceinline__ float dist2_exact(float ax, float ay, float az,
                                             float bx, float by, float bz) {
  float dx = __fsub_rn(ax, bx);
  float dy = __fsub_rn(ay, by);
  float dz = __fsub_rn(az, bz);
  return __fadd_rn(__fadd_rn(__fmul_rn(dx, dx), __fmul_rn(dy, dy)),
                   __fmul_rn(dz, dz));
}

__device__ __forceinline__ float gelu_f(float x) {
  return 0.5f * x * (1.0f + erff(x * 0.70710678118654752f));
}

// fp32 -> bf16 round-to-nearest-even (bit trick), and back.
__device__ __forceinline__ ushort f2bf(float f) {
  uint u = __float_as_uint(f);
  return (ushort)((u + 0x7FFFu + ((u >> 16) & 1u)) >> 16);
}
__device__ __forceinline__ float bf2f(ushort h) {
  return __uint_as_float(((uint)h) << 16);
}

// Split 8 fp32 into bf16 hi / lo packed words (2 bf16 per uint).
__device__ __forceinline__ void cvt8(float4 p, float4 q, uint4& hi, uint4& lo) {
  float v0 = p.x, v1 = p.y, v2 = p.z, v3 = p.w;
  float v4 = q.x, v5 = q.y, v6 = q.z, v7 = q.w;
  ushort h0 = f2bf(v0), h1 = f2bf(v1), h2 = f2bf(v2), h3 = f2bf(v3);
  ushort h4 = f2bf(v4), h5 = f2bf(v5), h6 = f2bf(v6), h7 = f2bf(v7);
  ushort l0 = f2bf(v0 - bf2f(h0)), l1 = f2bf(v1 - bf2f(h1));
  ushort l2 = f2bf(v2 - bf2f(h2)), l3 = f2bf(v3 - bf2f(h3));
  ushort l4 = f2bf(v4 - bf2f(h4)), l5 = f2bf(v5 - bf2f(h5));
  ushort l6 = f2bf(v6 - bf2f(h6)), l7 = f2bf(v7 - bf2f(h7));
  hi.x = (uint)h0 | ((uint)h1 << 16); hi.y = (uint)h2 | ((uint)h3 << 16);
  hi.z = (uint)h4 | ((uint)h5 << 16); hi.w = (uint)h6 | ((uint)h7 << 16);
  lo.x = (uint)l0 | ((uint)l1 << 16); lo.y = (uint)l2 | ((uint)l3 << 16);
  lo.z = (uint)l4 | ((uint)l5 << 16); lo.w = (uint)l6 | ((uint)l7 << 16);
}

// ---------------------------------------------------------------------------
// FPS v2: 4 waves, 8 pts/lane in registers, one barrier per iteration.
// Exact argmax semantics (key = dist_bits<<32 | (0x7FFFFFFF - idx)).
// ---------------------------------------------------------------------------
__global__ __launch_bounds__(256)
void fps_kernel(const float* __restrict__ pc, float* __restrict__ centers) {
  int b = blockIdx.x;
  __shared__ float4 pos4[NM];      // 32 KB, for uniform broadcast fetch
  __shared__ ull red[2][4];
  const float* pb = pc + (size_t)b * (NM * 3);
  int tid = threadIdx.x, lane = tid & 63, wv = tid >> 6;
  float px[8], py[8], pz[8];
#pragma unroll
  for (int i = 0; i < 8; ++i) {
    int p = tid + 256 * i;
    float x = pb[3 * p], y = pb[3 * p + 1], z = pb[3 * p + 2];
    px[i] = x; py[i] = y; pz[i] = z;
    pos4[p] = make_float4(x, y, z, 0.f);
  }
  __syncthreads();
  float* cb = centers + (size_t)b * (NCTR * 3);
  float4 s0 = pos4[0];
  float sx = s0.x, sy = s0.y, sz = s0.z;
  if (tid == 0) { cb[0] = sx; cb[1] = sy; cb[2] = sz; }
  float d[8];
  for (int n = 1; n < NCTR; ++n) {
    ull best = 0;
#pragma unroll
    for (int i = 0; i < 8; ++i) {
      int p = tid + 256 * i;
      float nd = dist2_exact(px[i], py[i], pz[i], sx, sy, sz);
      d[i] = (n == 1) ? nd : fminf(d[i], nd);
      ull key = ((ull)__float_as_uint(d[i]) << 32) | (unsigned)(0x7FFFFFFF - p);
      best = best > key ? best : key;
    }
#pragma unroll
    for (int off = 32; off; off >>= 1) {
      ull o = __shfl_xor(best, off);
      best = best > o ? best : o;
    }
    if (lane == 0) red[n & 1][wv] = best;
    __syncthreads();
    ull g0 = red[n & 1][0], g1 = red[n & 1][1];
    ull g2 = red[n & 1][2], g3 = red[n & 1][3];
    ull ga = g0 > g1 ? g0 : g1;
    ull gc2 = g2 > g3 ? g2 : g3;
    ull gb = ga > gc2 ? ga : gc2;
    int j = 0x7FFFFFFF - (int)(unsigned)(gb & 0xFFFFFFFFull);
    float4 np = pos4[j];
    sx = np.x; sy = np.y; sz = np.z;
    if (tid == 0) { cb[n * 3] = sx; cb[n * 3 + 1] = sy; cb[n * 3 + 2] = sz; }
  }
}

// ---------------------------------------------------------------------------
// KNN (unchanged).
// ---------------------------------------------------------------------------
__global__ __launch_bounds__(256)
void knn_kernel(const float* __restrict__ pc, const float* __restrict__ centers,
                int* __restrict__ nn) {
  __shared__ float pos[NM * 3];
  int b = blockIdx.x >> 7;
  int n0 = (blockIdx.x & 127) << 2;
  const float* pb = pc + (size_t)b * (NM * 3);
  for (int i = threadIdx.x; i < NM * 3; i += 256) pos[i] = pb[i];
  __syncthreads();
  int wv = threadIdx.x >> 6, lane = threadIdx.x & 63;
  int gc = b * NCTR + n0 + wv;
  float cx = centers[gc * 3], cy = centers[gc * 3 + 1], cz = centers[gc * 3 + 2];
  ull key[32];
  ull lmin = ~0ull;
#pragma unroll
  for (int r = 0; r < 32; ++r) {
    int p = lane + (r << 6);
    float nd = dist2_exact(pos[3 * p], pos[3 * p + 1], pos[3 * p + 2], cx, cy, cz);
    key[r] = ((ull)__float_as_uint(nd) << 11) | (unsigned)p;
    lmin = lmin < key[r] ? lmin : key[r];
  }
  int* nnc = nn + (size_t)gc * NK;
  for (int round = 0; round < NK; ++round) {
    ull w = lmin;
#pragma unroll
    for (int off = 32; off; off >>= 1) {
      ull o = __shfl_xor(w, off);
      w = w < o ? w : o;
    }
    if (lmin == w) {
      nnc[round] = (int)(w & 2047ull);
      lmin = ~0ull;
#pragma unroll
      for (int r = 0; r < 32; ++r) {
        key[r] = (key[r] == w) ? ~0ull : key[r];
        lmin = lmin < key[r] ? lmin : key[r];
      }
    }
  }
}

// ---------------------------------------------------------------------------
// Weight pre-split (unchanged).
// ---------------------------------------------------------------------------
__global__ __launch_bounds__(256)
void wconv(const float* __restrict__ W, ushort* __restrict__ out, int K8, int N,
           int Ksrc) {
  int c = blockIdx.x * 256 + threadIdx.x;
  if (c >= K8 * N) return;
  int kb = c / N, n = c - kb * N;
  float v[8];
#pragma unroll
  for (int i = 0; i < 8; ++i) {
    int row = kb * 8 + i;
    v[i] = (row < Ksrc) ? W[(size_t)row * N + n] : 0.f;
  }
  float4 p, q;
  p.x = v[0]; p.y = v[1]; p.z = v[2]; p.w = v[3];
  q.x = v[4]; q.y = v[5]; q.z = v[6]; q.w = v[7];
  uint4 hi, lo;
  cvt8(p, q, hi, lo);
  *(uint4*)(out + (size_t)c * 8) = hi;
  *(uint4*)(out + (size_t)(K8 * N + c) * 8) = lo;
}

// ---------------------------------------------------------------------------
// Fused edge pipeline with MFMA (unchanged from round 3).
// ---------------------------------------------------------------------------
__global__ __launch_bounds__(256, 2)
void edge_mfma(const float* __restrict__ pc, const float* __restrict__ centers,
               const int* __restrict__ nn, const ushort* __restrict__ lw1s,
               const float* __restrict__ lb1, const ushort* __restrict__ lw2s,
               const float* __restrict__ lb2, float* __restrict__ h) {
  __shared__ __align__(16) ushort featH[4096], featL[4096];
  __shared__ __align__(16) ushort t1H[16384], t1L[16384];
  int tid = threadIdx.x;
  int w = tid >> 6, lane = tid & 63;
  int l15 = lane & 15, l4 = lane >> 4;
  int wbase = w << 6;
  {
    int e = tid >> 2, s = tid & 3;
    int ge = blockIdx.x * 64 + e;
    int c = ge >> 5;
    int b = c >> 9;
    int j = nn[ge];
    const float* sp = pc + ((size_t)b * NM + j) * 3;
    float rx = sp[0] - centers[c * 3];
    float ry = sp[1] - centers[c * 3 + 1];
    float rz = sp[2] - centers[c * 3 + 2];
    auto putk = [&](int k, float v) {
      ushort hi = f2bf(v);
      ushort lo = f2bf(v - bf2f(hi));
      int idx = ((k >> 3) * 64 + e) * 8 + (k & 7);
      featH[idx] = hi;
      featL[idx] = lo;
    };
    if (s < 3) {
      float r = (s == 0) ? rx : (s == 1) ? ry : rz;
#pragma unroll
      for (int f = 0; f < 8; ++f) {
        float ef = (float)(M_PI * (double)(1 << f));
        float p = r * ef;
        putk(3 + 8 * s + f, sinf(p));
        putk(27 + 8 * s + f, cosf(p));
      }
    } else {
      putk(0, rx);
      putk(1, ry);
      putk(2, rz);
#pragma unroll
      for (int k = 51; k < 64; ++k) putk(k, 0.f);
    }
  }
  __syncthreads();
  const ushort* lw1H = lw1s;
  const ushort* lw1L = lw1s + 8 * 256 * 8;
  f32x4 acc1[4][4];
#pragma unroll
  for (int i = 0; i < 4; ++i)
#pragma unroll
    for (int j = 0; j < 4; ++j) acc1[i][j] = (f32x4){0.f, 0.f, 0.f, 0.f};
#pragma unroll
  for (int ks = 0; ks < 2; ++ks) {
    bf16x8 ah[4], al[4];
#pragma unroll
    for (int fm = 0; fm < 4; ++fm) {
      int idx = ((ks * 4 + l4) * 64 + fm * 16 + l15) * 8;
      ah[fm] = *(const bf16x8*)&featH[idx];
      al[fm] = *(const bf16x8*)&featL[idx];
    }
#pragma unroll
    for (int fn = 0; fn < 4; ++fn) {
      int col = wbase + fn * 16 + l15;
      size_t boff = ((size_t)(ks * 4 + l4) * 256 + col) * 8;
      bf16x8 bh = *(const bf16x8*)(lw1H + boff);
      bf16x8 bl = *(const bf16x8*)(lw1L + boff);
#pragma unroll
      for (int fm = 0; fm < 4; ++fm) {
        acc1[fm][fn] = __builtin_amdgcn_mfma_f32_16x16x32_bf16(al[fm], bh, acc1[fm][fn], 0, 0, 0);
        acc1[fm][fn] = __builtin_amdgcn_mfma_f32_16x16x32_bf16(ah[fm], bl, acc1[fm][fn], 0, 0, 0);
        acc1[fm][fn] = __builtin_amdgcn_mfma_f32_16x16x32_bf16(ah[fm], bh, acc1[fm][fn], 0, 0, 0);
      }
    }
  }
#pragma unroll
  for (int fn = 0; fn < 4; ++fn) {
    int chan = wbase + fn * 16 + l15;
    float bias = lb1[chan];
    int kb = chan >> 3, k7 = chan & 7;
#pragma unroll
    for (int fm = 0; fm < 4; ++fm) {
#pragma unroll
      for (int r = 0; r < 4; ++r) {
        int edge = fm * 16 + l4 * 4 + r;
        float v = fmaxf(acc1[fm][fn][r] + bias, 0.f);
        ushort hi = f2bf(v);
        ushort lo = f2bf(v - bf2f(hi));
        int idx = (kb * 64 + edge) * 8 + k7;
        t1H[idx] = hi;
        t1L[idx] = lo;
      }
    }
  }
  __syncthreads();
  const ushort* lw2H = lw2s;
  const ushort* lw2L = lw2s + 32 * 256 * 8;
  f32x4 acc2[4][4];
#pragma unroll
  for (int i = 0; i < 4; ++i)
#pragma unroll
    for (int j = 0; j < 4; ++j) acc2[i][j] = (f32x4){0.f, 0.f, 0.f, 0.f};
#pragma unroll
  for (int ks = 0; ks < 8; ++ks) {
    bf16x8 ah[4], al[4];
#pragma unroll
    for (int fm = 0; fm < 4; ++fm) {
      int idx = ((ks * 4 + l4) * 64 + fm * 16 + l15) * 8;
      ah[fm] = *(const bf16x8*)&t1H[idx];
      al[fm] = *(const bf16x8*)&t1L[idx];
    }
#pragma unroll
    for (int fn = 0; fn < 4; ++fn) {
      int col = wbase + fn * 16 + l15;
      size_t boff = ((size_t)(ks * 4 + l4) * 256 + col) * 8;
      bf16x8 bh = *(const bf16x8*)(lw2H + boff);
      bf16x8 bl = *(const bf16x8*)(lw2L + boff);
#pragma unroll
      for (int fm = 0; fm < 4; ++fm) {
        acc2[fm][fn] = __builtin_amdgcn_mfma_f32_16x16x32_bf16(al[fm], bh, acc2[fm][fn], 0, 0, 0);
        acc2[fm][fn] = __builtin_amdgcn_mfma_f32_16x16x32_bf16(ah[fm], bl, acc2[fm][fn], 0, 0, 0);
        acc2[fm][fn] = __builtin_amdgcn_mfma_f32_16x16x32_bf16(ah[fm], bh, acc2[fm][fn], 0, 0, 0);
      }
    }
  }
#pragma unroll
  for (int fn = 0; fn < 4; ++fn) {
    int col = wbase + fn * 16 + l15;
    float m0 = -INFINITY, m1 = -INFINITY;
#pragma unroll
    for (int r = 0; r < 4; ++r) {
      m0 = fmaxf(m0, fmaxf(acc2[0][fn][r], acc2[1][fn][r]));
      m1 = fmaxf(m1, fmaxf(acc2[2][fn][r], acc2[3][fn][r]));
    }
    m0 = fmaxf(m0, __shfl_xor(m0, 16));
    m0 = fmaxf(m0, __shfl_xor(m0, 32));
    m1 = fmaxf(m1, __shfl_xor(m1, 16));
    m1 = fmaxf(m1, __shfl_xor(m1, 32));
    if (l4 == 0) {
      float bias = lb2[col];
      int c0 = blockIdx.x * 2;
      h[(size_t)c0 * 256 + col] = m0 + bias;
      h[(size_t)(c0 + 1) * 256 + col] = m1 + bias;
    }
  }
}

// ---------------------------------------------------------------------------
// bf16x3 split MFMA GEMM (unchanged).
// ---------------------------------------------------------------------------
template <int EPI>
__global__ __launch_bounds__(256, 2)
void gemm_x3(const float* __restrict__ A, const ushort* __restrict__ Wh,
             const ushort* __restrict__ Wl, const float* __restrict__ bias,
             const float* __restrict__ gamma, const float* __restrict__ resid,
             float* __restrict__ C, int M, int N, int K) {
  __shared__ __align__(16) ushort Ah[4096], Al[4096], Bh[4096], Bl[4096];
  int tid = threadIdx.x;
  int bn = blockIdx.x << 7, bm = blockIdx.y << 7;
  int wid = tid >> 6, lane = tid & 63;
  int wr = wid >> 1, wc = wid & 1;
  int l15 = lane & 15, l4 = lane >> 4;

  int arow = tid >> 1, akb0 = (tid & 1) << 1;
  const float* Ap = A + (size_t)(bm + arow) * K + (akb0 << 3);
  int wkb = tid >> 7, wn = tid & 127;

  f32x4 acc[4][4];
#pragma unroll
  for (int i = 0; i < 4; ++i)
#pragma unroll
    for (int j = 0; j < 4; ++j) acc[i][j] = (f32x4){0.f, 0.f, 0.f, 0.f};

  float4 a0 = *(const float4*)(Ap + 0);
  float4 a1 = *(const float4*)(Ap + 4);
  float4 a2 = *(const float4*)(Ap + 8);
  float4 a3 = *(const float4*)(Ap + 12);
  size_t wo1 = ((size_t)wkb * N + bn + wn) * 8;
  size_t wo2 = ((size_t)(wkb + 2) * N + bn + wn) * 8;
  uint4 w0 = *(const uint4*)(Wh + wo1);
  uint4 w1 = *(const uint4*)(Wh + wo2);
  uint4 w2 = *(const uint4*)(Wl + wo1);
  uint4 w3 = *(const uint4*)(Wl + wo2);

  int nkt = K >> 5;
  for (int kt = 0; kt < nkt; ++kt) {
    uint4 h0, l0, h1, l1;
    cvt8(a0, a1, h0, l0);
    cvt8(a2, a3, h1, l1);
    *(uint4*)&Ah[(akb0 * 128 + arow) * 8] = h0;
    *(uint4*)&Ah[((akb0 + 1) * 128 + arow) * 8] = h1;
    *(uint4*)&Al[(akb0 * 128 + arow) * 8] = l0;
    *(uint4*)&Al[((akb0 + 1) * 128 + arow) * 8] = l1;
    *(uint4*)&Bh[tid * 8] = w0;
    *(uint4*)&Bh[(tid + 256) * 8] = w1;
    *(uint4*)&Bl[tid * 8] = w2;
    *(uint4*)&Bl[(tid + 256) * 8] = w3;
    __syncthreads();
    if (kt + 1 < nkt) {
      const float* Apn = Ap + ((kt + 1) << 5);
      a0 = *(const float4*)(Apn + 0);
      a1 = *(const float4*)(Apn + 4);
      a2 = *(const float4*)(Apn + 8);
      a3 = *(const float4*)(Apn + 12);
      size_t b1 = ((size_t)((kt + 1) * 4 + wkb) * N + bn + wn) * 8;
      size_t b2 = ((size_t)((kt + 1) * 4 + wkb + 2) * N + bn + wn) * 8;
      w0 = *(const uint4*)(Wh + b1);
      w1 = *(const uint4*)(Wh + b2);
      w2 = *(const uint4*)(Wl + b1);
      w3 = *(const uint4*)(Wl + b2);
    }
    bf16x8 ahf[4], alf[4];
#pragma unroll
    for (int fm = 0; fm < 4; ++fm) {
      int ci = l4 * 128 + wr * 64 + fm * 16 + l15;
      ahf[fm] = *(bf16x8*)&Ah[ci * 8];
      alf[fm] = *(bf16x8*)&Al[ci * 8];
    }
#pragma unroll
    for (int fn = 0; fn < 4; ++fn) {
      int ci = l4 * 128 + wc * 64 + fn * 16 + l15;
      bf16x8 bh = *(bf16x8*)&Bh[ci * 8];
      bf16x8 bl = *(bf16x8*)&Bl[ci * 8];
#pragma unroll
      for (int fm = 0; fm < 4; ++fm) {
        acc[fm][fn] = __builtin_amdgcn_mfma_f32_16x16x32_bf16(alf[fm], bh, acc[fm][fn], 0, 0, 0);
        acc[fm][fn] = __builtin_amdgcn_mfma_f32_16x16x32_bf16(ahf[fm], bl, acc[fm][fn], 0, 0, 0);
        acc[fm][fn] = __builtin_amdgcn_mfma_f32_16x16x32_bf16(ahf[fm], bh, acc[fm][fn], 0, 0, 0);
      }
    }
    __syncthreads();
  }

#pragma unroll
  for (int fn = 0; fn < 4; ++fn) {
    int col = bn + wc * 64 + fn * 16 + l15;
    float bv = bias[col];
    float gv = (EPI == 3) ? gamma[col] : 0.f;
#pragma unroll
    for (int fm = 0; fm < 4; ++fm) {
      int row0 = bm + wr * 64 + fm * 16 + l4 * 4;
#pragma unroll
      for (int r = 0; r < 4; ++r) {
        float v = acc[fm][fn][r] + bv;
        if (EPI == 1) v = fmaxf(v, 0.f);
        else if (EPI == 2) v = gelu_f(v);
        else if (EPI == 3) v = resid[(size_t)(row0 + r) * N + col] + gv * v;
        C[(size_t)(row0 + r) * N + col] = v;
      }
    }
  }
}

// ---------------------------------------------------------------------------
// Positional-embedding add (unchanged).
// ---------------------------------------------------------------------------
__global__ __launch_bounds__(256)
void pe_add(const float* __restrict__ centers, const float* __restrict__ ew,
            const float* __restrict__ eb, float* x) {
  __shared__ float fc[51];
  int c = blockIdx.x, tid = threadIdx.x;
  if (tid < 24) {
    int a = tid >> 3, f = tid & 7;
    float coord = centers[c * 3 + a];
    float p = coord * (float)(M_PI * (double)(1 << f));
    fc[3 + tid] = sinf(p);
    fc[27 + tid] = cosf(p);
  } else if (tid < 27) {
    fc[tid - 24] = centers[c * 3 + (tid - 24)];
  }
  __syncthreads();
  for (int j = tid; j < NDIM; j += 256) {
    float acc = eb[j];
#pragma unroll
    for (int d = 0; d < 51; ++d) acc = fmaf(fc[d], ew[d * NDIM + j], acc);
    x[(size_t)c * NDIM + j] += acc;
  }
}

// ---------------------------------------------------------------------------
// LayerNorm (unchanged).
// ---------------------------------------------------------------------------
__global__ __launch_bounds__(256)
void ln_f32(const float* __restrict__ x, const float* __restrict__ g,
            const float* __restrict__ b, float* __restrict__ y) {
  int row = (blockIdx.x << 2) + (threadIdx.x >> 6);
  int lane = threadIdx.x & 63;
  const float* xr = x + (size_t)row * NDIM;
  float v[6];
#pragma unroll
  for (int i = 0; i < 6; ++i) v[i] = xr[lane + (i << 6)];
  float s = 0.f;
#pragma unroll
  for (int i = 0; i < 6; ++i) s += v[i];
#pragma unroll
  for (int off = 32; off; off >>= 1) s += __shfl_xor(s, off);
  float m = s / 384.f;
  float var = 0.f;
#pragma unroll
  for (int i = 0; i < 6; ++i) { float dd = v[i] - m; var += dd * dd; }
#pragma unroll
  for (int off = 32; off; off >>= 1) var += __shfl_xor(var, off);
  var = var / 384.f;
  float rs = 1.f / sqrtf(var + 1e-6f);
#pragma unroll
  for (int i = 0; i < 6; ++i) {
    int cc = lane + (i << 6);
    y[(size_t)row * NDIM + cc] = (v[i] - m) * rs * g[cc] + b[cc];
  }
}

// ---------------------------------------------------------------------------
// MFMA flash attention (bf16x3 split scores + PV).
// Block = (b, head, 128 q rows); 4 waves, wave owns 32 q rows.
// KV chunks of 64 staged to LDS in B-frag layout; P transposed through
// per-wave private LDS into A-frag layout.
// ---------------------------------------------------------------------------
__global__ __launch_bounds__(256, 2)
void attn_mfma(const float* __restrict__ qkv, float* __restrict__ o) {
  __shared__ __align__(16) ushort kTH[4096], kTL[4096];  // [d/8][key][8]
  __shared__ __align__(16) ushort vSH[4096], vSL[4096];  // [k/8][d][8]
  __shared__ __align__(16) ushort pSH[8192], pSL[8192];  // per-wave [k/8][32q][8]
  int bi = blockIdx.x;
  int qt = bi & 3;
  int hh = (bi >> 2) % 6;
  int b = bi / 24;
  int tid = threadIdx.x;
  int w = tid >> 6, lane = tid & 63;
  int l15 = lane & 15, l4 = lane >> 4;
  const float* base = qkv + (size_t)(b * NCTR) * 1152;
  int qbase = qt * 128 + w * 32;

  // Q fragments in registers (hi/lo).
  bf16x8 qh[2][2], ql[2][2];
#pragma unroll
  for (int qr = 0; qr < 2; ++qr) {
#pragma unroll
    for (int ds = 0; ds < 2; ++ds) {
      const float* qp = base + (size_t)(qbase + qr * 16 + l15) * 1152 + hh * 64 +
                        ds * 32 + l4 * 8;
      float4 f0 = *(const float4*)qp;
      float4 f1 = *(const float4*)(qp + 4);
      uint4 hi, lo;
      cvt8(f0, f1, hi, lo);
      qh[qr][ds] = *(bf16x8*)&hi;
      ql[qr][ds] = *(bf16x8*)&lo;
    }
  }

  f32x4 oacc[2][4];
#pragma unroll
  for (int i = 0; i < 2; ++i)
#pragma unroll
    for (int j = 0; j < 4; ++j) oacc[i][j] = (f32x4){0.f, 0.f, 0.f, 0.f};
  float m_[2][4], l_[2][4];
#pragma unroll
  for (int i = 0; i < 2; ++i)
#pragma unroll
    for (int r = 0; r < 4; ++r) { m_[i][r] = -INFINITY; l_[i][r] = 0.f; }

  ushort* pHw = pSH + w * 2048;
  ushort* pLw = pSL + w * 2048;

  for (int ch = 0; ch < 8; ++ch) {
    // ---- stage K chunk: kT[(d>>3)*64+key][d&7], keys = ch*64+key ----
    {
      int key = tid & 63, dgh = tid >> 6;  // dgh: 2 d-groups of 8 each
      const float* kp = base + (size_t)(ch * 64 + key) * 1152 + 384 + hh * 64;
#pragma unroll
      for (int i = 0; i < 2; ++i) {
        int dg = dgh * 2 + i;
        float4 f0 = *(const float4*)(kp + dg * 8);
        float4 f1 = *(const float4*)(kp + dg * 8 + 4);
        uint4 hi, lo;
        cvt8(f0, f1, hi, lo);
        *(uint4*)&kTH[(dg * 64 + key) * 8] = hi;
        *(uint4*)&kTL[(dg * 64 + key) * 8] = lo;
      }
      // ---- stage V chunk: vS[(k>>3)*64+d][k&7] ----
      int d = tid & 63, kb2 = tid >> 6;
#pragma unroll
      for (int i = 0; i < 2; ++i) {
        int kb = kb2 + i * 4;
        float vv[8];
#pragma unroll
        for (int j = 0; j < 8; ++j)
          vv[j] = base[(size_t)(ch * 64 + kb * 8 + j) * 1152 + 768 + hh * 64 + d];
        float4 f0, f1;
        f0.x = vv[0]; f0.y = vv[1]; f0.z = vv[2]; f0.w = vv[3];
        f1.x = vv[4]; f1.y = vv[5]; f1.z = vv[6]; f1.w = vv[7];
        uint4 hi, lo;
        cvt8(f0, f1, hi, lo);
        *(uint4*)&vSH[(kb * 64 + d) * 8] = hi;
        *(uint4*)&vSL[(kb * 64 + d) * 8] = lo;
      }
    }
    __syncthreads();

    // ---- scores: sacc[qr][kc] over 2 d-steps ----
    f32x4 sacc[2][4];
#pragma unroll
    for (int i = 0; i < 2; ++i)
#pragma unroll
      for (int j = 0; j < 4; ++j) sacc[i][j] = (f32x4){0.f, 0.f, 0.f, 0.f};
#pragma unroll
    for (int ds = 0; ds < 2; ++ds) {
#pragma unroll
      for (int kc = 0; kc < 4; ++kc) {
        int idx = ((ds * 4 + l4) * 64 + kc * 16 + l15) * 8;
        bf16x8 bh = *(const bf16x8*)&kTH[idx];
        bf16x8 bl = *(const bf16x8*)&kTL[idx];
#pragma unroll
        for (int qr = 0; qr < 2; ++qr) {
          sacc[qr][kc] = __builtin_amdgcn_mfma_f32_16x16x32_bf16(ql[qr][ds], bh, sacc[qr][kc], 0, 0, 0);
          sacc[qr][kc] = __builtin_amdgcn_mfma_f32_16x16x32_bf16(qh[qr][ds], bl, sacc[qr][kc], 0, 0, 0);
          sacc[qr][kc] = __builtin_amdgcn_mfma_f32_16x16x32_bf16(qh[qr][ds], bh, sacc[qr][kc], 0, 0, 0);
        }
      }
    }

    // ---- online softmax ----
    float t[2][4];
#pragma unroll
    for (int qr = 0; qr < 2; ++qr)
#pragma unroll
      for (int r = 0; r < 4; ++r) {
        float a0 = sacc[qr][0][r] * 0.125f; sacc[qr][0][r] = a0;
        float a1 = sacc[qr][1][r] * 0.125f; sacc[qr][1][r] = a1;
        float a2 = sacc[qr][2][r] * 0.125f; sacc[qr][2][r] = a2;
        float a3 = sacc[qr][3][r] * 0.125f; sacc[qr][3][r] = a3;
        t[qr][r] = fmaxf(fmaxf(a0, a1), fmaxf(a2, a3));
      }
#pragma unroll
    for (int off = 1; off < 16; off <<= 1)
#pragma unroll
      for (int qr = 0; qr < 2; ++qr)
#pragma unroll
        for (int r = 0; r < 4; ++r)
          t[qr][r] = fmaxf(t[qr][r], __shfl_xor(t[qr][r], off));
    float f_[2][4];
#pragma unroll
    for (int qr = 0; qr < 2; ++qr)
#pragma unroll
      for (int r = 0; r < 4; ++r) {
        float mn = fmaxf(m_[qr][r], t[qr][r]);
        f_[qr][r] = expf(m_[qr][r] - mn);
        m_[qr][r] = mn;
      }
#pragma unroll
    for (int qr = 0; qr < 2; ++qr)
#pragma unroll
      for (int dc = 0; dc < 4; ++dc)
#pragma unroll
        for (int r = 0; r < 4; ++r) oacc[qr][dc][r] *= f_[qr][r];
    float sm[2][4];
#pragma unroll
    for (int qr = 0; qr < 2; ++qr)
#pragma unroll
      for (int r = 0; r < 4; ++r) {
        float p0 = expf(sacc[qr][0][r] - m_[qr][r]); sacc[qr][0][r] = p0;
        float p1 = expf(sacc[qr][1][r] - m_[qr][r]); sacc[qr][1][r] = p1;
        float p2 = expf(sacc[qr][2][r] - m_[qr][r]); sacc[qr][2][r] = p2;
        float p3 = expf(sacc[qr][3][r] - m_[qr][r]); sacc[qr][3][r] = p3;
        sm[qr][r] = ((p0 + p1) + (p2 + p3));
      }
#pragma unroll
    for (int off = 1; off < 16; off <<= 1)
#pragma unroll
      for (int qr = 0; qr < 2; ++qr)
#pragma unroll
        for (int r = 0; r < 4; ++r)
          sm[qr][r] += __shfl_xor(sm[qr][r], off);
#pragma unroll
    for (int qr = 0; qr < 2; ++qr)
#pragma unroll
      for (int r = 0; r < 4; ++r) l_[qr][r] = l_[qr][r] * f_[qr][r] + sm[qr][r];

    // ---- P -> per-wave LDS in A-frag layout [k/8][32q][8] ----
#pragma unroll
    for (int qr = 0; qr < 2; ++qr)
#pragma unroll
      for (int kc = 0; kc < 4; ++kc)
#pragma unroll
        for (int r = 0; r < 4; ++r) {
          float pv = sacc[qr][kc][r];
          ushort hi = f2bf(pv);
          ushort lo = f2bf(pv - bf2f(hi));
          int k = kc * 16 + l15;
          int qrow = qr * 16 + l4 * 4 + r;
          int idx = ((k >> 3) * 32 + qrow) * 8 + (k & 7);
          pHw[idx] = hi;
          pLw[idx] = lo;
        }

    // ---- PV: oacc[qr][dc] += P frag x V frag ----
#pragma unroll
    for (int ks = 0; ks < 2; ++ks) {
      bf16x8 pah[2], pal[2];
#pragma unroll
      for (int qr = 0; qr < 2; ++qr) {
        int idx = ((ks * 4 + l4) * 32 + qr * 16 + l15) * 8;
        pah[qr] = *(const bf16x8*)&pHw[idx];
        pal[qr] = *(const bf16x8*)&pLw[idx];
      }
#pragma unroll
      for (int dc = 0; dc < 4; ++dc) {
        int idx = ((ks * 4 + l4) * 64 + dc * 16 + l15) * 8;
        bf16x8 vh = *(const bf16x8*)&vSH[idx];
        bf16x8 vl = *(const bf16x8*)&vSL[idx];
#pragma unroll
        for (int qr = 0; qr < 2; ++qr) {
          oacc[qr][dc] = __builtin_amdgcn_mfma_f32_16x16x32_bf16(pal[qr], vh, oacc[qr][dc], 0, 0, 0);
          oacc[qr][dc] = __builtin_amdgcn_mfma_f32_16x16x32_bf16(pah[qr], vl, oacc[qr][dc], 0, 0, 0);
          oacc[qr][dc] = __builtin_amdgcn_mfma_f32_16x16x32_bf16(pah[qr], vh, oacc[qr][dc], 0, 0, 0);
        }
      }
    }
    __syncthreads();
  }

  // ---- write O = oacc / l ----
  float il[2][4];
#pragma unroll
  for (int qr = 0; qr < 2; ++qr)
#pragma unroll
    for (int r = 0; r < 4; ++r) il[qr][r] = 1.f / l_[qr][r];
#pragma unroll
  for (int qr = 0; qr < 2; ++qr)
#pragma unroll
    for (int dc = 0; dc < 4; ++dc)
#pragma unroll
      for (int r = 0; r < 4; ++r) {
        int row = b * NCTR + qbase + qr * 16 + l4 * 4 + r;
        int col = hh * 64 + dc * 16 + l15;
        o[(size_t)row * NDIM + col] = oacc[qr][dc][r] * il[qr][r];
      }
}

// ---------------------------------------------------------------------------
extern "C" void kernel_launch(void* const* d_in, const int* in_sizes, int n_in,
                              void* d_out, int out_size, void* d_ws, size_t ws_size,
                              hipStream_t stream) {
  const float* pc      = (const float*)d_in[0];
  const float* embed_w = (const float*)d_in[1];
  const float* embed_b = (const float*)d_in[2];
  const float* lw1     = (const float*)d_in[3];
  const float* lb1     = (const float*)d_in[4];
  const float* lw2     = (const float*)d_in[5];
  const float* lb2     = (const float*)d_in[6];
  const float* gw1     = (const float*)d_in[7];
  const float* gb1     = (const float*)d_in[8];
  const float* gw2     = (const float*)d_in[9];
  const float* gb2     = (const float*)d_in[10];
  const float* ln1_g   = (const float*)d_in[11];
  const float* ln1_b   = (const float*)d_in[12];
  const float* qkv_w   = (const float*)d_in[13];
  const float* qkv_b   = (const float*)d_in[14];
  const float* proj_w  = (const float*)d_in[15];
  const float* proj_b  = (const float*)d_in[16];
  const float* gamma1  = (const float*)d_in[17];
  const float* ln2_g   = (const float*)d_in[18];
  const float* ln2_b   = (const float*)d_in[19];
  const float* fc1_w   = (const float*)d_in[20];
  const float* fc1_b   = (const float*)d_in[21];
  const float* fc2_w   = (const float*)d_in[22];
  const float* fc2_b   = (const float*)d_in[23];
  const float* gamma2  = (const float*)d_in[24];
  const float* lnf_g   = (const float*)d_in[25];
  const float* lnf_b   = (const float*)d_in[26];

  float* out = (float*)d_out;
  float* centers = out + (size_t)NB * NCTR * NDIM;

  int* nn = (int*)d_ws;
  float* fws = (float*)d_ws;
  float* h  = fws + 262144;            // [8192,256]
  float* x  = h + 8192 * 256;          // [8192,384]
  float* xn = x + 8192 * 384;          // [8192,384]
  float* F  = xn + 8192 * 384;         // [8192,1536]
  ushort* wsplit = (ushort*)(fws + 21233664);

  // --- weight pre-split (bf16 hi/lo, MFMA layout) ---
  size_t wofs = 0;
  ushort* qkvH[6]; ushort* projH[6]; ushort* fc1H[6]; ushort* fc2H[6];
  auto convp = [&](const float* w, int Kpad, int N, int Ksrc) -> ushort* {
    ushort* dst = wsplit + wofs;
    int K8 = Kpad >> 3, total = K8 * N;
    wconv<<<(total + 255) / 256, 256, 0, stream>>>(w, dst, K8, N, Ksrc);
    wofs += (size_t)2 * Kpad * N;
    return dst;
  };
  for (int l = 0; l < 6; ++l) qkvH[l] = convp(qkv_w + (size_t)l * 384 * 1152, 384, 1152, 384);
  for (int l = 0; l < 6; ++l) projH[l] = convp(proj_w + (size_t)l * 384 * 384, 384, 384, 384);
  for (int l = 0; l < 6; ++l) fc1H[l] = convp(fc1_w + (size_t)l * 384 * 1536, 384, 1536, 384);
  for (int l = 0; l < 6; ++l) fc2H[l] = convp(fc2_w + (size_t)l * 1536 * 384, 1536, 384, 1536);
  ushort* g1H = convp(gw1, 256, 256, 256);
  ushort* g2H = convp(gw2, 256, 384, 256);
  ushort* lw1s = convp(lw1, 64, 256, 51);
  ushort* lw2s = convp(lw2, 256, 256, 256);

  // --- geometry + fused edge pipeline ---
  fps_kernel<<<NB, 256, 0, stream>>>(pc, centers);
  knn_kernel<<<2048, 256, 0, stream>>>(pc, centers, nn);
  edge_mfma<<<4096, 256, 0, stream>>>(pc, centers, nn, lw1s, lb1, lw2s, lb2, h);

  gemm_x3<1><<<dim3(2, 64), 256, 0, stream>>>(h, g1H, g1H + 256 * 256, gb1,
                                              nullptr, nullptr, xn, 8192, 256, 256);
  gemm_x3<0><<<dim3(3, 64), 256, 0, stream>>>(xn, g2H, g2H + 256 * 384, gb2,
                                              nullptr, nullptr, x, 8192, 384, 256);
  pe_add<<<8192, 256, 0, stream>>>(centers, embed_w, embed_b, x);

  for (int l = 0; l < 6; ++l) {
    ln_f32<<<2048, 256, 0, stream>>>(x, ln1_g + l * 384, ln1_b + l * 384, xn);
    gemm_x3<0><<<dim3(9, 64), 256, 0, stream>>>(
        xn, qkvH[l], qkvH[l] + 384 * 1152, qkv_b + l * 1152, nullptr, nullptr, F,
        8192, 1152, 384);
    attn_mfma<<<384, 256, 0, stream>>>(F, xn);
    gemm_x3<3><<<dim3(3, 64), 256, 0, stream>>>(
        xn, projH[l], projH[l] + 384 * 384, proj_b + l * 384, gamma1 + l * 384, x, x,
        8192, 384, 384);
    ln_f32<<<2048, 256, 0, stream>>>(x, ln2_g + l * 384, ln2_b + l * 384, xn);
    gemm_x3<2><<<dim3(12, 64), 256, 0, stream>>>(
        xn, fc1H[l], fc1H[l] + 384 * 1536, fc1_b + l * 1536, nullptr, nullptr, F,
        8192, 1536, 384);
    gemm_x3<3><<<dim3(3, 64), 256, 0, stream>>>(
        F, fc2H[l], fc2H[l] + 1536 * 384, fc2_b + l * 384, gamma2 + l * 384, x, x,
        8192, 384, 1536);
  }
  ln_f32<<<2048, 256, 0, stream>>>(x, lnf_g, lnf_b, out);
}

// Round 6
// 2072.713 us; speedup vs baseline: 2.2203x; 1.0948x over previous
//
#include <hip/hip_runtime.h>
#include <math.h>

#define NB 16
#define NM 2048
#define NCTR 512
#define NK 32
#define NDIM 384

typedef unsigned long long ull;
typedef unsigned int uint;
typedef unsigned short ushort;
typedef __attribute__((ext_vector_type(8))) short bf16x8;
typedef __attribute__((ext_vector_type(4))) float f32x4;

// Exact (no-FMA-contraction) squared distance, matching XLA's per-op fp32.
__device__ __forceinline__ float dist2_exact(float ax, float ay, float az,
                                             float bx, float by, float bz) {
  float dx = __fsub_rn(ax, bx);
  float dy = __fsub_rn(ay, by);
  float dz = __fsub_rn(az, bz);
  return __fadd_rn(__fadd_rn(__fmul_rn(dx, dx), __fmul_rn(dy, dy)),
                   __fmul_rn(dz, dz));
}

__device__ __forceinline__ float gelu_f(float x) {
  return 0.5f * x * (1.0f + erff(x * 0.70710678118654752f));
}

// fp32 -> bf16 round-to-nearest-even (bit trick), and back.
__device__ __forceinline__ ushort f2bf(float f) {
  uint u = __float_as_uint(f);
  return (ushort)((u + 0x7FFFu + ((u >> 16) & 1u)) >> 16);
}
__device__ __forceinline__ float bf2f(ushort h) {
  return __uint_as_float(((uint)h) << 16);
}

// Split 8 fp32 into bf16 hi / lo packed words (2 bf16 per uint).
__device__ __forceinline__ void cvt8(float4 p, float4 q, uint4& hi, uint4& lo) {
  float v0 = p.x, v1 = p.y, v2 = p.z, v3 = p.w;
  float v4 = q.x, v5 = q.y, v6 = q.z, v7 = q.w;
  ushort h0 = f2bf(v0), h1 = f2bf(v1), h2 = f2bf(v2), h3 = f2bf(v3);
  ushort h4 = f2bf(v4), h5 = f2bf(v5), h6 = f2bf(v6), h7 = f2bf(v7);
  ushort l0 = f2bf(v0 - bf2f(h0)), l1 = f2bf(v1 - bf2f(h1));
  ushort l2 = f2bf(v2 - bf2f(h2)), l3 = f2bf(v3 - bf2f(h3));
  ushort l4 = f2bf(v4 - bf2f(h4)), l5 = f2bf(v5 - bf2f(h5));
  ushort l6 = f2bf(v6 - bf2f(h6)), l7 = f2bf(v7 - bf2f(h7));
  hi.x = (uint)h0 | ((uint)h1 << 16); hi.y = (uint)h2 | ((uint)h3 << 16);
  hi.z = (uint)h4 | ((uint)h5 << 16); hi.w = (uint)h6 | ((uint)h7 << 16);
  lo.x = (uint)l0 | ((uint)l1 << 16); lo.y = (uint)l2 | ((uint)l3 << 16);
  lo.z = (uint)l4 | ((uint)l5 << 16); lo.w = (uint)l6 | ((uint)l7 << 16);
}

// ---------------------------------------------------------------------------
// FPS v2 (unchanged from round 5).
// ---------------------------------------------------------------------------
__global__ __launch_bounds__(256)
void fps_kernel(const float* __restrict__ pc, float* __restrict__ centers) {
  int b = blockIdx.x;
  __shared__ float4 pos4[NM];
  __shared__ ull red[2][4];
  const float* pb = pc + (size_t)b * (NM * 3);
  int tid = threadIdx.x, lane = tid & 63, wv = tid >> 6;
  float px[8], py[8], pz[8];
#pragma unroll
  for (int i = 0; i < 8; ++i) {
    int p = tid + 256 * i;
    float x = pb[3 * p], y = pb[3 * p + 1], z = pb[3 * p + 2];
    px[i] = x; py[i] = y; pz[i] = z;
    pos4[p] = make_float4(x, y, z, 0.f);
  }
  __syncthreads();
  float* cb = centers + (size_t)b * (NCTR * 3);
  float4 s0 = pos4[0];
  float sx = s0.x, sy = s0.y, sz = s0.z;
  if (tid == 0) { cb[0] = sx; cb[1] = sy; cb[2] = sz; }
  float d[8];
  for (int n = 1; n < NCTR; ++n) {
    ull best = 0;
#pragma unroll
    for (int i = 0; i < 8; ++i) {
      int p = tid + 256 * i;
      float nd = dist2_exact(px[i], py[i], pz[i], sx, sy, sz);
      d[i] = (n == 1) ? nd : fminf(d[i], nd);
      ull key = ((ull)__float_as_uint(d[i]) << 32) | (unsigned)(0x7FFFFFFF - p);
      best = best > key ? best : key;
    }
#pragma unroll
    for (int off = 32; off; off >>= 1) {
      ull o = __shfl_xor(best, off);
      best = best > o ? best : o;
    }
    if (lane == 0) red[n & 1][wv] = best;
    __syncthreads();
    ull g0 = red[n & 1][0], g1 = red[n & 1][1];
    ull g2 = red[n & 1][2], g3 = red[n & 1][3];
    ull ga = g0 > g1 ? g0 : g1;
    ull gc2 = g2 > g3 ? g2 : g3;
    ull gb = ga > gc2 ? ga : gc2;
    int j = 0x7FFFFFFF - (int)(unsigned)(gb & 0xFFFFFFFFull);
    float4 np = pos4[j];
    sx = np.x; sy = np.y; sz = np.z;
    if (tid == 0) { cb[n * 3] = sx; cb[n * 3 + 1] = sy; cb[n * 3 + 2] = sz; }
  }
}

// ---------------------------------------------------------------------------
// KNN v2: fix the key[32] scratch spill (old VGPR_Count=44 < 64 needed).
// launch_bounds(256,2) -> 256-VGPR cap; rescan via 4 group-mins of 8 so the
// owner lane touches only the affected 8-key group per extraction.
// ---------------------------------------------------------------------------
__global__ __launch_bounds__(256, 2)
void knn_kernel(const float* __restrict__ pc, const float* __restrict__ centers,
                int* __restrict__ nn) {
  __shared__ float pos[NM * 3];
  int b = blockIdx.x >> 7;
  int n0 = (blockIdx.x & 127) << 2;
  const float* pb = pc + (size_t)b * (NM * 3);
  for (int i = threadIdx.x; i < NM * 3; i += 256) pos[i] = pb[i];
  __syncthreads();
  int wv = threadIdx.x >> 6, lane = threadIdx.x & 63;
  int gc = b * NCTR + n0 + wv;
  float cx = centers[gc * 3], cy = centers[gc * 3 + 1], cz = centers[gc * 3 + 2];
  ull key[32];
  ull gmin[4];
#pragma unroll
  for (int g = 0; g < 4; ++g) {
    gmin[g] = ~0ull;
#pragma unroll
    for (int i = 0; i < 8; ++i) {
      int r = g * 8 + i;
      int p = lane + (r << 6);
      float nd = dist2_exact(pos[3 * p], pos[3 * p + 1], pos[3 * p + 2], cx, cy, cz);
      key[r] = ((ull)__float_as_uint(nd) << 11) | (unsigned)p;
      gmin[g] = gmin[g] < key[r] ? gmin[g] : key[r];
    }
  }
  ull a01 = gmin[0] < gmin[1] ? gmin[0] : gmin[1];
  ull a23 = gmin[2] < gmin[3] ? gmin[2] : gmin[3];
  ull lmin = a01 < a23 ? a01 : a23;
  int* nnc = nn + (size_t)gc * NK;
  for (int round = 0; round < NK; ++round) {
    ull w = lmin;
#pragma unroll
    for (int off = 32; off; off >>= 1) {
      ull o = __shfl_xor(w, off);
      w = w < o ? w : o;
    }
    if (lmin == w) {                  // unique owner (idx embedded in key)
      nnc[round] = (int)(w & 2047ull);
#pragma unroll
      for (int g = 0; g < 4; ++g) {
        if (gmin[g] == w) {
          gmin[g] = ~0ull;
#pragma unroll
          for (int i = 0; i < 8; ++i) {
            int r = g * 8 + i;
            key[r] = (key[r] == w) ? ~0ull : key[r];
            gmin[g] = gmin[g] < key[r] ? gmin[g] : key[r];
          }
        }
      }
      ull b01 = gmin[0] < gmin[1] ? gmin[0] : gmin[1];
      ull b23 = gmin[2] < gmin[3] ? gmin[2] : gmin[3];
      lmin = b01 < b23 ? b01 : b23;
    }
  }
}

// ---------------------------------------------------------------------------
// Weight pre-split (unchanged).
// ---------------------------------------------------------------------------
__global__ __launch_bounds__(256)
void wconv(const float* __restrict__ W, ushort* __restrict__ out, int K8, int N,
           int Ksrc) {
  int c = blockIdx.x * 256 + threadIdx.x;
  if (c >= K8 * N) return;
  int kb = c / N, n = c - kb * N;
  float v[8];
#pragma unroll
  for (int i = 0; i < 8; ++i) {
    int row = kb * 8 + i;
    v[i] = (row < Ksrc) ? W[(size_t)row * N + n] : 0.f;
  }
  float4 p, q;
  p.x = v[0]; p.y = v[1]; p.z = v[2]; p.w = v[3];
  q.x = v[4]; q.y = v[5]; q.z = v[6]; q.w = v[7];
  uint4 hi, lo;
  cvt8(p, q, hi, lo);
  *(uint4*)(out + (size_t)c * 8) = hi;
  *(uint4*)(out + (size_t)(K8 * N + c) * 8) = lo;
}

// ---------------------------------------------------------------------------
// Fused edge pipeline with MFMA (unchanged).
// ---------------------------------------------------------------------------
__global__ __launch_bounds__(256, 2)
void edge_mfma(const float* __restrict__ pc, const float* __restrict__ centers,
               const int* __restrict__ nn, const ushort* __restrict__ lw1s,
               const float* __restrict__ lb1, const ushort* __restrict__ lw2s,
               const float* __restrict__ lb2, float* __restrict__ h) {
  __shared__ __align__(16) ushort featH[4096], featL[4096];
  __shared__ __align__(16) ushort t1H[16384], t1L[16384];
  int tid = threadIdx.x;
  int w = tid >> 6, lane = tid & 63;
  int l15 = lane & 15, l4 = lane >> 4;
  int wbase = w << 6;
  {
    int e = tid >> 2, s = tid & 3;
    int ge = blockIdx.x * 64 + e;
    int c = ge >> 5;
    int b = c >> 9;
    int j = nn[ge];
    const float* sp = pc + ((size_t)b * NM + j) * 3;
    float rx = sp[0] - centers[c * 3];
    float ry = sp[1] - centers[c * 3 + 1];
    float rz = sp[2] - centers[c * 3 + 2];
    auto putk = [&](int k, float v) {
      ushort hi = f2bf(v);
      ushort lo = f2bf(v - bf2f(hi));
      int idx = ((k >> 3) * 64 + e) * 8 + (k & 7);
      featH[idx] = hi;
      featL[idx] = lo;
    };
    if (s < 3) {
      float r = (s == 0) ? rx : (s == 1) ? ry : rz;
#pragma unroll
      for (int f = 0; f < 8; ++f) {
        float ef = (float)(M_PI * (double)(1 << f));
        float p = r * ef;
        putk(3 + 8 * s + f, sinf(p));
        putk(27 + 8 * s + f, cosf(p));
      }
    } else {
      putk(0, rx);
      putk(1, ry);
      putk(2, rz);
#pragma unroll
      for (int k = 51; k < 64; ++k) putk(k, 0.f);
    }
  }
  __syncthreads();
  const ushort* lw1H = lw1s;
  const ushort* lw1L = lw1s + 8 * 256 * 8;
  f32x4 acc1[4][4];
#pragma unroll
  for (int i = 0; i < 4; ++i)
#pragma unroll
    for (int j = 0; j < 4; ++j) acc1[i][j] = (f32x4){0.f, 0.f, 0.f, 0.f};
#pragma unroll
  for (int ks = 0; ks < 2; ++ks) {
    bf16x8 ah[4], al[4];
#pragma unroll
    for (int fm = 0; fm < 4; ++fm) {
      int idx = ((ks * 4 + l4) * 64 + fm * 16 + l15) * 8;
      ah[fm] = *(const bf16x8*)&featH[idx];
      al[fm] = *(const bf16x8*)&featL[idx];
    }
#pragma unroll
    for (int fn = 0; fn < 4; ++fn) {
      int col = wbase + fn * 16 + l15;
      size_t boff = ((size_t)(ks * 4 + l4) * 256 + col) * 8;
      bf16x8 bh = *(const bf16x8*)(lw1H + boff);
      bf16x8 bl = *(const bf16x8*)(lw1L + boff);
#pragma unroll
      for (int fm = 0; fm < 4; ++fm) {
        acc1[fm][fn] = __builtin_amdgcn_mfma_f32_16x16x32_bf16(al[fm], bh, acc1[fm][fn], 0, 0, 0);
        acc1[fm][fn] = __builtin_amdgcn_mfma_f32_16x16x32_bf16(ah[fm], bl, acc1[fm][fn], 0, 0, 0);
        acc1[fm][fn] = __builtin_amdgcn_mfma_f32_16x16x32_bf16(ah[fm], bh, acc1[fm][fn], 0, 0, 0);
      }
    }
  }
#pragma unroll
  for (int fn = 0; fn < 4; ++fn) {
    int chan = wbase + fn * 16 + l15;
    float bias = lb1[chan];
    int kb = chan >> 3, k7 = chan & 7;
#pragma unroll
    for (int fm = 0; fm < 4; ++fm) {
#pragma unroll
      for (int r = 0; r < 4; ++r) {
        int edge = fm * 16 + l4 * 4 + r;
        float v = fmaxf(acc1[fm][fn][r] + bias, 0.f);
        ushort hi = f2bf(v);
        ushort lo = f2bf(v - bf2f(hi));
        int idx = (kb * 64 + edge) * 8 + k7;
        t1H[idx] = hi;
        t1L[idx] = lo;
      }
    }
  }
  __syncthreads();
  const ushort* lw2H = lw2s;
  const ushort* lw2L = lw2s + 32 * 256 * 8;
  f32x4 acc2[4][4];
#pragma unroll
  for (int i = 0; i < 4; ++i)
#pragma unroll
    for (int j = 0; j < 4; ++j) acc2[i][j] = (f32x4){0.f, 0.f, 0.f, 0.f};
#pragma unroll
  for (int ks = 0; ks < 8; ++ks) {
    bf16x8 ah[4], al[4];
#pragma unroll
    for (int fm = 0; fm < 4; ++fm) {
      int idx = ((ks * 4 + l4) * 64 + fm * 16 + l15) * 8;
      ah[fm] = *(const bf16x8*)&t1H[idx];
      al[fm] = *(const bf16x8*)&t1L[idx];
    }
#pragma unroll
    for (int fn = 0; fn < 4; ++fn) {
      int col = wbase + fn * 16 + l15;
      size_t boff = ((size_t)(ks * 4 + l4) * 256 + col) * 8;
      bf16x8 bh = *(const bf16x8*)(lw2H + boff);
      bf16x8 bl = *(const bf16x8*)(lw2L + boff);
#pragma unroll
      for (int fm = 0; fm < 4; ++fm) {
        acc2[fm][fn] = __builtin_amdgcn_mfma_f32_16x16x32_bf16(al[fm], bh, acc2[fm][fn], 0, 0, 0);
        acc2[fm][fn] = __builtin_amdgcn_mfma_f32_16x16x32_bf16(ah[fm], bl, acc2[fm][fn], 0, 0, 0);
        acc2[fm][fn] = __builtin_amdgcn_mfma_f32_16x16x32_bf16(ah[fm], bh, acc2[fm][fn], 0, 0, 0);
      }
    }
  }
#pragma unroll
  for (int fn = 0; fn < 4; ++fn) {
    int col = wbase + fn * 16 + l15;
    float m0 = -INFINITY, m1 = -INFINITY;
#pragma unroll
    for (int r = 0; r < 4; ++r) {
      m0 = fmaxf(m0, fmaxf(acc2[0][fn][r], acc2[1][fn][r]));
      m1 = fmaxf(m1, fmaxf(acc2[2][fn][r], acc2[3][fn][r]));
    }
    m0 = fmaxf(m0, __shfl_xor(m0, 16));
    m0 = fmaxf(m0, __shfl_xor(m0, 32));
    m1 = fmaxf(m1, __shfl_xor(m1, 16));
    m1 = fmaxf(m1, __shfl_xor(m1, 32));
    if (l4 == 0) {
      float bias = lb2[col];
      int c0 = blockIdx.x * 2;
      h[(size_t)c0 * 256 + col] = m0 + bias;
      h[(size_t)(c0 + 1) * 256 + col] = m1 + bias;
    }
  }
}

// ---------------------------------------------------------------------------
// bf16x3 split MFMA GEMM (unchanged).
// ---------------------------------------------------------------------------
template <int EPI>
__global__ __launch_bounds__(256, 2)
void gemm_x3(const float* __restrict__ A, const ushort* __restrict__ Wh,
             const ushort* __restrict__ Wl, const float* __restrict__ bias,
             const float* __restrict__ gamma, const float* __restrict__ resid,
             float* __restrict__ C, int M, int N, int K) {
  __shared__ __align__(16) ushort Ah[4096], Al[4096], Bh[4096], Bl[4096];
  int tid = threadIdx.x;
  int bn = blockIdx.x << 7, bm = blockIdx.y << 7;
  int wid = tid >> 6, lane = tid & 63;
  int wr = wid >> 1, wc = wid & 1;
  int l15 = lane & 15, l4 = lane >> 4;

  int arow = tid >> 1, akb0 = (tid & 1) << 1;
  const float* Ap = A + (size_t)(bm + arow) * K + (akb0 << 3);
  int wkb = tid >> 7, wn = tid & 127;

  f32x4 acc[4][4];
#pragma unroll
  for (int i = 0; i < 4; ++i)
#pragma unroll
    for (int j = 0; j < 4; ++j) acc[i][j] = (f32x4){0.f, 0.f, 0.f, 0.f};

  float4 a0 = *(const float4*)(Ap + 0);
  float4 a1 = *(const float4*)(Ap + 4);
  float4 a2 = *(const float4*)(Ap + 8);
  float4 a3 = *(const float4*)(Ap + 12);
  size_t wo1 = ((size_t)wkb * N + bn + wn) * 8;
  size_t wo2 = ((size_t)(wkb + 2) * N + bn + wn) * 8;
  uint4 w0 = *(const uint4*)(Wh + wo1);
  uint4 w1 = *(const uint4*)(Wh + wo2);
  uint4 w2 = *(const uint4*)(Wl + wo1);
  uint4 w3 = *(const uint4*)(Wl + wo2);

  int nkt = K >> 5;
  for (int kt = 0; kt < nkt; ++kt) {
    uint4 h0, l0, h1, l1;
    cvt8(a0, a1, h0, l0);
    cvt8(a2, a3, h1, l1);
    *(uint4*)&Ah[(akb0 * 128 + arow) * 8] = h0;
    *(uint4*)&Ah[((akb0 + 1) * 128 + arow) * 8] = h1;
    *(uint4*)&Al[(akb0 * 128 + arow) * 8] = l0;
    *(uint4*)&Al[((akb0 + 1) * 128 + arow) * 8] = l1;
    *(uint4*)&Bh[tid * 8] = w0;
    *(uint4*)&Bh[(tid + 256) * 8] = w1;
    *(uint4*)&Bl[tid * 8] = w2;
    *(uint4*)&Bl[(tid + 256) * 8] = w3;
    __syncthreads();
    if (kt + 1 < nkt) {
      const float* Apn = Ap + ((kt + 1) << 5);
      a0 = *(const float4*)(Apn + 0);
      a1 = *(const float4*)(Apn + 4);
      a2 = *(const float4*)(Apn + 8);
      a3 = *(const float4*)(Apn + 12);
      size_t b1 = ((size_t)((kt + 1) * 4 + wkb) * N + bn + wn) * 8;
      size_t b2 = ((size_t)((kt + 1) * 4 + wkb + 2) * N + bn + wn) * 8;
      w0 = *(const uint4*)(Wh + b1);
      w1 = *(const uint4*)(Wh + b2);
      w2 = *(const uint4*)(Wl + b1);
      w3 = *(const uint4*)(Wl + b2);
    }
    bf16x8 ahf[4], alf[4];
#pragma unroll
    for (int fm = 0; fm < 4; ++fm) {
      int ci = l4 * 128 + wr * 64 + fm * 16 + l15;
      ahf[fm] = *(bf16x8*)&Ah[ci * 8];
      alf[fm] = *(bf16x8*)&Al[ci * 8];
    }
#pragma unroll
    for (int fn = 0; fn < 4; ++fn) {
      int ci = l4 * 128 + wc * 64 + fn * 16 + l15;
      bf16x8 bh = *(bf16x8*)&Bh[ci * 8];
      bf16x8 bl = *(bf16x8*)&Bl[ci * 8];
#pragma unroll
      for (int fm = 0; fm < 4; ++fm) {
        acc[fm][fn] = __builtin_amdgcn_mfma_f32_16x16x32_bf16(alf[fm], bh, acc[fm][fn], 0, 0, 0);
        acc[fm][fn] = __builtin_amdgcn_mfma_f32_16x16x32_bf16(ahf[fm], bl, acc[fm][fn], 0, 0, 0);
        acc[fm][fn] = __builtin_amdgcn_mfma_f32_16x16x32_bf16(ahf[fm], bh, acc[fm][fn], 0, 0, 0);
      }
    }
    __syncthreads();
  }

#pragma unroll
  for (int fn = 0; fn < 4; ++fn) {
    int col = bn + wc * 64 + fn * 16 + l15;
    float bv = bias[col];
    float gv = (EPI == 3) ? gamma[col] : 0.f;
#pragma unroll
    for (int fm = 0; fm < 4; ++fm) {
      int row0 = bm + wr * 64 + fm * 16 + l4 * 4;
#pragma unroll
      for (int r = 0; r < 4; ++r) {
        float v = acc[fm][fn][r] + bv;
        if (EPI == 1) v = fmaxf(v, 0.f);
        else if (EPI == 2) v = gelu_f(v);
        else if (EPI == 3) v = resid[(size_t)(row0 + r) * N + col] + gv * v;
        C[(size_t)(row0 + r) * N + col] = v;
      }
    }
  }
}

// ---------------------------------------------------------------------------
// Positional-embedding add (unchanged).
// ---------------------------------------------------------------------------
__global__ __launch_bounds__(256)
void pe_add(const float* __restrict__ centers, const float* __restrict__ ew,
            const float* __restrict__ eb, float* x) {
  __shared__ float fc[51];
  int c = blockIdx.x, tid = threadIdx.x;
  if (tid < 24) {
    int a = tid >> 3, f = tid & 7;
    float coord = centers[c * 3 + a];
    float p = coord * (float)(M_PI * (double)(1 << f));
    fc[3 + tid] = sinf(p);
    fc[27 + tid] = cosf(p);
  } else if (tid < 27) {
    fc[tid - 24] = centers[c * 3 + (tid - 24)];
  }
  __syncthreads();
  for (int j = tid; j < NDIM; j += 256) {
    float acc = eb[j];
#pragma unroll
    for (int d = 0; d < 51; ++d) acc = fmaf(fc[d], ew[d * NDIM + j], acc);
    x[(size_t)c * NDIM + j] += acc;
  }
}

// ---------------------------------------------------------------------------
// LayerNorm (unchanged).
// ---------------------------------------------------------------------------
__global__ __launch_bounds__(256)
void ln_f32(const float* __restrict__ x, const float* __restrict__ g,
            const float* __restrict__ b, float* __restrict__ y) {
  int row = (blockIdx.x << 2) + (threadIdx.x >> 6);
  int lane = threadIdx.x & 63;
  const float* xr = x + (size_t)row * NDIM;
  float v[6];
#pragma unroll
  for (int i = 0; i < 6; ++i) v[i] = xr[lane + (i << 6)];
  float s = 0.f;
#pragma unroll
  for (int i = 0; i < 6; ++i) s += v[i];
#pragma unroll
  for (int off = 32; off; off >>= 1) s += __shfl_xor(s, off);
  float m = s / 384.f;
  float var = 0.f;
#pragma unroll
  for (int i = 0; i < 6; ++i) { float dd = v[i] - m; var += dd * dd; }
#pragma unroll
  for (int off = 32; off; off >>= 1) var += __shfl_xor(var, off);
  var = var / 384.f;
  float rs = 1.f / sqrtf(var + 1e-6f);
#pragma unroll
  for (int i = 0; i < 6; ++i) {
    int cc = lane + (i << 6);
    y[(size_t)row * NDIM + cc] = (v[i] - m) * rs * g[cc] + b[cc];
  }
}

// ---------------------------------------------------------------------------
// MFMA flash attention (unchanged from round 5).
// ---------------------------------------------------------------------------
__global__ __launch_bounds__(256, 2)
void attn_mfma(const float* __restrict__ qkv, float* __restrict__ o) {
  __shared__ __align__(16) ushort kTH[4096], kTL[4096];
  __shared__ __align__(16) ushort vSH[4096], vSL[4096];
  __shared__ __align__(16) ushort pSH[8192], pSL[8192];
  int bi = blockIdx.x;
  int qt = bi & 3;
  int hh = (bi >> 2) % 6;
  int b = bi / 24;
  int tid = threadIdx.x;
  int w = tid >> 6, lane = tid & 63;
  int l15 = lane & 15, l4 = lane >> 4;
  const float* base = qkv + (size_t)(b * NCTR) * 1152;
  int qbase = qt * 128 + w * 32;

  bf16x8 qh[2][2], ql[2][2];
#pragma unroll
  for (int qr = 0; qr < 2; ++qr) {
#pragma unroll
    for (int ds = 0; ds < 2; ++ds) {
      const float* qp = base + (size_t)(qbase + qr * 16 + l15) * 1152 + hh * 64 +
                        ds * 32 + l4 * 8;
      float4 f0 = *(const float4*)qp;
      float4 f1 = *(const float4*)(qp + 4);
      uint4 hi, lo;
      cvt8(f0, f1, hi, lo);
      qh[qr][ds] = *(bf16x8*)&hi;
      ql[qr][ds] = *(bf16x8*)&lo;
    }
  }

  f32x4 oacc[2][4];
#pragma unroll
  for (int i = 0; i < 2; ++i)
#pragma unroll
    for (int j = 0; j < 4; ++j) oacc[i][j] = (f32x4){0.f, 0.f, 0.f, 0.f};
  float m_[2][4], l_[2][4];
#pragma unroll
  for (int i = 0; i < 2; ++i)
#pragma unroll
    for (int r = 0; r < 4; ++r) { m_[i][r] = -INFINITY; l_[i][r] = 0.f; }

  ushort* pHw = pSH + w * 2048;
  ushort* pLw = pSL + w * 2048;

  for (int ch = 0; ch < 8; ++ch) {
    {
      int key = tid & 63, dgh = tid >> 6;
      const float* kp = base + (size_t)(ch * 64 + key) * 1152 + 384 + hh * 64;
#pragma unroll
      for (int i = 0; i < 2; ++i) {
        int dg = dgh * 2 + i;
        float4 f0 = *(const float4*)(kp + dg * 8);
        float4 f1 = *(const float4*)(kp + dg * 8 + 4);
        uint4 hi, lo;
        cvt8(f0, f1, hi, lo);
        *(uint4*)&kTH[(dg * 64 + key) * 8] = hi;
        *(uint4*)&kTL[(dg * 64 + key) * 8] = lo;
      }
      int d = tid & 63, kb2 = tid >> 6;
#pragma unroll
      for (int i = 0; i < 2; ++i) {
        int kb = kb2 + i * 4;
        float vv[8];
#pragma unroll
        for (int j = 0; j < 8; ++j)
          vv[j] = base[(size_t)(ch * 64 + kb * 8 + j) * 1152 + 768 + hh * 64 + d];
        float4 f0, f1;
        f0.x = vv[0]; f0.y = vv[1]; f0.z = vv[2]; f0.w = vv[3];
        f1.x = vv[4]; f1.y = vv[5]; f1.z = vv[6]; f1.w = vv[7];
        uint4 hi, lo;
        cvt8(f0, f1, hi, lo);
        *(uint4*)&vSH[(kb * 64 + d) * 8] = hi;
        *(uint4*)&vSL[(kb * 64 + d) * 8] = lo;
      }
    }
    __syncthreads();

    f32x4 sacc[2][4];
#pragma unroll
    for (int i = 0; i < 2; ++i)
#pragma unroll
      for (int j = 0; j < 4; ++j) sacc[i][j] = (f32x4){0.f, 0.f, 0.f, 0.f};
#pragma unroll
    for (int ds = 0; ds < 2; ++ds) {
#pragma unroll
      for (int kc = 0; kc < 4; ++kc) {
        int idx = ((ds * 4 + l4) * 64 + kc * 16 + l15) * 8;
        bf16x8 bh = *(const bf16x8*)&kTH[idx];
        bf16x8 bl = *(const bf16x8*)&kTL[idx];
#pragma unroll
        for (int qr = 0; qr < 2; ++qr) {
          sacc[qr][kc] = __builtin_amdgcn_mfma_f32_16x16x32_bf16(ql[qr][ds], bh, sacc[qr][kc], 0, 0, 0);
          sacc[qr][kc] = __builtin_amdgcn_mfma_f32_16x16x32_bf16(qh[qr][ds], bl, sacc[qr][kc], 0, 0, 0);
          sacc[qr][kc] = __builtin_amdgcn_mfma_f32_16x16x32_bf16(qh[qr][ds], bh, sacc[qr][kc], 0, 0, 0);
        }
      }
    }

    float t[2][4];
#pragma unroll
    for (int qr = 0; qr < 2; ++qr)
#pragma unroll
      for (int r = 0; r < 4; ++r) {
        float a0 = sacc[qr][0][r] * 0.125f; sacc[qr][0][r] = a0;
        float a1 = sacc[qr][1][r] * 0.125f; sacc[qr][1][r] = a1;
        float a2 = sacc[qr][2][r] * 0.125f; sacc[qr][2][r] = a2;
        float a3 = sacc[qr][3][r] * 0.125f; sacc[qr][3][r] = a3;
        t[qr][r] = fmaxf(fmaxf(a0, a1), fmaxf(a2, a3));
      }
#pragma unroll
    for (int off = 1; off < 16; off <<= 1)
#pragma unroll
      for (int qr = 0; qr < 2; ++qr)
#pragma unroll
        for (int r = 0; r < 4; ++r)
          t[qr][r] = fmaxf(t[qr][r], __shfl_xor(t[qr][r], off));
    float f_[2][4];
#pragma unroll
    for (int qr = 0; qr < 2; ++qr)
#pragma unroll
      for (int r = 0; r < 4; ++r) {
        float mn = fmaxf(m_[qr][r], t[qr][r]);
        f_[qr][r] = expf(m_[qr][r] - mn);
        m_[qr][r] = mn;
      }
#pragma unroll
    for (int qr = 0; qr < 2; ++qr)
#pragma unroll
      for (int dc = 0; dc < 4; ++dc)
#pragma unroll
        for (int r = 0; r < 4; ++r) oacc[qr][dc][r] *= f_[qr][r];
    float sm[2][4];
#pragma unroll
    for (int qr = 0; qr < 2; ++qr)
#pragma unroll
      for (int r = 0; r < 4; ++r) {
        float p0 = expf(sacc[qr][0][r] - m_[qr][r]); sacc[qr][0][r] = p0;
        float p1 = expf(sacc[qr][1][r] - m_[qr][r]); sacc[qr][1][r] = p1;
        float p2 = expf(sacc[qr][2][r] - m_[qr][r]); sacc[qr][2][r] = p2;
        float p3 = expf(sacc[qr][3][r] - m_[qr][r]); sacc[qr][3][r] = p3;
        sm[qr][r] = ((p0 + p1) + (p2 + p3));
      }
#pragma unroll
    for (int off = 1; off < 16; off <<= 1)
#pragma unroll
      for (int qr = 0; qr < 2; ++qr)
#pragma unroll
        for (int r = 0; r < 4; ++r)
          sm[qr][r] += __shfl_xor(sm[qr][r], off);
#pragma unroll
    for (int qr = 0; qr < 2; ++qr)
#pragma unroll
      for (int r = 0; r < 4; ++r) l_[qr][r] = l_[qr][r] * f_[qr][r] + sm[qr][r];

#pragma unroll
    for (int qr = 0; qr < 2; ++qr)
#pragma unroll
      for (int kc = 0; kc < 4; ++kc)
#pragma unroll
        for (int r = 0; r < 4; ++r) {
          float pv = sacc[qr][kc][r];
          ushort hi = f2bf(pv);
          ushort lo = f2bf(pv - bf2f(hi));
          int k = kc * 16 + l15;
          int qrow = qr * 16 + l4 * 4 + r;
          int idx = ((k >> 3) * 32 + qrow) * 8 + (k & 7);
          pHw[idx] = hi;
          pLw[idx] = lo;
        }

#pragma unroll
    for (int ks = 0; ks < 2; ++ks) {
      bf16x8 pah[2], pal[2];
#pragma unroll
      for (int qr = 0; qr < 2; ++qr) {
        int idx = ((ks * 4 + l4) * 32 + qr * 16 + l15) * 8;
        pah[qr] = *(const bf16x8*)&pHw[idx];
        pal[qr] = *(const bf16x8*)&pLw[idx];
      }
#pragma unroll
      for (int dc = 0; dc < 4; ++dc) {
        int idx = ((ks * 4 + l4) * 64 + dc * 16 + l15) * 8;
        bf16x8 vh = *(const bf16x8*)&vSH[idx];
        bf16x8 vl = *(const bf16x8*)&vSL[idx];
#pragma unroll
        for (int qr = 0; qr < 2; ++qr) {
          oacc[qr][dc] = __builtin_amdgcn_mfma_f32_16x16x32_bf16(pal[qr], vh, oacc[qr][dc], 0, 0, 0);
          oacc[qr][dc] = __builtin_amdgcn_mfma_f32_16x16x32_bf16(pah[qr], vl, oacc[qr][dc], 0, 0, 0);
          oacc[qr][dc] = __builtin_amdgcn_mfma_f32_16x16x32_bf16(pah[qr], vh, oacc[qr][dc], 0, 0, 0);
        }
      }
    }
    __syncthreads();
  }

  float il[2][4];
#pragma unroll
  for (int qr = 0; qr < 2; ++qr)
#pragma unroll
    for (int r = 0; r < 4; ++r) il[qr][r] = 1.f / l_[qr][r];
#pragma unroll
  for (int qr = 0; qr < 2; ++qr)
#pragma unroll
    for (int dc = 0; dc < 4; ++dc)
#pragma unroll
      for (int r = 0; r < 4; ++r) {
        int row = b * NCTR + qbase + qr * 16 + l4 * 4 + r;
        int col = hh * 64 + dc * 16 + l15;
        o[(size_t)row * NDIM + col] = oacc[qr][dc][r] * il[qr][r];
      }
}

// ---------------------------------------------------------------------------
extern "C" void kernel_launch(void* const* d_in, const int* in_sizes, int n_in,
                              void* d_out, int out_size, void* d_ws, size_t ws_size,
                              hipStream_t stream) {
  const float* pc      = (const float*)d_in[0];
  const float* embed_w = (const float*)d_in[1];
  const float* embed_b = (const float*)d_in[2];
  const float* lw1     = (const float*)d_in[3];
  const float* lb1     = (const float*)d_in[4];
  const float* lw2     = (const float*)d_in[5];
  const float* lb2     = (const float*)d_in[6];
  const float* gw1     = (const float*)d_in[7];
  const float* gb1     = (const float*)d_in[8];
  const float* gw2     = (const float*)d_in[9];
  const float* gb2     = (const float*)d_in[10];
  const float* ln1_g   = (const float*)d_in[11];
  const float* ln1_b   = (const float*)d_in[12];
  const float* qkv_w   = (const float*)d_in[13];
  const float* qkv_b   = (const float*)d_in[14];
  const float* proj_w  = (const float*)d_in[15];
  const float* proj_b  = (const float*)d_in[16];
  const float* gamma1  = (const float*)d_in[17];
  const float* ln2_g   = (const float*)d_in[18];
  const float* ln2_b   = (const float*)d_in[19];
  const float* fc1_w   = (const float*)d_in[20];
  const float* fc1_b   = (const float*)d_in[21];
  const float* fc2_w   = (const float*)d_in[22];
  const float* fc2_b   = (const float*)d_in[23];
  const float* gamma2  = (const float*)d_in[24];
  const float* lnf_g   = (const float*)d_in[25];
  const float* lnf_b   = (const float*)d_in[26];

  float* out = (float*)d_out;
  float* centers = out + (size_t)NB * NCTR * NDIM;

  int* nn = (int*)d_ws;
  float* fws = (float*)d_ws;
  float* h  = fws + 262144;            // [8192,256]
  float* x  = h + 8192 * 256;          // [8192,384]
  float* xn = x + 8192 * 384;          // [8192,384]
  float* F  = xn + 8192 * 384;         // [8192,1536]
  ushort* wsplit = (ushort*)(fws + 21233664);

  // --- weight pre-split (bf16 hi/lo, MFMA layout) ---
  size_t wofs = 0;
  ushort* qkvH[6]; ushort* projH[6]; ushort* fc1H[6]; ushort* fc2H[6];
  auto convp = [&](const float* w, int Kpad, int N, int Ksrc) -> ushort* {
    ushort* dst = wsplit + wofs;
    int K8 = Kpad >> 3, total = K8 * N;
    wconv<<<(total + 255) / 256, 256, 0, stream>>>(w, dst, K8, N, Ksrc);
    wofs += (size_t)2 * Kpad * N;
    return dst;
  };
  for (int l = 0; l < 6; ++l) qkvH[l] = convp(qkv_w + (size_t)l * 384 * 1152, 384, 1152, 384);
  for (int l = 0; l < 6; ++l) projH[l] = convp(proj_w + (size_t)l * 384 * 384, 384, 384, 384);
  for (int l = 0; l < 6; ++l) fc1H[l] = convp(fc1_w + (size_t)l * 384 * 1536, 384, 1536, 384);
  for (int l = 0; l < 6; ++l) fc2H[l] = convp(fc2_w + (size_t)l * 1536 * 384, 1536, 384, 1536);
  ushort* g1H = convp(gw1, 256, 256, 256);
  ushort* g2H = convp(gw2, 256, 384, 256);
  ushort* lw1s = convp(lw1, 64, 256, 51);
  ushort* lw2s = convp(lw2, 256, 256, 256);

  // --- geometry + fused edge pipeline ---
  fps_kernel<<<NB, 256, 0, stream>>>(pc, centers);
  knn_kernel<<<2048, 256, 0, stream>>>(pc, centers, nn);
  edge_mfma<<<4096, 256, 0, stream>>>(pc, centers, nn, lw1s, lb1, lw2s, lb2, h);

  gemm_x3<1><<<dim3(2, 64), 256, 0, stream>>>(h, g1H, g1H + 256 * 256, gb1,
                                              nullptr, nullptr, xn, 8192, 256, 256);
  gemm_x3<0><<<dim3(3, 64), 256, 0, stream>>>(xn, g2H, g2H + 256 * 384, gb2,
                                              nullptr, nullptr, x, 8192, 384, 256);
  pe_add<<<8192, 256, 0, stream>>>(centers, embed_w, embed_b, x);

  for (int l = 0; l < 6; ++l) {
    ln_f32<<<2048, 256, 0, stream>>>(x, ln1_g + l * 384, ln1_b + l * 384, xn);
    gemm_x3<0><<<dim3(9, 64), 256, 0, stream>>>(
        xn, qkvH[l], qkvH[l] + 384 * 1152, qkv_b + l * 1152, nullptr, nullptr, F,
        8192, 1152, 384);
    attn_mfma<<<384, 256, 0, stream>>>(F, xn);
    gemm_x3<3><<<dim3(3, 64), 256, 0, stream>>>(
        xn, projH[l], projH[l] + 384 * 384, proj_b + l * 384, gamma1 + l * 384, x, x,
        8192, 384, 384);
    ln_f32<<<2048, 256, 0, stream>>>(x, ln2_g + l * 384, ln2_b + l * 384, xn);
    gemm_x3<2><<<dim3(12, 64), 256, 0, stream>>>(
        xn, fc1H[l], fc1H[l] + 384 * 1536, fc1_b + l * 1536, nullptr, nullptr, F,
        8192, 1536, 384);
    gemm_x3<3><<<dim3(3, 64), 256, 0, stream>>>(
        F, fc2H[l], fc2H[l] + 1536 * 384, fc2_b + l * 384, gamma2 + l * 384, x, x,
        8192, 384, 1536);
  }
  ln_f32<<<2048, 256, 0, stream>>>(x, lnf_g, lnf_b, out);
}

// Round 7
// 2025.549 us; speedup vs baseline: 2.2720x; 1.0233x over previous
//
#include <hip/hip_runtime.h>
#include <math.h>

#define NB 16
#define NM 2048
#define NCTR 512
#define NK 32
#define NDIM 384

typedef unsigned long long ull;
typedef unsigned int uint;
typedef unsigned short ushort;
typedef __attribute__((ext_vector_type(8))) short bf16x8;
typedef __attribute__((ext_vector_type(4))) float f32x4;

// Exact (no-FMA-contraction) squared distance, matching XLA's per-op fp32.
__device__ __forceinline__ float dist2_exact(float ax, float ay, float az,
                                             float bx, float by, float bz) {
  float dx = __fsub_rn(ax, bx);
  float dy = __fsub_rn(ay, by);
  float dz = __fsub_rn(az, bz);
  return __fadd_rn(__fadd_rn(__fmul_rn(dx, dx), __fmul_rn(dy, dy)),
                   __fmul_rn(dz, dz));
}

__device__ __forceinline__ float gelu_f(float x) {
  return 0.5f * x * (1.0f + erff(x * 0.70710678118654752f));
}

// fp32 -> bf16 round-to-nearest-even (bit trick), and back.
__device__ __forceinline__ ushort f2bf(float f) {
  uint u = __float_as_uint(f);
  return (ushort)((u + 0x7FFFu + ((u >> 16) & 1u)) >> 16);
}
__device__ __forceinline__ float bf2f(ushort h) {
  return __uint_as_float(((uint)h) << 16);
}

// Split 8 fp32 into bf16 hi / lo packed words (2 bf16 per uint).
__device__ __forceinline__ void cvt8(float4 p, float4 q, uint4& hi, uint4& lo) {
  float v0 = p.x, v1 = p.y, v2 = p.z, v3 = p.w;
  float v4 = q.x, v5 = q.y, v6 = q.z, v7 = q.w;
  ushort h0 = f2bf(v0), h1 = f2bf(v1), h2 = f2bf(v2), h3 = f2bf(v3);
  ushort h4 = f2bf(v4), h5 = f2bf(v5), h6 = f2bf(v6), h7 = f2bf(v7);
  ushort l0 = f2bf(v0 - bf2f(h0)), l1 = f2bf(v1 - bf2f(h1));
  ushort l2 = f2bf(v2 - bf2f(h2)), l3 = f2bf(v3 - bf2f(h3));
  ushort l4 = f2bf(v4 - bf2f(h4)), l5 = f2bf(v5 - bf2f(h5));
  ushort l6 = f2bf(v6 - bf2f(h6)), l7 = f2bf(v7 - bf2f(h7));
  hi.x = (uint)h0 | ((uint)h1 << 16); hi.y = (uint)h2 | ((uint)h3 << 16);
  hi.z = (uint)h4 | ((uint)h5 << 16); hi.w = (uint)h6 | ((uint)h7 << 16);
  lo.x = (uint)l0 | ((uint)l1 << 16); lo.y = (uint)l2 | ((uint)l3 << 16);
  lo.z = (uint)l4 | ((uint)l5 << 16); lo.w = (uint)l6 | ((uint)l7 << 16);
}

__device__ __forceinline__ void split_store(float v, ushort* H, ushort* L,
                                            size_t off) {
  ushort hi = f2bf(v);
  H[off] = hi;
  L[off] = f2bf(v - bf2f(hi));
}

// ---------------------------------------------------------------------------
// FPS v2 (unchanged).
// ---------------------------------------------------------------------------
__global__ __launch_bounds__(256)
void fps_kernel(const float* __restrict__ pc, float* __restrict__ centers) {
  int b = blockIdx.x;
  __shared__ float4 pos4[NM];
  __shared__ ull red[2][4];
  const float* pb = pc + (size_t)b * (NM * 3);
  int tid = threadIdx.x, lane = tid & 63, wv = tid >> 6;
  float px[8], py[8], pz[8];
#pragma unroll
  for (int i = 0; i < 8; ++i) {
    int p = tid + 256 * i;
    float x = pb[3 * p], y = pb[3 * p + 1], z = pb[3 * p + 2];
    px[i] = x; py[i] = y; pz[i] = z;
    pos4[p] = make_float4(x, y, z, 0.f);
  }
  __syncthreads();
  float* cb = centers + (size_t)b * (NCTR * 3);
  float4 s0 = pos4[0];
  float sx = s0.x, sy = s0.y, sz = s0.z;
  if (tid == 0) { cb[0] = sx; cb[1] = sy; cb[2] = sz; }
  float d[8];
  for (int n = 1; n < NCTR; ++n) {
    ull best = 0;
#pragma unroll
    for (int i = 0; i < 8; ++i) {
      int p = tid + 256 * i;
      float nd = dist2_exact(px[i], py[i], pz[i], sx, sy, sz);
      d[i] = (n == 1) ? nd : fminf(d[i], nd);
      ull key = ((ull)__float_as_uint(d[i]) << 32) | (unsigned)(0x7FFFFFFF - p);
      best = best > key ? best : key;
    }
#pragma unroll
    for (int off = 32; off; off >>= 1) {
      ull o = __shfl_xor(best, off);
      best = best > o ? best : o;
    }
    if (lane == 0) red[n & 1][wv] = best;
    __syncthreads();
    ull g0 = red[n & 1][0], g1 = red[n & 1][1];
    ull g2 = red[n & 1][2], g3 = red[n & 1][3];
    ull ga = g0 > g1 ? g0 : g1;
    ull gc2 = g2 > g3 ? g2 : g3;
    ull gb = ga > gc2 ? ga : gc2;
    int j = 0x7FFFFFFF - (int)(unsigned)(gb & 0xFFFFFFFFull);
    float4 np = pos4[j];
    sx = np.x; sy = np.y; sz = np.z;
    if (tid == 0) { cb[n * 3] = sx; cb[n * 3 + 1] = sy; cb[n * 3 + 2] = sz; }
  }
}

// ---------------------------------------------------------------------------
// KNN v2 (unchanged from round 6 — spill-free).
// ---------------------------------------------------------------------------
__global__ __launch_bounds__(256, 2)
void knn_kernel(const float* __restrict__ pc, const float* __restrict__ centers,
                int* __restrict__ nn) {
  __shared__ float pos[NM * 3];
  int b = blockIdx.x >> 7;
  int n0 = (blockIdx.x & 127) << 2;
  const float* pb = pc + (size_t)b * (NM * 3);
  for (int i = threadIdx.x; i < NM * 3; i += 256) pos[i] = pb[i];
  __syncthreads();
  int wv = threadIdx.x >> 6, lane = threadIdx.x & 63;
  int gc = b * NCTR + n0 + wv;
  float cx = centers[gc * 3], cy = centers[gc * 3 + 1], cz = centers[gc * 3 + 2];
  ull key[32];
  ull gmin[4];
#pragma unroll
  for (int g = 0; g < 4; ++g) {
    gmin[g] = ~0ull;
#pragma unroll
    for (int i = 0; i < 8; ++i) {
      int r = g * 8 + i;
      int p = lane + (r << 6);
      float nd = dist2_exact(pos[3 * p], pos[3 * p + 1], pos[3 * p + 2], cx, cy, cz);
      key[r] = ((ull)__float_as_uint(nd) << 11) | (unsigned)p;
      gmin[g] = gmin[g] < key[r] ? gmin[g] : key[r];
    }
  }
  ull a01 = gmin[0] < gmin[1] ? gmin[0] : gmin[1];
  ull a23 = gmin[2] < gmin[3] ? gmin[2] : gmin[3];
  ull lmin = a01 < a23 ? a01 : a23;
  int* nnc = nn + (size_t)gc * NK;
  for (int round = 0; round < NK; ++round) {
    ull w = lmin;
#pragma unroll
    for (int off = 32; off; off >>= 1) {
      ull o = __shfl_xor(w, off);
      w = w < o ? w : o;
    }
    if (lmin == w) {
      nnc[round] = (int)(w & 2047ull);
#pragma unroll
      for (int g = 0; g < 4; ++g) {
        if (gmin[g] == w) {
          gmin[g] = ~0ull;
#pragma unroll
          for (int i = 0; i < 8; ++i) {
            int r = g * 8 + i;
            key[r] = (key[r] == w) ? ~0ull : key[r];
            gmin[g] = gmin[g] < key[r] ? gmin[g] : key[r];
          }
        }
      }
      ull b01 = gmin[0] < gmin[1] ? gmin[0] : gmin[1];
      ull b23 = gmin[2] < gmin[3] ? gmin[2] : gmin[3];
      lmin = b01 < b23 ? b01 : b23;
    }
  }
}

// ---------------------------------------------------------------------------
// Weight pre-split (unchanged; now called once per stacked family).
// ---------------------------------------------------------------------------
__global__ __launch_bounds__(256)
void wconv(const float* __restrict__ W, ushort* __restrict__ out, int K8, int N,
           int Ksrc) {
  int c = blockIdx.x * 256 + threadIdx.x;
  if (c >= K8 * N) return;
  int kb = c / N, n = c - kb * N;
  float v[8];
#pragma unroll
  for (int i = 0; i < 8; ++i) {
    int row = kb * 8 + i;
    v[i] = (row < Ksrc) ? W[(size_t)row * N + n] : 0.f;
  }
  float4 p, q;
  p.x = v[0]; p.y = v[1]; p.z = v[2]; p.w = v[3];
  q.x = v[4]; q.y = v[5]; q.z = v[6]; q.w = v[7];
  uint4 hi, lo;
  cvt8(p, q, hi, lo);
  *(uint4*)(out + (size_t)c * 8) = hi;
  *(uint4*)(out + (size_t)(K8 * N + c) * 8) = lo;
}

// ---------------------------------------------------------------------------
// Fused edge pipeline (round-3 structure; h now emitted as split planes).
// ---------------------------------------------------------------------------
__global__ __launch_bounds__(256, 2)
void edge_mfma(const float* __restrict__ pc, const float* __restrict__ centers,
               const int* __restrict__ nn, const ushort* __restrict__ lw1s,
               const float* __restrict__ lb1, const ushort* __restrict__ lw2s,
               const float* __restrict__ lb2, ushort* __restrict__ hH,
               ushort* __restrict__ hL) {
  __shared__ __align__(16) ushort featH[4096], featL[4096];
  __shared__ __align__(16) ushort t1H[16384], t1L[16384];
  int tid = threadIdx.x;
  int w = tid >> 6, lane = tid & 63;
  int l15 = lane & 15, l4 = lane >> 4;
  int wbase = w << 6;
  {
    int e = tid >> 2, s = tid & 3;
    int ge = blockIdx.x * 64 + e;
    int c = ge >> 5;
    int b = c >> 9;
    int j = nn[ge];
    const float* sp = pc + ((size_t)b * NM + j) * 3;
    float rx = sp[0] - centers[c * 3];
    float ry = sp[1] - centers[c * 3 + 1];
    float rz = sp[2] - centers[c * 3 + 2];
    auto putk = [&](int k, float v) {
      ushort hi = f2bf(v);
      ushort lo = f2bf(v - bf2f(hi));
      int idx = ((k >> 3) * 64 + e) * 8 + (k & 7);
      featH[idx] = hi;
      featL[idx] = lo;
    };
    if (s < 3) {
      float r = (s == 0) ? rx : (s == 1) ? ry : rz;
#pragma unroll
      for (int f = 0; f < 8; ++f) {
        float ef = (float)(M_PI * (double)(1 << f));
        float p = r * ef;
        putk(3 + 8 * s + f, sinf(p));
        putk(27 + 8 * s + f, cosf(p));
      }
    } else {
      putk(0, rx);
      putk(1, ry);
      putk(2, rz);
#pragma unroll
      for (int k = 51; k < 64; ++k) putk(k, 0.f);
    }
  }
  __syncthreads();
  const ushort* lw1H = lw1s;
  const ushort* lw1L = lw1s + 8 * 256 * 8;
  f32x4 acc1[4][4];
#pragma unroll
  for (int i = 0; i < 4; ++i)
#pragma unroll
    for (int j = 0; j < 4; ++j) acc1[i][j] = (f32x4){0.f, 0.f, 0.f, 0.f};
#pragma unroll
  for (int ks = 0; ks < 2; ++ks) {
    bf16x8 ah[4], al[4];
#pragma unroll
    for (int fm = 0; fm < 4; ++fm) {
      int idx = ((ks * 4 + l4) * 64 + fm * 16 + l15) * 8;
      ah[fm] = *(const bf16x8*)&featH[idx];
      al[fm] = *(const bf16x8*)&featL[idx];
    }
#pragma unroll
    for (int fn = 0; fn < 4; ++fn) {
      int col = wbase + fn * 16 + l15;
      size_t boff = ((size_t)(ks * 4 + l4) * 256 + col) * 8;
      bf16x8 bh = *(const bf16x8*)(lw1H + boff);
      bf16x8 bl = *(const bf16x8*)(lw1L + boff);
#pragma unroll
      for (int fm = 0; fm < 4; ++fm) {
        acc1[fm][fn] = __builtin_amdgcn_mfma_f32_16x16x32_bf16(al[fm], bh, acc1[fm][fn], 0, 0, 0);
        acc1[fm][fn] = __builtin_amdgcn_mfma_f32_16x16x32_bf16(ah[fm], bl, acc1[fm][fn], 0, 0, 0);
        acc1[fm][fn] = __builtin_amdgcn_mfma_f32_16x16x32_bf16(ah[fm], bh, acc1[fm][fn], 0, 0, 0);
      }
    }
  }
#pragma unroll
  for (int fn = 0; fn < 4; ++fn) {
    int chan = wbase + fn * 16 + l15;
    float bias = lb1[chan];
    int kb = chan >> 3, k7 = chan & 7;
#pragma unroll
    for (int fm = 0; fm < 4; ++fm) {
#pragma unroll
      for (int r = 0; r < 4; ++r) {
        int edge = fm * 16 + l4 * 4 + r;
        float v = fmaxf(acc1[fm][fn][r] + bias, 0.f);
        ushort hi = f2bf(v);
        ushort lo = f2bf(v - bf2f(hi));
        int idx = (kb * 64 + edge) * 8 + k7;
        t1H[idx] = hi;
        t1L[idx] = lo;
      }
    }
  }
  __syncthreads();
  const ushort* lw2H = lw2s;
  const ushort* lw2L = lw2s + 32 * 256 * 8;
  f32x4 acc2[4][4];
#pragma unroll
  for (int i = 0; i < 4; ++i)
#pragma unroll
    for (int j = 0; j < 4; ++j) acc2[i][j] = (f32x4){0.f, 0.f, 0.f, 0.f};
#pragma unroll
  for (int ks = 0; ks < 8; ++ks) {
    bf16x8 ah[4], al[4];
#pragma unroll
    for (int fm = 0; fm < 4; ++fm) {
      int idx = ((ks * 4 + l4) * 64 + fm * 16 + l15) * 8;
      ah[fm] = *(const bf16x8*)&t1H[idx];
      al[fm] = *(const bf16x8*)&t1L[idx];
    }
#pragma unroll
    for (int fn = 0; fn < 4; ++fn) {
      int col = wbase + fn * 16 + l15;
      size_t boff = ((size_t)(ks * 4 + l4) * 256 + col) * 8;
      bf16x8 bh = *(const bf16x8*)(lw2H + boff);
      bf16x8 bl = *(const bf16x8*)(lw2L + boff);
#pragma unroll
      for (int fm = 0; fm < 4; ++fm) {
        acc2[fm][fn] = __builtin_amdgcn_mfma_f32_16x16x32_bf16(al[fm], bh, acc2[fm][fn], 0, 0, 0);
        acc2[fm][fn] = __builtin_amdgcn_mfma_f32_16x16x32_bf16(ah[fm], bl, acc2[fm][fn], 0, 0, 0);
        acc2[fm][fn] = __builtin_amdgcn_mfma_f32_16x16x32_bf16(ah[fm], bh, acc2[fm][fn], 0, 0, 0);
      }
    }
  }
#pragma unroll
  for (int fn = 0; fn < 4; ++fn) {
    int col = wbase + fn * 16 + l15;
    float m0 = -INFINITY, m1 = -INFINITY;
#pragma unroll
    for (int r = 0; r < 4; ++r) {
      m0 = fmaxf(m0, fmaxf(acc2[0][fn][r], acc2[1][fn][r]));
      m1 = fmaxf(m1, fmaxf(acc2[2][fn][r], acc2[3][fn][r]));
    }
    m0 = fmaxf(m0, __shfl_xor(m0, 16));
    m0 = fmaxf(m0, __shfl_xor(m0, 32));
    m1 = fmaxf(m1, __shfl_xor(m1, 16));
    m1 = fmaxf(m1, __shfl_xor(m1, 32));
    if (l4 == 0) {
      float bias = lb2[col];
      int c0 = blockIdx.x * 2;
      split_store(m0 + bias, hH, hL, (size_t)c0 * 256 + col);
      split_store(m1 + bias, hH, hL, (size_t)(c0 + 1) * 256 + col);
    }
  }
}

// ---------------------------------------------------------------------------
// Split-plane MFMA GEMM: A given as bf16 hi/lo row-major planes (no in-loop
// cvt). EPI: 0=bias 1=relu 2=gelu 3=resid+gamma*(.). OUTS: 0=fp32 C,
// 1=split planes CH/CL.
// ---------------------------------------------------------------------------
template <int EPI, int OUTS>
__global__ __launch_bounds__(256, 2)
void gemm_s(const ushort* __restrict__ AH, const ushort* __restrict__ AL,
            const ushort* __restrict__ Wh, const ushort* __restrict__ Wl,
            const float* __restrict__ bias, const float* __restrict__ gamma,
            const float* __restrict__ resid, float* __restrict__ C,
            ushort* __restrict__ CH, ushort* __restrict__ CL,
            int M, int N, int K) {
  __shared__ __align__(16) ushort Ah[4096], Al[4096], Bh[4096], Bl[4096];
  int tid = threadIdx.x;
  int bn = blockIdx.x << 7, bm = blockIdx.y << 7;
  int wid = tid >> 6, lane = tid & 63;
  int wr = wid >> 1, wc = wid & 1;
  int l15 = lane & 15, l4 = lane >> 4;

  int arow = tid >> 1, akb0 = (tid & 1) << 1;
  const ushort* ApH = AH + (size_t)(bm + arow) * K + (akb0 << 3);
  const ushort* ApL = AL + (size_t)(bm + arow) * K + (akb0 << 3);
  int wkb = tid >> 7, wn = tid & 127;

  f32x4 acc[4][4];
#pragma unroll
  for (int i = 0; i < 4; ++i)
#pragma unroll
    for (int j = 0; j < 4; ++j) acc[i][j] = (f32x4){0.f, 0.f, 0.f, 0.f};

  uint4 a0 = *(const uint4*)(ApH + 0);
  uint4 a1 = *(const uint4*)(ApH + 8);
  uint4 a2 = *(const uint4*)(ApL + 0);
  uint4 a3 = *(const uint4*)(ApL + 8);
  size_t wo1 = ((size_t)wkb * N + bn + wn) * 8;
  size_t wo2 = ((size_t)(wkb + 2) * N + bn + wn) * 8;
  uint4 w0 = *(const uint4*)(Wh + wo1);
  uint4 w1 = *(const uint4*)(Wh + wo2);
  uint4 w2 = *(const uint4*)(Wl + wo1);
  uint4 w3 = *(const uint4*)(Wl + wo2);

  int nkt = K >> 5;
  for (int kt = 0; kt < nkt; ++kt) {
    *(uint4*)&Ah[(akb0 * 128 + arow) * 8] = a0;
    *(uint4*)&Ah[((akb0 + 1) * 128 + arow) * 8] = a1;
    *(uint4*)&Al[(akb0 * 128 + arow) * 8] = a2;
    *(uint4*)&Al[((akb0 + 1) * 128 + arow) * 8] = a3;
    *(uint4*)&Bh[tid * 8] = w0;
    *(uint4*)&Bh[(tid + 256) * 8] = w1;
    *(uint4*)&Bl[tid * 8] = w2;
    *(uint4*)&Bl[(tid + 256) * 8] = w3;
    __syncthreads();
    if (kt + 1 < nkt) {
      a0 = *(const uint4*)(ApH + (kt + 1) * 32 + 0);
      a1 = *(const uint4*)(ApH + (kt + 1) * 32 + 8);
      a2 = *(const uint4*)(ApL + (kt + 1) * 32 + 0);
      a3 = *(const uint4*)(ApL + (kt + 1) * 32 + 8);
      size_t b1 = ((size_t)((kt + 1) * 4 + wkb) * N + bn + wn) * 8;
      size_t b2 = ((size_t)((kt + 1) * 4 + wkb + 2) * N + bn + wn) * 8;
      w0 = *(const uint4*)(Wh + b1);
      w1 = *(const uint4*)(Wh + b2);
      w2 = *(const uint4*)(Wl + b1);
      w3 = *(const uint4*)(Wl + b2);
    }
    bf16x8 ahf[4], alf[4];
#pragma unroll
    for (int fm = 0; fm < 4; ++fm) {
      int ci = l4 * 128 + wr * 64 + fm * 16 + l15;
      ahf[fm] = *(bf16x8*)&Ah[ci * 8];
      alf[fm] = *(bf16x8*)&Al[ci * 8];
    }
#pragma unroll
    for (int fn = 0; fn < 4; ++fn) {
      int ci = l4 * 128 + wc * 64 + fn * 16 + l15;
      bf16x8 bh = *(bf16x8*)&Bh[ci * 8];
      bf16x8 bl = *(bf16x8*)&Bl[ci * 8];
#pragma unroll
      for (int fm = 0; fm < 4; ++fm) {
        acc[fm][fn] = __builtin_amdgcn_mfma_f32_16x16x32_bf16(alf[fm], bh, acc[fm][fn], 0, 0, 0);
        acc[fm][fn] = __builtin_amdgcn_mfma_f32_16x16x32_bf16(ahf[fm], bl, acc[fm][fn], 0, 0, 0);
        acc[fm][fn] = __builtin_amdgcn_mfma_f32_16x16x32_bf16(ahf[fm], bh, acc[fm][fn], 0, 0, 0);
      }
    }
    __syncthreads();
  }

#pragma unroll
  for (int fn = 0; fn < 4; ++fn) {
    int col = bn + wc * 64 + fn * 16 + l15;
    float bv = bias[col];
    float gv = (EPI == 3) ? gamma[col] : 0.f;
#pragma unroll
    for (int fm = 0; fm < 4; ++fm) {
      int row0 = bm + wr * 64 + fm * 16 + l4 * 4;
#pragma unroll
      for (int r = 0; r < 4; ++r) {
        float v = acc[fm][fn][r] + bv;
        if (EPI == 1) v = fmaxf(v, 0.f);
        else if (EPI == 2) v = gelu_f(v);
        else if (EPI == 3) v = resid[(size_t)(row0 + r) * N + col] + gv * v;
        size_t off = (size_t)(row0 + r) * N + col;
        if (OUTS == 0) C[off] = v;
        else split_store(v, CH, CL, off);
      }
    }
  }
}

// ---------------------------------------------------------------------------
// Positional-embedding add (unchanged; x stays fp32).
// ---------------------------------------------------------------------------
__global__ __launch_bounds__(256)
void pe_add(const float* __restrict__ centers, const float* __restrict__ ew,
            const float* __restrict__ eb, float* x) {
  __shared__ float fc[51];
  int c = blockIdx.x, tid = threadIdx.x;
  if (tid < 24) {
    int a = tid >> 3, f = tid & 7;
    float coord = centers[c * 3 + a];
    float p = coord * (float)(M_PI * (double)(1 << f));
    fc[3 + tid] = sinf(p);
    fc[27 + tid] = cosf(p);
  } else if (tid < 27) {
    fc[tid - 24] = centers[c * 3 + (tid - 24)];
  }
  __syncthreads();
  for (int j = tid; j < NDIM; j += 256) {
    float acc = eb[j];
#pragma unroll
    for (int d = 0; d < 51; ++d) acc = fmaf(fc[d], ew[d * NDIM + j], acc);
    x[(size_t)c * NDIM + j] += acc;
  }
}

// ---------------------------------------------------------------------------
// LayerNorm fp32-out (final) and split-out (in-loop).
// ---------------------------------------------------------------------------
__global__ __launch_bounds__(256)
void ln_f32(const float* __restrict__ x, const float* __restrict__ g,
            const float* __restrict__ b, float* __restrict__ y) {
  int row = (blockIdx.x << 2) + (threadIdx.x >> 6);
  int lane = threadIdx.x & 63;
  const float* xr = x + (size_t)row * NDIM;
  float v[6];
#pragma unroll
  for (int i = 0; i < 6; ++i) v[i] = xr[lane + (i << 6)];
  float s = 0.f;
#pragma unroll
  for (int i = 0; i < 6; ++i) s += v[i];
#pragma unroll
  for (int off = 32; off; off >>= 1) s += __shfl_xor(s, off);
  float m = s / 384.f;
  float var = 0.f;
#pragma unroll
  for (int i = 0; i < 6; ++i) { float dd = v[i] - m; var += dd * dd; }
#pragma unroll
  for (int off = 32; off; off >>= 1) var += __shfl_xor(var, off);
  var = var / 384.f;
  float rs = 1.f / sqrtf(var + 1e-6f);
#pragma unroll
  for (int i = 0; i < 6; ++i) {
    int cc = lane + (i << 6);
    y[(size_t)row * NDIM + cc] = (v[i] - m) * rs * g[cc] + b[cc];
  }
}

__global__ __launch_bounds__(256)
void ln_split(const float* __restrict__ x, const float* __restrict__ g,
              const float* __restrict__ b, ushort* __restrict__ yH,
              ushort* __restrict__ yL) {
  int row = (blockIdx.x << 2) + (threadIdx.x >> 6);
  int lane = threadIdx.x & 63;
  const float* xr = x + (size_t)row * NDIM;
  float v[6];
#pragma unroll
  for (int i = 0; i < 6; ++i) v[i] = xr[lane + (i << 6)];
  float s = 0.f;
#pragma unroll
  for (int i = 0; i < 6; ++i) s += v[i];
#pragma unroll
  for (int off = 32; off; off >>= 1) s += __shfl_xor(s, off);
  float m = s / 384.f;
  float var = 0.f;
#pragma unroll
  for (int i = 0; i < 6; ++i) { float dd = v[i] - m; var += dd * dd; }
#pragma unroll
  for (int off = 32; off; off >>= 1) var += __shfl_xor(var, off);
  var = var / 384.f;
  float rs = 1.f / sqrtf(var + 1e-6f);
#pragma unroll
  for (int i = 0; i < 6; ++i) {
    int cc = lane + (i << 6);
    float yv = (v[i] - m) * rs * g[cc] + b[cc];
    split_store(yv, yH, yL, (size_t)row * NDIM + cc);
  }
}

// ---------------------------------------------------------------------------
// MFMA flash attention on split planes: Q frags direct from global; K/V
// staging is pure data movement (no cvt). Output emitted as split planes.
// ---------------------------------------------------------------------------
__global__ __launch_bounds__(256, 2)
void attn_mfma(const ushort* __restrict__ FH, const ushort* __restrict__ FL,
               ushort* __restrict__ oH, ushort* __restrict__ oL) {
  __shared__ __align__(16) ushort kTH[4096], kTL[4096];
  __shared__ __align__(16) ushort vSH[4096], vSL[4096];
  __shared__ __align__(16) ushort pSH[8192], pSL[8192];
  int bi = blockIdx.x;
  int qt = bi & 3;
  int hh = (bi >> 2) % 6;
  int b = bi / 24;
  int tid = threadIdx.x;
  int w = tid >> 6, lane = tid & 63;
  int l15 = lane & 15, l4 = lane >> 4;
  const ushort* baseH = FH + (size_t)(b * NCTR) * 1152;
  const ushort* baseL = FL + (size_t)(b * NCTR) * 1152;
  int qbase = qt * 128 + w * 32;

  bf16x8 qh[2][2], ql[2][2];
#pragma unroll
  for (int qr = 0; qr < 2; ++qr) {
#pragma unroll
    for (int ds = 0; ds < 2; ++ds) {
      size_t off = (size_t)(qbase + qr * 16 + l15) * 1152 + hh * 64 + ds * 32 + l4 * 8;
      qh[qr][ds] = *(const bf16x8*)(baseH + off);
      ql[qr][ds] = *(const bf16x8*)(baseL + off);
    }
  }

  f32x4 oacc[2][4];
#pragma unroll
  for (int i = 0; i < 2; ++i)
#pragma unroll
    for (int j = 0; j < 4; ++j) oacc[i][j] = (f32x4){0.f, 0.f, 0.f, 0.f};
  float m_[2][4], l_[2][4];
#pragma unroll
  for (int i = 0; i < 2; ++i)
#pragma unroll
    for (int r = 0; r < 4; ++r) { m_[i][r] = -INFINITY; l_[i][r] = 0.f; }

  ushort* pHw = pSH + w * 2048;
  ushort* pLw = pSL + w * 2048;

  for (int ch = 0; ch < 8; ++ch) {
    {
      int key = tid & 63, dgh = tid >> 6;
      size_t krow = (size_t)(ch * 64 + key) * 1152 + 384 + hh * 64;
#pragma unroll
      for (int i = 0; i < 2; ++i) {
        int dg = dgh * 2 + i;
        *(uint4*)&kTH[(dg * 64 + key) * 8] = *(const uint4*)(baseH + krow + dg * 8);
        *(uint4*)&kTL[(dg * 64 + key) * 8] = *(const uint4*)(baseL + krow + dg * 8);
      }
      int d = tid & 63, kb2 = tid >> 6;
#pragma unroll
      for (int i = 0; i < 2; ++i) {
        int kb = kb2 + i * 4;
        ushort hv[8], lv[8];
#pragma unroll
        for (int j = 0; j < 8; ++j) {
          size_t off = (size_t)(ch * 64 + kb * 8 + j) * 1152 + 768 + hh * 64 + d;
          hv[j] = baseH[off];
          lv[j] = baseL[off];
        }
        uint4 H, L;
        H.x = (uint)hv[0] | ((uint)hv[1] << 16); H.y = (uint)hv[2] | ((uint)hv[3] << 16);
        H.z = (uint)hv[4] | ((uint)hv[5] << 16); H.w = (uint)hv[6] | ((uint)hv[7] << 16);
        L.x = (uint)lv[0] | ((uint)lv[1] << 16); L.y = (uint)lv[2] | ((uint)lv[3] << 16);
        L.z = (uint)lv[4] | ((uint)lv[5] << 16); L.w = (uint)lv[6] | ((uint)lv[7] << 16);
        *(uint4*)&vSH[(kb * 64 + d) * 8] = H;
        *(uint4*)&vSL[(kb * 64 + d) * 8] = L;
      }
    }
    __syncthreads();

    f32x4 sacc[2][4];
#pragma unroll
    for (int i = 0; i < 2; ++i)
#pragma unroll
      for (int j = 0; j < 4; ++j) sacc[i][j] = (f32x4){0.f, 0.f, 0.f, 0.f};
#pragma unroll
    for (int ds = 0; ds < 2; ++ds) {
#pragma unroll
      for (int kc = 0; kc < 4; ++kc) {
        int idx = ((ds * 4 + l4) * 64 + kc * 16 + l15) * 8;
        bf16x8 bh = *(const bf16x8*)&kTH[idx];
        bf16x8 bl = *(const bf16x8*)&kTL[idx];
#pragma unroll
        for (int qr = 0; qr < 2; ++qr) {
          sacc[qr][kc] = __builtin_amdgcn_mfma_f32_16x16x32_bf16(ql[qr][ds], bh, sacc[qr][kc], 0, 0, 0);
          sacc[qr][kc] = __builtin_amdgcn_mfma_f32_16x16x32_bf16(qh[qr][ds], bl, sacc[qr][kc], 0, 0, 0);
          sacc[qr][kc] = __builtin_amdgcn_mfma_f32_16x16x32_bf16(qh[qr][ds], bh, sacc[qr][kc], 0, 0, 0);
        }
      }
    }

    float t[2][4];
#pragma unroll
    for (int qr = 0; qr < 2; ++qr)
#pragma unroll
      for (int r = 0; r < 4; ++r) {
        float a0 = sacc[qr][0][r] * 0.125f; sacc[qr][0][r] = a0;
        float a1 = sacc[qr][1][r] * 0.125f; sacc[qr][1][r] = a1;
        float a2 = sacc[qr][2][r] * 0.125f; sacc[qr][2][r] = a2;
        float a3 = sacc[qr][3][r] * 0.125f; sacc[qr][3][r] = a3;
        t[qr][r] = fmaxf(fmaxf(a0, a1), fmaxf(a2, a3));
      }
#pragma unroll
    for (int off = 1; off < 16; off <<= 1)
#pragma unroll
      for (int qr = 0; qr < 2; ++qr)
#pragma unroll
        for (int r = 0; r < 4; ++r)
          t[qr][r] = fmaxf(t[qr][r], __shfl_xor(t[qr][r], off));
    float f_[2][4];
#pragma unroll
    for (int qr = 0; qr < 2; ++qr)
#pragma unroll
      for (int r = 0; r < 4; ++r) {
        float mn = fmaxf(m_[qr][r], t[qr][r]);
        f_[qr][r] = expf(m_[qr][r] - mn);
        m_[qr][r] = mn;
      }
#pragma unroll
    for (int qr = 0; qr < 2; ++qr)
#pragma unroll
      for (int dc = 0; dc < 4; ++dc)
#pragma unroll
        for (int r = 0; r < 4; ++r) oacc[qr][dc][r] *= f_[qr][r];
    float sm[2][4];
#pragma unroll
    for (int qr = 0; qr < 2; ++qr)
#pragma unroll
      for (int r = 0; r < 4; ++r) {
        float p0 = expf(sacc[qr][0][r] - m_[qr][r]); sacc[qr][0][r] = p0;
        float p1 = expf(sacc[qr][1][r] - m_[qr][r]); sacc[qr][1][r] = p1;
        float p2 = expf(sacc[qr][2][r] - m_[qr][r]); sacc[qr][2][r] = p2;
        float p3 = expf(sacc[qr][3][r] - m_[qr][r]); sacc[qr][3][r] = p3;
        sm[qr][r] = ((p0 + p1) + (p2 + p3));
      }
#pragma unroll
    for (int off = 1; off < 16; off <<= 1)
#pragma unroll
      for (int qr = 0; qr < 2; ++qr)
#pragma unroll
        for (int r = 0; r < 4; ++r)
          sm[qr][r] += __shfl_xor(sm[qr][r], off);
#pragma unroll
    for (int qr = 0; qr < 2; ++qr)
#pragma unroll
      for (int r = 0; r < 4; ++r) l_[qr][r] = l_[qr][r] * f_[qr][r] + sm[qr][r];

#pragma unroll
    for (int qr = 0; qr < 2; ++qr)
#pragma unroll
      for (int kc = 0; kc < 4; ++kc)
#pragma unroll
        for (int r = 0; r < 4; ++r) {
          float pv = sacc[qr][kc][r];
          ushort hi = f2bf(pv);
          ushort lo = f2bf(pv - bf2f(hi));
          int k = kc * 16 + l15;
          int qrow = qr * 16 + l4 * 4 + r;
          int idx = ((k >> 3) * 32 + qrow) * 8 + (k & 7);
          pHw[idx] = hi;
          pLw[idx] = lo;
        }

#pragma unroll
    for (int ks = 0; ks < 2; ++ks) {
      bf16x8 pah[2], pal[2];
#pragma unroll
      for (int qr = 0; qr < 2; ++qr) {
        int idx = ((ks * 4 + l4) * 32 + qr * 16 + l15) * 8;
        pah[qr] = *(const bf16x8*)&pHw[idx];
        pal[qr] = *(const bf16x8*)&pLw[idx];
      }
#pragma unroll
      for (int dc = 0; dc < 4; ++dc) {
        int idx = ((ks * 4 + l4) * 64 + dc * 16 + l15) * 8;
        bf16x8 vh = *(const bf16x8*)&vSH[idx];
        bf16x8 vl = *(const bf16x8*)&vSL[idx];
#pragma unroll
        for (int qr = 0; qr < 2; ++qr) {
          oacc[qr][dc] = __builtin_amdgcn_mfma_f32_16x16x32_bf16(pal[qr], vh, oacc[qr][dc], 0, 0, 0);
          oacc[qr][dc] = __builtin_amdgcn_mfma_f32_16x16x32_bf16(pah[qr], vl, oacc[qr][dc], 0, 0, 0);
          oacc[qr][dc] = __builtin_amdgcn_mfma_f32_16x16x32_bf16(pah[qr], vh, oacc[qr][dc], 0, 0, 0);
        }
      }
    }
    __syncthreads();
  }

  float il[2][4];
#pragma unroll
  for (int qr = 0; qr < 2; ++qr)
#pragma unroll
    for (int r = 0; r < 4; ++r) il[qr][r] = 1.f / l_[qr][r];
#pragma unroll
  for (int qr = 0; qr < 2; ++qr)
#pragma unroll
    for (int dc = 0; dc < 4; ++dc)
#pragma unroll
      for (int r = 0; r < 4; ++r) {
        int row = b * NCTR + qbase + qr * 16 + l4 * 4 + r;
        int col = hh * 64 + dc * 16 + l15;
        split_store(oacc[qr][dc][r] * il[qr][r], oH, oL, (size_t)row * NDIM + col);
      }
}

// ---------------------------------------------------------------------------
extern "C" void kernel_launch(void* const* d_in, const int* in_sizes, int n_in,
                              void* d_out, int out_size, void* d_ws, size_t ws_size,
                              hipStream_t stream) {
  const float* pc      = (const float*)d_in[0];
  const float* embed_w = (const float*)d_in[1];
  const float* embed_b = (const float*)d_in[2];
  const float* lw1     = (const float*)d_in[3];
  const float* lb1     = (const float*)d_in[4];
  const float* lw2     = (const float*)d_in[5];
  const float* lb2     = (const float*)d_in[6];
  const float* gw1     = (const float*)d_in[7];
  const float* gb1     = (const float*)d_in[8];
  const float* gw2     = (const float*)d_in[9];
  const float* gb2     = (const float*)d_in[10];
  const float* ln1_g   = (const float*)d_in[11];
  const float* ln1_b   = (const float*)d_in[12];
  const float* qkv_w   = (const float*)d_in[13];
  const float* qkv_b   = (const float*)d_in[14];
  const float* proj_w  = (const float*)d_in[15];
  const float* proj_b  = (const float*)d_in[16];
  const float* gamma1  = (const float*)d_in[17];
  const float* ln2_g   = (const float*)d_in[18];
  const float* ln2_b   = (const float*)d_in[19];
  const float* fc1_w   = (const float*)d_in[20];
  const float* fc1_b   = (const float*)d_in[21];
  const float* fc2_w   = (const float*)d_in[22];
  const float* fc2_b   = (const float*)d_in[23];
  const float* gamma2  = (const float*)d_in[24];
  const float* lnf_g   = (const float*)d_in[25];
  const float* lnf_b   = (const float*)d_in[26];

  float* out = (float*)d_out;
  float* centers = out + (size_t)NB * NCTR * NDIM;

  char* ws = (char*)d_ws;
  int*    nn  = (int*)(ws + 0);                    //  1,048,576
  float*  x   = (float*)(ws + 1048576);            // 12,582,912 fp32 resid
  ushort* xnH = (ushort*)(ws + 13631488);          //  6,291,456
  ushort* xnL = (ushort*)(ws + 19922944);          //  6,291,456
  ushort* FH  = (ushort*)(ws + 26214400);          // 25,165,824
  ushort* FL  = (ushort*)(ws + 51380224);          // 25,165,824
  ushort* hH  = (ushort*)(ws + 76546048);          //  4,194,304
  ushort* hL  = (ushort*)(ws + 80740352);          //  4,194,304
  ushort* wsplit = (ushort*)(ws + 84934656);       // 43,450,368 -> 128,385,024

  // --- weight pre-split, stacked per family (8 launches) ---
  size_t wofs = 0;
  auto convp = [&](const float* w, int Kpad, int N, int Ksrc) -> ushort* {
    ushort* dst = wsplit + wofs;
    int K8 = Kpad >> 3, total = K8 * N;
    wconv<<<(total + 255) / 256, 256, 0, stream>>>(w, dst, K8, N, Ksrc);
    wofs += (size_t)2 * Kpad * N;
    return dst;
  };
  ushort* qkvS = convp(qkv_w, 2304, 1152, 2304);   // per-layer hi stride 442368, lo base +2654208
  ushort* projS = convp(proj_w, 2304, 384, 2304);  // stride 147456, lo +884736
  ushort* fc1S = convp(fc1_w, 2304, 1536, 2304);   // stride 589824, lo +3538944
  ushort* fc2S = convp(fc2_w, 9216, 384, 9216);    // stride 589824, lo +3538944
  ushort* g1S  = convp(gw1, 256, 256, 256);        // lo +65536
  ushort* g2S  = convp(gw2, 256, 384, 256);        // lo +98304
  ushort* lw1s = convp(lw1, 64, 256, 51);
  ushort* lw2s = convp(lw2, 256, 256, 256);

  // --- geometry + fused edge pipeline ---
  fps_kernel<<<NB, 256, 0, stream>>>(pc, centers);
  knn_kernel<<<2048, 256, 0, stream>>>(pc, centers, nn);
  edge_mfma<<<4096, 256, 0, stream>>>(pc, centers, nn, lw1s, lb1, lw2s, lb2, hH, hL);

  gemm_s<1, 1><<<dim3(2, 64), 256, 0, stream>>>(hH, hL, g1S, g1S + 65536, gb1,
                                                nullptr, nullptr, nullptr, xnH, xnL,
                                                8192, 256, 256);
  gemm_s<0, 0><<<dim3(3, 64), 256, 0, stream>>>(xnH, xnL, g2S, g2S + 98304, gb2,
                                                nullptr, nullptr, x, nullptr, nullptr,
                                                8192, 384, 256);
  pe_add<<<8192, 256, 0, stream>>>(centers, embed_w, embed_b, x);

  for (int l = 0; l < 6; ++l) {
    ln_split<<<2048, 256, 0, stream>>>(x, ln1_g + l * 384, ln1_b + l * 384, xnH, xnL);
    gemm_s<0, 1><<<dim3(9, 64), 256, 0, stream>>>(
        xnH, xnL, qkvS + (size_t)l * 442368, qkvS + 2654208 + (size_t)l * 442368,
        qkv_b + l * 1152, nullptr, nullptr, nullptr, FH, FL, 8192, 1152, 384);
    attn_mfma<<<384, 256, 0, stream>>>(FH, FL, xnH, xnL);
    gemm_s<3, 0><<<dim3(3, 64), 256, 0, stream>>>(
        xnH, xnL, projS + (size_t)l * 147456, projS + 884736 + (size_t)l * 147456,
        proj_b + l * 384, gamma1 + l * 384, x, x, nullptr, nullptr, 8192, 384, 384);
    ln_split<<<2048, 256, 0, stream>>>(x, ln2_g + l * 384, ln2_b + l * 384, xnH, xnL);
    gemm_s<2, 1><<<dim3(12, 64), 256, 0, stream>>>(
        xnH, xnL, fc1S + (size_t)l * 589824, fc1S + 3538944 + (size_t)l * 589824,
        fc1_b + l * 1536, nullptr, nullptr, nullptr, FH, FL, 8192, 1536, 384);
    gemm_s<3, 0><<<dim3(3, 64), 256, 0, stream>>>(
        FH, FL, fc2S + (size_t)l * 589824, fc2S + 3538944 + (size_t)l * 589824,
        fc2_b + l * 384, gamma2 + l * 384, x, x, nullptr, nullptr, 8192, 384, 1536);
  }
  ln_f32<<<2048, 256, 0, stream>>>(x, lnf_g, lnf_b, out);
}